// Round 1
// baseline (2608.990 us; speedup 1.0000x reference)
//
#include <hip/hip_runtime.h>
#include <math.h>

#define BB 16
#define NN 1024
#define KSEL 512
#define DIN 64
#define HH 256
#define NHEAD 8
#define HD 32
#define LL 2
#define FFD 1024
#define MTOT (BB*NN)   // 16384

// ---------------- block reduce helpers (256 threads = 4 waves) ----------------
__device__ __forceinline__ float block_sum(float v, float* red) {
    #pragma unroll
    for (int o = 32; o; o >>= 1) v += __shfl_down(v, o, 64);
    int wid = threadIdx.x >> 6;
    __syncthreads();
    if ((threadIdx.x & 63) == 0) red[wid] = v;
    __syncthreads();
    return red[0] + red[1] + red[2] + red[3];
}

__device__ __forceinline__ float block_max(float v, float* red) {
    #pragma unroll
    for (int o = 32; o; o >>= 1) v = fmaxf(v, __shfl_down(v, o, 64));
    int wid = threadIdx.x >> 6;
    __syncthreads();
    if ((threadIdx.x & 63) == 0) red[wid] = v;
    __syncthreads();
    return fmaxf(fmaxf(red[0], red[1]), fmaxf(red[2], red[3]));
}

// ---------------- fp32 tiled GEMM: C[M,Nd] = A[M,Kd] @ Bw[Kd,Nd] + bias ----------------
template<int RELU>
__global__ __launch_bounds__(256) void gemm_kernel(const float* __restrict__ A,
                                                   const float* __restrict__ Bw,
                                                   const float* __restrict__ bias,
                                                   float* __restrict__ C,
                                                   int M, int Kd, int Nd) {
    __shared__ float As[16][65];
    __shared__ float Bs[16][65];
    const int tid = threadIdx.x;
    const int bm = blockIdx.y * 64;
    const int bn = blockIdx.x * 64;
    const int tx = tid & 15;   // n dir
    const int ty = tid >> 4;   // m dir
    float acc[4][4] = {};

    for (int k0 = 0; k0 < Kd; k0 += 16) {
        #pragma unroll
        for (int i = tid; i < 64 * 16; i += 256) {
            int m = i >> 4, k = i & 15;
            As[k][m] = A[(size_t)(bm + m) * Kd + k0 + k];
        }
        #pragma unroll
        for (int i = tid; i < 16 * 64; i += 256) {
            int k = i >> 6, n = i & 63;
            Bs[k][n] = Bw[(size_t)(k0 + k) * Nd + bn + n];
        }
        __syncthreads();
        #pragma unroll
        for (int k = 0; k < 16; ++k) {
            float a[4], b[4];
            #pragma unroll
            for (int i = 0; i < 4; ++i) a[i] = As[k][ty * 4 + i];
            #pragma unroll
            for (int j = 0; j < 4; ++j) b[j] = Bs[k][tx * 4 + j];
            #pragma unroll
            for (int i = 0; i < 4; ++i)
                #pragma unroll
                for (int j = 0; j < 4; ++j)
                    acc[i][j] = fmaf(a[i], b[j], acc[i][j]);
        }
        __syncthreads();
    }
    #pragma unroll
    for (int i = 0; i < 4; ++i) {
        #pragma unroll
        for (int j = 0; j < 4; ++j) {
            float v = acc[i][j] + bias[bn + tx * 4 + j];
            if (RELU) v = fmaxf(v, 0.f);
            C[(size_t)(bm + ty * 4 + i) * Nd + bn + tx * 4 + j] = v;
        }
    }
}

// ---------------- attention: one thread per q row, flash-style ----------------
__global__ __launch_bounds__(256) void attn_kernel(const float* __restrict__ qkv,
                                                   float* __restrict__ o) {
    __shared__ float Ks[128][HD];
    __shared__ float Vs[128][HD];
    const int tid = threadIdx.x;
    const int qb = blockIdx.x & 3;
    const int h  = (blockIdx.x >> 2) & 7;
    const int b  = blockIdx.x >> 5;
    const int q  = qb * 256 + tid;

    const float scale = 0.17677669529663687f;  // 1/sqrt(32)
    float qr[HD];
    const float* qrow = qkv + (size_t)(b * NN + q) * (3 * HH) + h * HD;
    #pragma unroll
    for (int d = 0; d < HD; ++d) qr[d] = qrow[d] * scale;

    float m = -INFINITY, l = 0.f;
    float acc[HD] = {};

    for (int kc = 0; kc < NN; kc += 128) {
        for (int i = tid; i < 128 * HD; i += 256) {
            int kk = i >> 5, d = i & 31;
            const float* base = qkv + (size_t)(b * NN + kc + kk) * (3 * HH);
            Ks[kk][d] = base[HH + h * HD + d];
            Vs[kk][d] = base[2 * HH + h * HD + d];
        }
        __syncthreads();
        for (int kk = 0; kk < 128; ++kk) {
            float s = 0.f;
            #pragma unroll
            for (int d = 0; d < HD; ++d) s = fmaf(qr[d], Ks[kk][d], s);
            float mn = fmaxf(m, s);
            float corr = __expf(m - mn);
            float p = __expf(s - mn);
            l = l * corr + p;
            #pragma unroll
            for (int d = 0; d < HD; ++d) acc[d] = fmaf(acc[d], corr, p * Vs[kk][d]);
            m = mn;
        }
        __syncthreads();
    }
    float inv = 1.f / l;
    float* orow = o + (size_t)(b * NN + q) * HH + h * HD;
    #pragma unroll
    for (int d = 0; d < HD; ++d) orow[d] = acc[d] * inv;
}

// ---------------- residual + LayerNorm: h = LN(h + delta) * g + b ----------------
__global__ __launch_bounds__(256) void ln_residual_kernel(float* __restrict__ hio,
                                                          const float* __restrict__ delta,
                                                          const float* __restrict__ g,
                                                          const float* __restrict__ bta) {
    __shared__ float red[4];
    const int row = blockIdx.x;
    const int t = threadIdx.x;
    float v = hio[(size_t)row * HH + t] + delta[(size_t)row * HH + t];
    float mean = block_sum(v, red) * (1.f / HH);
    float d = v - mean;
    float var = block_sum(d * d, red) * (1.f / HH);
    float rs = rsqrtf(var + 1e-5f);
    hio[(size_t)row * HH + t] = d * rs * g[t] + bta[t];
}

// ---------------- allocation: one block per batch ----------------
__global__ __launch_bounds__(256) void alloc_kernel(const float* __restrict__ enc,
                                                    const int* __restrict__ idx,
                                                    const float* __restrict__ Wc,
                                                    const float* __restrict__ bc,
                                                    float* __restrict__ out) {
    __shared__ float mean_s[HH];
    __shared__ float ctx_s[HH];
    __shared__ float alloc_s[KSEL];
    __shared__ int   idx_s[KSEL];
    __shared__ float red[4];
    __shared__ float diff_s;
    const int b = blockIdx.x;
    const int t = threadIdx.x;

    for (int k = t; k < KSEL; k += 256) idx_s[k] = idx[b * KSEL + k];
    __syncthreads();

    // count valid
    float c = 0.f;
    for (int k = t; k < KSEL; k += 256) c += (idx_s[k] < NN) ? 1.f : 0.f;
    float cntf = fmaxf(block_sum(c, red), 1.f);

    // mean over gathered rows (thread t owns column t; coalesced across threads)
    float sum = 0.f;
    for (int k = 0; k < KSEL; ++k) {
        int id = idx_s[k];
        if (id < NN) sum += enc[(size_t)(b * NN + id) * HH + t];
    }
    mean_s[t] = sum / cntf;
    __syncthreads();

    // ctx = mean @ Wc + bc
    float cv = bc[t];
    for (int j = 0; j < HH; ++j) cv = fmaf(mean_s[j], Wc[(size_t)j * HH + t], cv);
    ctx_s[t] = cv;
    __syncthreads();

    // scores (each thread handles k = t and k = t+256)
    float sc[2];
    #pragma unroll
    for (int r = 0; r < 2; ++r) {
        int k = t + r * 256;
        int id = idx_s[k];
        float s = -1e9f;
        if (id < NN) {
            s = 0.f;
            const float* row = enc + (size_t)(b * NN + id) * HH;
            for (int j = 0; j < HH; ++j) s = fmaf(ctx_s[j], row[j], s);
        }
        sc[r] = s;
    }
    float smax = block_max(fmaxf(sc[0], sc[1]), red);
    float e0 = (idx_s[t] < NN)       ? expf(sc[0] - smax) : 0.f;
    float e1 = (idx_s[t + 256] < NN) ? expf(sc[1] - smax) : 0.f;
    float ssum = block_sum(e0 + e1, red);
    float inv = 100.f / ssum;

    float a0 = rintf(e0 * inv);
    float a1 = rintf(e1 * inv);
    alloc_s[t] = a0;
    alloc_s[t + 256] = a1;
    float asum = block_sum(a0 + a1, red);
    if (t == 0) diff_s = 100.f - asum;
    __syncthreads();

    // apply diff to slot 0 (idx_s[0] always valid: lengths >= K/2 >= 1)
    if (t == 0 && idx_s[0] < NN) alloc_s[0] += diff_s;
    __syncthreads();

    // outputs: [0:8192) = selected_indices as float; [8192:) = bw [B,N]
    float* bw = out + BB * KSEL + (size_t)b * NN;
    for (int n = t; n < NN; n += 256) bw[n] = 0.f;
    __syncthreads();
    for (int k = t; k < KSEL; k += 256) {
        int id = idx_s[k];
        if (id < NN) bw[id] = alloc_s[k];
        out[b * KSEL + k] = (float)idx_s[k];
    }
}

// ---------------- launch ----------------
extern "C" void kernel_launch(void* const* d_in, const int* in_sizes, int n_in,
                              void* d_out, int out_size, void* d_ws, size_t ws_size,
                              hipStream_t stream) {
    const float* x     = (const float*)d_in[0];
    const int*   sel   = (const int*)  d_in[1];
    const float* W_in  = (const float*)d_in[2];
    const float* b_in  = (const float*)d_in[3];
    const float* Wqkv  = (const float*)d_in[4];
    const float* bqkv  = (const float*)d_in[5];
    const float* Wo    = (const float*)d_in[6];
    const float* bo    = (const float*)d_in[7];
    const float* ln1_g = (const float*)d_in[8];
    const float* ln1_b = (const float*)d_in[9];
    const float* W1    = (const float*)d_in[10];
    const float* b1    = (const float*)d_in[11];
    const float* W2    = (const float*)d_in[12];
    const float* b2    = (const float*)d_in[13];
    const float* ln2_g = (const float*)d_in[14];
    const float* ln2_b = (const float*)d_in[15];
    const float* Wc    = (const float*)d_in[16];
    const float* bc    = (const float*)d_in[17];
    float* out = (float*)d_out;

    float* h    = (float*)d_ws;               // 16384*256
    float* buf1 = h + (size_t)MTOT * HH;      // 16384*1024 (qkv / ff / tmp)
    float* buf2 = buf1 + (size_t)MTOT * FFD;  // 16384*256

    // h = x @ W_in + b_in
    gemm_kernel<0><<<dim3(256 / 64, MTOT / 64), 256, 0, stream>>>(x, W_in, b_in, h, MTOT, DIN, HH);

    for (int l = 0; l < LL; ++l) {
        // qkv
        gemm_kernel<0><<<dim3(768 / 64, MTOT / 64), 256, 0, stream>>>(
            h, Wqkv + (size_t)l * HH * 3 * HH, bqkv + l * 3 * HH, buf1, MTOT, HH, 3 * HH);
        // attention
        attn_kernel<<<BB * NHEAD * (NN / 256), 256, 0, stream>>>(buf1, buf2);
        // o proj
        gemm_kernel<0><<<dim3(HH / 64, MTOT / 64), 256, 0, stream>>>(
            buf2, Wo + (size_t)l * HH * HH, bo + l * HH, buf1, MTOT, HH, HH);
        // h = LN(h + o)
        ln_residual_kernel<<<MTOT, 256, 0, stream>>>(h, buf1, ln1_g + l * HH, ln1_b + l * HH);
        // ffn
        gemm_kernel<1><<<dim3(FFD / 64, MTOT / 64), 256, 0, stream>>>(
            h, W1 + (size_t)l * HH * FFD, b1 + l * FFD, buf1, MTOT, HH, FFD);
        gemm_kernel<0><<<dim3(HH / 64, MTOT / 64), 256, 0, stream>>>(
            buf1, W2 + (size_t)l * FFD * HH, b2 + l * HH, buf2, MTOT, FFD, HH);
        // h = LN(h + f)
        ln_residual_kernel<<<MTOT, 256, 0, stream>>>(h, buf2, ln2_g + l * HH, ln2_b + l * HH);
    }

    // allocation + output write
    alloc_kernel<<<BB, 256, 0, stream>>>(h, sel, Wc, bc, out);
}

// Round 2
// 1112.435 us; speedup vs baseline: 2.3453x; 2.3453x over previous
//
#include <hip/hip_runtime.h>
#include <math.h>

#define BB 16
#define NN 1024
#define KSEL 512
#define DIN 64
#define HH 256
#define NHEAD 8
#define HD 32
#define LL 2
#define FFD 1024
#define MTOT (BB*NN)   // 16384

typedef __attribute__((ext_vector_type(8))) short s8v;   // 8 bf16
typedef __attribute__((ext_vector_type(4))) short s4v;
typedef __attribute__((ext_vector_type(4))) float f4v;

__device__ __forceinline__ float b2f(short u) {
    union { unsigned int i; float f; } v;
    v.i = ((unsigned int)(unsigned short)u) << 16;
    return v.f;
}
__device__ __forceinline__ short f2b(float f) {
    union { float f; unsigned int i; } v;
    v.f = f;
    unsigned int r = v.i + 0x7fffu + ((v.i >> 16) & 1u);
    return (short)(r >> 16);
}

#define GLOAD16(g, l) __builtin_amdgcn_global_load_lds( \
    (const __attribute__((address_space(1))) unsigned int*)(const void*)(g), \
    (__attribute__((address_space(3))) unsigned int*)(l), 16, 0, 0)

// ---------------- block reduce helpers ----------------
__device__ __forceinline__ float block_sum(float v, float* red) {
    #pragma unroll
    for (int o = 32; o; o >>= 1) v += __shfl_down(v, o, 64);
    int wid = threadIdx.x >> 6;
    __syncthreads();
    if ((threadIdx.x & 63) == 0) red[wid] = v;
    __syncthreads();
    return red[0] + red[1] + red[2] + red[3];
}
__device__ __forceinline__ float block_max(float v, float* red) {
    #pragma unroll
    for (int o = 32; o; o >>= 1) v = fmaxf(v, __shfl_down(v, o, 64));
    int wid = threadIdx.x >> 6;
    __syncthreads();
    if ((threadIdx.x & 63) == 0) red[wid] = v;
    __syncthreads();
    return fmaxf(fmaxf(red[0], red[1]), fmaxf(red[2], red[3]));
}

// ---------------- convert fp32 -> bf16 (x input) ----------------
__global__ __launch_bounds__(256) void cvt_kernel(const float* __restrict__ in,
                                                  short* __restrict__ out, int n4) {
    int i = blockIdx.x * 256 + threadIdx.x;
    if (i >= n4) return;
    f4v v = *(const f4v*)(in + (size_t)i * 4);
    s4v o;
    o[0] = f2b(v[0]); o[1] = f2b(v[1]); o[2] = f2b(v[2]); o[3] = f2b(v[3]);
    *(s4v*)(out + (size_t)i * 4) = o;
}

// ---------------- weight transpose+convert: in fp32 [K][N] -> out bf16 [N][K] ----------------
__global__ __launch_bounds__(256) void wtrans_kernel(const float* __restrict__ in,
                                                     short* __restrict__ out, int K, int N) {
    __shared__ float s[32][33];
    int bn = blockIdx.x * 32, bk = blockIdx.y * 32;
    int c = threadIdx.x & 31, r8 = threadIdx.x >> 5;
    #pragma unroll
    for (int i = 0; i < 4; ++i) {
        int r = r8 + i * 8;
        s[r][c] = in[(size_t)(bk + r) * N + bn + c];
    }
    __syncthreads();
    #pragma unroll
    for (int i = 0; i < 4; ++i) {
        int r = r8 + i * 8;  // indexes N dim of out tile
        out[(size_t)(bn + r) * K + bk + c] = f2b(s[c][r]);
    }
}

// ---------------- bf16 MFMA GEMM: C[M,N] = A[M,K] @ BT[N,K]^T + bias ----------------
// 128x128 tile, BK=32, 4 waves (2x2), 16x16x32 mfma, global_load_lds staging,
// XOR slot-swizzle (slot ^= row&3) on both stage-source and ds_read -> 8-cyc b128 floor.
template<int RELU>
__global__ __launch_bounds__(256) void gemm_mfma(const short* __restrict__ A,
                                                 const short* __restrict__ BT,
                                                 const float* __restrict__ bias,
                                                 short* __restrict__ C,
                                                 int M, int K, int N) {
    __shared__ __align__(16) short Alds[128 * 32];
    __shared__ __align__(16) short Blds[128 * 32];
    const int tid = threadIdx.x, lane = tid & 63, wid = tid >> 6;
    const int bm = blockIdx.y * 128, bn = blockIdx.x * 128;
    const int wr = wid >> 1, wc = wid & 1;
    f4v acc[4][4] = {};

    // staging coords: chunk i covers LDS bytes (wid*2+i)*1024 + lane*16
    const int row0 = (wid * 2 + 0) * 16 + (lane >> 2);
    const int row1 = (wid * 2 + 1) * 16 + (lane >> 2);
    const int sc0 = ((lane & 3) ^ (row0 & 3)) * 8;   // element offset of source 16B slot
    const int sc1 = ((lane & 3) ^ (row1 & 3)) * 8;
    short* aldst0 = Alds + (wid * 2 + 0) * 512;
    short* aldst1 = Alds + (wid * 2 + 1) * 512;
    short* bldst0 = Blds + (wid * 2 + 0) * 512;
    short* bldst1 = Blds + (wid * 2 + 1) * 512;
    const short* aB = A + (size_t)bm * K;
    const short* bB = BT + (size_t)bn * K;

    const int frow = lane & 15, fs = lane >> 4;

    for (int k0 = 0; k0 < K; k0 += 32) {
        GLOAD16(aB + (size_t)row0 * K + k0 + sc0, aldst0);
        GLOAD16(aB + (size_t)row1 * K + k0 + sc1, aldst1);
        GLOAD16(bB + (size_t)row0 * K + k0 + sc0, bldst0);
        GLOAD16(bB + (size_t)row1 * K + k0 + sc1, bldst1);
        __syncthreads();
        s8v af[4], bf[4];
        #pragma unroll
        for (int m = 0; m < 4; ++m) {
            int row = wr * 64 + m * 16 + frow;
            af[m] = *(const s8v*)((const char*)Alds + row * 64 + ((fs ^ (row & 3)) * 16));
        }
        #pragma unroll
        for (int n = 0; n < 4; ++n) {
            int row = wc * 64 + n * 16 + frow;
            bf[n] = *(const s8v*)((const char*)Blds + row * 64 + ((fs ^ (row & 3)) * 16));
        }
        #pragma unroll
        for (int m = 0; m < 4; ++m)
            #pragma unroll
            for (int n = 0; n < 4; ++n)
                acc[m][n] = __builtin_amdgcn_mfma_f32_16x16x32_bf16(af[m], bf[n], acc[m][n], 0, 0, 0);
        __syncthreads();
    }
    #pragma unroll
    for (int m = 0; m < 4; ++m) {
        int rbase = bm + wr * 64 + m * 16 + (lane >> 4) * 4;
        #pragma unroll
        for (int n = 0; n < 4; ++n) {
            int col = bn + wc * 64 + n * 16 + (lane & 15);
            float bv = bias[col];
            #pragma unroll
            for (int r = 0; r < 4; ++r) {
                float v = acc[m][n][r] + bv;
                if (RELU) v = fmaxf(v, 0.f);
                C[(size_t)(rbase + r) * N + col] = f2b(v);
            }
        }
    }
}

// ---------------- attention: split-K=2, deferred-rescale online softmax ----------------
__global__ __launch_bounds__(256) void attn_kernel(const short* __restrict__ qkv,
                                                   float* __restrict__ pbuf) {
    __shared__ float Kf[128][32];
    __shared__ float Vf[128][32];
    const int tid = threadIdx.x;
    const int split = blockIdx.x & 1;
    const int qb = (blockIdx.x >> 1) & 3;
    const int h = (blockIdx.x >> 3) & 7;
    const int b = blockIdx.x >> 6;
    const int q = qb * 256 + tid;
    const float scale = 0.17677669529663687f;

    float qr[HD];
    {
        const s8v* qp = (const s8v*)(qkv + ((size_t)(b * NN + q)) * 768 + h * HD);
        #pragma unroll
        for (int v = 0; v < 4; ++v) {
            s8v x = qp[v];
            #pragma unroll
            for (int j = 0; j < 8; ++j) qr[v * 8 + j] = b2f(x[j]) * scale;
        }
    }
    float m = -1e30f, l = 0.f, acc[HD] = {};
    const int kb = split * 512;
    for (int kc = 0; kc < 512; kc += 128) {
        int row = tid >> 1, half = tid & 1;
        const short* kbase = qkv + ((size_t)(b * NN + kb + kc + row)) * 768 + HH + h * HD + half * 16;
        s8v k0 = *(const s8v*)kbase, k1 = *(const s8v*)(kbase + 8);
        s8v v0 = *(const s8v*)(kbase + HH), v1 = *(const s8v*)(kbase + HH + 8);
        __syncthreads();
        #pragma unroll
        for (int j = 0; j < 8; ++j) {
            Kf[row][half * 16 + j]     = b2f(k0[j]);
            Kf[row][half * 16 + 8 + j] = b2f(k1[j]);
            Vf[row][half * 16 + j]     = b2f(v0[j]);
            Vf[row][half * 16 + 8 + j] = b2f(v1[j]);
        }
        __syncthreads();
        for (int kk = 0; kk < 128; ++kk) {
            const float* kr = Kf[kk];
            float s0 = 0.f, s1 = 0.f, s2 = 0.f, s3 = 0.f;
            #pragma unroll
            for (int j = 0; j < 8; ++j) {
                s0 = fmaf(qr[j],      kr[j],      s0);
                s1 = fmaf(qr[8 + j],  kr[8 + j],  s1);
                s2 = fmaf(qr[16 + j], kr[16 + j], s2);
                s3 = fmaf(qr[24 + j], kr[24 + j], s3);
            }
            float s = (s0 + s1) + (s2 + s3);
            if (s > m + 4.f) {      // deferred rescale (bounded p <= e^4)
                float corr = __expf(m - s);
                l *= corr;
                #pragma unroll
                for (int d = 0; d < HD; ++d) acc[d] *= corr;
                m = s;
            }
            float p = __expf(s - m);
            l += p;
            const float* vr = Vf[kk];
            #pragma unroll
            for (int d = 0; d < HD; ++d) acc[d] = fmaf(p, vr[d], acc[d]);
        }
    }
    size_t r = (size_t)(b * NHEAD + h) * NN + q;
    float* pb = pbuf + r * 68 + split * 34;
    #pragma unroll
    for (int d = 0; d < HD; ++d) pb[d] = acc[d];
    pb[32] = m; pb[33] = l;
}

__global__ __launch_bounds__(256) void attn_merge_kernel(const float* __restrict__ pbuf,
                                                         short* __restrict__ o) {
    size_t r = (size_t)blockIdx.x * 256 + threadIdx.x;  // < B*NH*N
    const float* p0 = pbuf + r * 68;
    const float* p1 = p0 + 34;
    float m0 = p0[32], l0 = p0[33], m1 = p1[32], l1 = p1[33];
    float M = fmaxf(m0, m1);
    float c0 = __expf(m0 - M), c1 = __expf(m1 - M);
    float inv = 1.f / (l0 * c0 + l1 * c1);
    int q = (int)(r & (NN - 1));
    int h = (int)((r >> 10) & 7);
    int b = (int)(r >> 13);
    short* orow = o + ((size_t)(b * NN + q)) * HH + h * HD;
    #pragma unroll
    for (int d = 0; d < HD; ++d) orow[d] = f2b((p0[d] * c0 + p1[d] * c1) * inv);
}

// ---------------- residual + LayerNorm (bf16 io) ----------------
__global__ __launch_bounds__(256) void ln_residual_kernel(short* __restrict__ hio,
                                                          const short* __restrict__ delta,
                                                          const float* __restrict__ g,
                                                          const float* __restrict__ bta) {
    __shared__ float red[4];
    const int row = blockIdx.x;
    const int t = threadIdx.x;
    float v = b2f(hio[(size_t)row * HH + t]) + b2f(delta[(size_t)row * HH + t]);
    float mean = block_sum(v, red) * (1.f / HH);
    float d = v - mean;
    float var = block_sum(d * d, red) * (1.f / HH);
    float rs = rsqrtf(var + 1e-5f);
    hio[(size_t)row * HH + t] = f2b(d * rs * g[t] + bta[t]);
}

// ---------------- allocation (enc in bf16) ----------------
__global__ __launch_bounds__(256) void alloc_kernel(const short* __restrict__ enc,
                                                    const int* __restrict__ idx,
                                                    const float* __restrict__ Wc,
                                                    const float* __restrict__ bc,
                                                    float* __restrict__ out) {
    __shared__ float mean_s[HH];
    __shared__ float ctx_s[HH];
    __shared__ float alloc_s[KSEL];
    __shared__ int   idx_s[KSEL];
    __shared__ float red[4];
    __shared__ float diff_s;
    const int b = blockIdx.x;
    const int t = threadIdx.x;

    for (int k = t; k < KSEL; k += 256) idx_s[k] = idx[b * KSEL + k];
    __syncthreads();

    float c = 0.f;
    for (int k = t; k < KSEL; k += 256) c += (idx_s[k] < NN) ? 1.f : 0.f;
    float cntf = fmaxf(block_sum(c, red), 1.f);

    float sum = 0.f;
    for (int k = 0; k < KSEL; ++k) {
        int id = idx_s[k];
        if (id < NN) sum += b2f(enc[(size_t)(b * NN + id) * HH + t]);
    }
    mean_s[t] = sum / cntf;
    __syncthreads();

    float cv = bc[t];
    for (int j = 0; j < HH; ++j) cv = fmaf(mean_s[j], Wc[(size_t)j * HH + t], cv);
    ctx_s[t] = cv;
    __syncthreads();

    float sc[2];
    #pragma unroll
    for (int r = 0; r < 2; ++r) {
        int k = t + r * 256;
        int id = idx_s[k];
        float s = -1e9f;
        if (id < NN) {
            s = 0.f;
            const short* row = enc + (size_t)(b * NN + id) * HH;
            for (int j = 0; j < HH; ++j) s = fmaf(ctx_s[j], b2f(row[j]), s);
        }
        sc[r] = s;
    }
    float smax = block_max(fmaxf(sc[0], sc[1]), red);
    float e0 = (idx_s[t] < NN)       ? expf(sc[0] - smax) : 0.f;
    float e1 = (idx_s[t + 256] < NN) ? expf(sc[1] - smax) : 0.f;
    float ssum = block_sum(e0 + e1, red);
    float inv = 100.f / ssum;

    float a0 = rintf(e0 * inv);
    float a1 = rintf(e1 * inv);
    alloc_s[t] = a0;
    alloc_s[t + 256] = a1;
    float asum = block_sum(a0 + a1, red);
    if (t == 0) diff_s = 100.f - asum;
    __syncthreads();
    if (t == 0 && idx_s[0] < NN) alloc_s[0] += diff_s;
    __syncthreads();

    float* bw = out + BB * KSEL + (size_t)b * NN;
    for (int n = t; n < NN; n += 256) bw[n] = 0.f;
    __syncthreads();
    for (int k = t; k < KSEL; k += 256) {
        int id = idx_s[k];
        if (id < NN) bw[id] = alloc_s[k];
        out[b * KSEL + k] = (float)idx_s[k];
    }
}

// ---------------- launch ----------------
extern "C" void kernel_launch(void* const* d_in, const int* in_sizes, int n_in,
                              void* d_out, int out_size, void* d_ws, size_t ws_size,
                              hipStream_t stream) {
    const float* x     = (const float*)d_in[0];
    const int*   sel   = (const int*)  d_in[1];
    const float* W_in  = (const float*)d_in[2];
    const float* b_in  = (const float*)d_in[3];
    const float* Wqkv  = (const float*)d_in[4];
    const float* bqkv  = (const float*)d_in[5];
    const float* Wo    = (const float*)d_in[6];
    const float* bo    = (const float*)d_in[7];
    const float* ln1_g = (const float*)d_in[8];
    const float* ln1_b = (const float*)d_in[9];
    const float* W1    = (const float*)d_in[10];
    const float* b1    = (const float*)d_in[11];
    const float* W2    = (const float*)d_in[12];
    const float* b2    = (const float*)d_in[13];
    const float* ln2_g = (const float*)d_in[14];
    const float* ln2_b = (const float*)d_in[15];
    const float* Wc    = (const float*)d_in[16];
    const float* bc    = (const float*)d_in[17];
    float* out = (float*)d_out;

    char* base = (char*)d_ws;
    short* h    = (short*)(base);                       // 8 MB
    short* qkv  = (short*)(base + (8u << 20));          // 24 MB (also o-proj/ffn2 delta)
    short* obuf = (short*)(base + (32u << 20));         // 8 MB
    char*  region = base + (40u << 20);                 // 36 MB: pbuf (attn) / ff (ffn)
    float* pbuf = (float*)region;
    short* ff   = (short*)region;
    short* xb   = (short*)(base + (76u << 20));         // 2 MB
    short* wt   = (short*)(base + (78u << 20));         // ~3.1 MB
    short* W_inT  = wt;                                  // [256][64]
    short* WqkvT  = W_inT + 256 * 64;                    // [L][768][256]
    short* WoT    = WqkvT + LL * 768 * 256;              // [L][256][256]
    short* W1T    = WoT   + LL * 256 * 256;              // [L][1024][256]
    short* W2T    = W1T   + LL * 1024 * 256;             // [L][256][1024]

    // convert inputs
    cvt_kernel<<<(MTOT * DIN / 4 + 255) / 256, 256, 0, stream>>>(x, xb, MTOT * DIN / 4);
    wtrans_kernel<<<dim3(256 / 32, 64 / 32), 256, 0, stream>>>(W_in, W_inT, 64, 256);
    for (int l = 0; l < LL; ++l) {
        wtrans_kernel<<<dim3(768 / 32, 256 / 32), 256, 0, stream>>>(
            Wqkv + (size_t)l * HH * 768, WqkvT + (size_t)l * 768 * HH, 256, 768);
        wtrans_kernel<<<dim3(256 / 32, 256 / 32), 256, 0, stream>>>(
            Wo + (size_t)l * HH * HH, WoT + (size_t)l * HH * HH, 256, 256);
        wtrans_kernel<<<dim3(1024 / 32, 256 / 32), 256, 0, stream>>>(
            W1 + (size_t)l * HH * FFD, W1T + (size_t)l * FFD * HH, 256, 1024);
        wtrans_kernel<<<dim3(256 / 32, 1024 / 32), 256, 0, stream>>>(
            W2 + (size_t)l * FFD * HH, W2T + (size_t)l * HH * FFD, 1024, 256);
    }

    // h = x @ W_in + b_in
    gemm_mfma<0><<<dim3(HH / 128, MTOT / 128), 256, 0, stream>>>(xb, W_inT, b_in, h, MTOT, DIN, HH);

    for (int l = 0; l < LL; ++l) {
        gemm_mfma<0><<<dim3(768 / 128, MTOT / 128), 256, 0, stream>>>(
            h, WqkvT + (size_t)l * 768 * HH, bqkv + l * 768, qkv, MTOT, HH, 768);
        attn_kernel<<<BB * NHEAD * 4 * 2, 256, 0, stream>>>(qkv, pbuf);
        attn_merge_kernel<<<BB * NHEAD * NN / 256, 256, 0, stream>>>(pbuf, obuf);
        gemm_mfma<0><<<dim3(HH / 128, MTOT / 128), 256, 0, stream>>>(
            obuf, WoT + (size_t)l * HH * HH, bo + l * HH, qkv, MTOT, HH, HH);
        ln_residual_kernel<<<MTOT, 256, 0, stream>>>(h, qkv, ln1_g + l * HH, ln1_b + l * HH);
        gemm_mfma<1><<<dim3(FFD / 128, MTOT / 128), 256, 0, stream>>>(
            h, W1T + (size_t)l * FFD * HH, b1 + l * FFD, ff, MTOT, HH, FFD);
        gemm_mfma<0><<<dim3(HH / 128, MTOT / 128), 256, 0, stream>>>(
            ff, W2T + (size_t)l * HH * FFD, b2 + l * HH, qkv, MTOT, FFD, HH);
        ln_residual_kernel<<<MTOT, 256, 0, stream>>>(h, qkv, ln2_g + l * HH, ln2_b + l * HH);
    }

    alloc_kernel<<<BB, 256, 0, stream>>>(h, sel, Wc, bc, out);
}

// Round 3
// 462.218 us; speedup vs baseline: 5.6445x; 2.4067x over previous
//
#include <hip/hip_runtime.h>
#include <math.h>

#define BB 16
#define NN 1024
#define KSEL 512
#define DIN 64
#define HH 256
#define NHEAD 8
#define HD 32
#define LL 2
#define FFD 1024
#define MTOT (BB*NN)   // 16384

typedef __attribute__((ext_vector_type(8))) short s8v;   // 8 bf16
typedef __attribute__((ext_vector_type(4))) short s4v;
typedef __attribute__((ext_vector_type(4))) float f4v;
typedef __attribute__((ext_vector_type(16))) float f16x;

__device__ __forceinline__ float b2f(short u) {
    union { unsigned int i; float f; } v;
    v.i = ((unsigned int)(unsigned short)u) << 16;
    return v.f;
}
__device__ __forceinline__ short f2b(float f) {
    union { float f; unsigned int i; } v;
    v.f = f;
    unsigned int r = v.i + 0x7fffu + ((v.i >> 16) & 1u);
    return (short)(r >> 16);
}
__device__ __forceinline__ unsigned cvtpk_bf16(float a, float b) {
    unsigned r;
    asm("v_cvt_pk_bf16_f32 %0, %1, %2" : "=v"(r) : "v"(a), "v"(b));
    return r;
}

#define GLOAD16(g, l) __builtin_amdgcn_global_load_lds( \
    (const __attribute__((address_space(1))) unsigned int*)(const void*)(g), \
    (__attribute__((address_space(3))) unsigned int*)(l), 16, 0, 0)

// ---------------- block reduce helpers ----------------
__device__ __forceinline__ float block_sum(float v, float* red) {
    #pragma unroll
    for (int o = 32; o; o >>= 1) v += __shfl_down(v, o, 64);
    int wid = threadIdx.x >> 6;
    __syncthreads();
    if ((threadIdx.x & 63) == 0) red[wid] = v;
    __syncthreads();
    return red[0] + red[1] + red[2] + red[3];
}
__device__ __forceinline__ float block_max(float v, float* red) {
    #pragma unroll
    for (int o = 32; o; o >>= 1) v = fmaxf(v, __shfl_down(v, o, 64));
    int wid = threadIdx.x >> 6;
    __syncthreads();
    if ((threadIdx.x & 63) == 0) red[wid] = v;
    __syncthreads();
    return fmaxf(fmaxf(red[0], red[1]), fmaxf(red[2], red[3]));
}

// ---------------- convert fp32 -> bf16 (x input) ----------------
__global__ __launch_bounds__(256) void cvt_kernel(const float* __restrict__ in,
                                                  short* __restrict__ out, int n4) {
    int i = blockIdx.x * 256 + threadIdx.x;
    if (i >= n4) return;
    f4v v = *(const f4v*)(in + (size_t)i * 4);
    s4v o;
    o[0] = f2b(v[0]); o[1] = f2b(v[1]); o[2] = f2b(v[2]); o[3] = f2b(v[3]);
    *(s4v*)(out + (size_t)i * 4) = o;
}

// ---------------- weight transpose+convert: in fp32 [K][N] -> out bf16 [N][K] ----------------
__global__ __launch_bounds__(256) void wtrans_kernel(const float* __restrict__ in,
                                                     short* __restrict__ out, int K, int N) {
    __shared__ float s[32][33];
    int bn = blockIdx.x * 32, bk = blockIdx.y * 32;
    int c = threadIdx.x & 31, r8 = threadIdx.x >> 5;
    #pragma unroll
    for (int i = 0; i < 4; ++i) {
        int r = r8 + i * 8;
        s[r][c] = in[(size_t)(bk + r) * N + bn + c];
    }
    __syncthreads();
    #pragma unroll
    for (int i = 0; i < 4; ++i) {
        int r = r8 + i * 8;
        out[(size_t)(bn + r) * K + bk + c] = f2b(s[c][r]);
    }
}

// ---------------- bf16 MFMA GEMM: C[M,N] = A[M,K] @ BT[N,K]^T + bias ----------------
template<int RELU, int QSCALE>
__global__ __launch_bounds__(256) void gemm_mfma(const short* __restrict__ A,
                                                 const short* __restrict__ BT,
                                                 const float* __restrict__ bias,
                                                 short* __restrict__ C,
                                                 int M, int K, int N) {
    __shared__ __align__(16) short Alds[128 * 32];
    __shared__ __align__(16) short Blds[128 * 32];
    const int tid = threadIdx.x, lane = tid & 63, wid = tid >> 6;
    const int bm = blockIdx.y * 128, bn = blockIdx.x * 128;
    const int wr = wid >> 1, wc = wid & 1;
    f4v acc[4][4] = {};

    const int row0 = (wid * 2 + 0) * 16 + (lane >> 2);
    const int row1 = (wid * 2 + 1) * 16 + (lane >> 2);
    const int sc0 = ((lane & 3) ^ (row0 & 3)) * 8;
    const int sc1 = ((lane & 3) ^ (row1 & 3)) * 8;
    short* aldst0 = Alds + (wid * 2 + 0) * 512;
    short* aldst1 = Alds + (wid * 2 + 1) * 512;
    short* bldst0 = Blds + (wid * 2 + 0) * 512;
    short* bldst1 = Blds + (wid * 2 + 1) * 512;
    const short* aB = A + (size_t)bm * K;
    const short* bB = BT + (size_t)bn * K;

    const int frow = lane & 15, fs = lane >> 4;

    for (int k0 = 0; k0 < K; k0 += 32) {
        GLOAD16(aB + (size_t)row0 * K + k0 + sc0, aldst0);
        GLOAD16(aB + (size_t)row1 * K + k0 + sc1, aldst1);
        GLOAD16(bB + (size_t)row0 * K + k0 + sc0, bldst0);
        GLOAD16(bB + (size_t)row1 * K + k0 + sc1, bldst1);
        __syncthreads();
        s8v af[4], bf[4];
        #pragma unroll
        for (int m = 0; m < 4; ++m) {
            int row = wr * 64 + m * 16 + frow;
            af[m] = *(const s8v*)((const char*)Alds + row * 64 + ((fs ^ (row & 3)) * 16));
        }
        #pragma unroll
        for (int n = 0; n < 4; ++n) {
            int row = wc * 64 + n * 16 + frow;
            bf[n] = *(const s8v*)((const char*)Blds + row * 64 + ((fs ^ (row & 3)) * 16));
        }
        #pragma unroll
        for (int m = 0; m < 4; ++m)
            #pragma unroll
            for (int n = 0; n < 4; ++n)
                acc[m][n] = __builtin_amdgcn_mfma_f32_16x16x32_bf16(af[m], bf[n], acc[m][n], 0, 0, 0);
        __syncthreads();
    }
    #pragma unroll
    for (int m = 0; m < 4; ++m) {
        int rbase = bm + wr * 64 + m * 16 + (lane >> 4) * 4;
        #pragma unroll
        for (int n = 0; n < 4; ++n) {
            int col = bn + wc * 64 + n * 16 + (lane & 15);
            float bv = bias[col];
            #pragma unroll
            for (int r = 0; r < 4; ++r) {
                float v = acc[m][n][r] + bv;
                if (QSCALE) { if (col < 256) v *= 0.17677669529663687f; }
                if (RELU) v = fmaxf(v, 0.f);
                C[(size_t)(rbase + r) * N + col] = f2b(v);
            }
        }
    }
}

// ---------------- MFMA flash attention (swapped QK^T, in-register softmax) ----------------
// block: 256 thr = 4 waves; wave w handles 32 q rows; block covers q-tile of 128.
// Q pre-scaled by 1/sqrt(HD) in the qkv GEMM epilogue.
__global__ __launch_bounds__(256) void attn_mfma(const short* __restrict__ qkv,
                                                 short* __restrict__ o) {
    __shared__ __align__(16) short Klds[2][4][64][8];   // [buf][hd-chunk][token][8hd]
    __shared__ __align__(16) short Vlds[2][32][72];     // [buf][d][token padded]
    const int tid = threadIdx.x, lane = tid & 63, wid = tid >> 6;
    const int hi = lane >> 5, lq = lane & 31;
    const int qt = blockIdx.x & 7;
    const int h  = (blockIdx.x >> 3) & 7;
    const int b  = blockIdx.x >> 6;
    const int q0 = qt * 128 + wid * 32;
    const short* qkvb = qkv + (size_t)b * NN * 768;

    // Q fragments (B-operand): lane holds q=lq, hd = hi*8+j (+16 for frag 1)
    s8v qf0, qf1;
    {
        const short* qrow = qkvb + (size_t)(q0 + lq) * 768 + h * 32 + hi * 8;
        qf0 = *(const s8v*)qrow;
        qf1 = *(const s8v*)(qrow + 16);
    }

    const int token = tid & 63, cK = tid >> 6, dc = cK * 8;

    float m = -1e30f, l = 0.f;
    f16x acc = {};

    // prologue: stage tile 0 into buf 0
    {
        const short* kvrow = qkvb + (size_t)token * 768 + 256 + h * 32;
        GLOAD16(kvrow + cK * 8, &Klds[0][cK][token][0]);
        s8v vv = *(const s8v*)(kvrow + 256 + dc);
        #pragma unroll
        for (int j = 0; j < 8; ++j) Vlds[0][dc + j][token] = vv[j];
    }
    __syncthreads();

    for (int t = 0; t < 16; ++t) {
        const int bb = t & 1;
        s8v vvn;
        if (t < 15) {
            const short* kvrow = qkvb + (size_t)((t + 1) * 64 + token) * 768 + 256 + h * 32;
            GLOAD16(kvrow + cK * 8, &Klds[bb ^ 1][cK][token][0]);
            vvn = *(const s8v*)(kvrow + 256 + dc);
        }
        #pragma unroll
        for (int kt = 0; kt < 2; ++kt) {
            const s8v kf0 = *(const s8v*)&Klds[bb][hi][kt * 32 + lq][0];
            const s8v kf1 = *(const s8v*)&Klds[bb][2 + hi][kt * 32 + lq][0];
            f16x p = {};
            p = __builtin_amdgcn_mfma_f32_32x32x16_bf16(kf0, qf0, p, 0, 0, 0);
            p = __builtin_amdgcn_mfma_f32_32x32x16_bf16(kf1, qf1, p, 0, 0, 0);
            // in-register row max (lane holds 16 of the 32 k's for q=lq)
            float tmax = p[0];
            #pragma unroll
            for (int r = 1; r < 16; ++r) tmax = fmaxf(tmax, p[r]);
            tmax = fmaxf(tmax, __shfl_xor(tmax, 32));
            if (__any(tmax > m + 8.f)) {          // defer-max rescale
                float mn = fmaxf(m, tmax);
                float f = __expf(m - mn);
                l *= f;
                #pragma unroll
                for (int r = 0; r < 16; ++r)
                    acc[r] *= __shfl(f, (r & 3) + 8 * (r >> 2) + 4 * hi);
                m = mn;
            }
            float ps = 0.f;
            #pragma unroll
            for (int r = 0; r < 16; ++r) { p[r] = __expf(p[r] - m); ps += p[r]; }
            l += ps;
            // P -> bf16 A-fragments via cvt_pk + permlane32_swap
            unsigned w[8];
            #pragma unroll
            for (int i = 0; i < 8; ++i) w[i] = cvtpk_bf16(p[2 * i], p[2 * i + 1]);
            asm volatile("v_permlane32_swap_b32 %0, %1" : "+v"(w[0]), "+v"(w[2]));
            asm volatile("v_permlane32_swap_b32 %0, %1" : "+v"(w[1]), "+v"(w[3]));
            asm volatile("v_permlane32_swap_b32 %0, %1" : "+v"(w[4]), "+v"(w[6]));
            asm volatile("v_permlane32_swap_b32 %0, %1" : "+v"(w[5]), "+v"(w[7]));
            union { unsigned u[4]; s8v v; } pa0, pa1;
            pa0.u[0] = w[0]; pa0.u[1] = w[1]; pa0.u[2] = w[2]; pa0.u[3] = w[3];
            pa1.u[0] = w[4]; pa1.u[1] = w[5]; pa1.u[2] = w[6]; pa1.u[3] = w[7];
            const s8v vf0 = *(const s8v*)&Vlds[bb][lq][kt * 32 + hi * 8];
            const s8v vf1 = *(const s8v*)&Vlds[bb][lq][kt * 32 + 16 + hi * 8];
            acc = __builtin_amdgcn_mfma_f32_32x32x16_bf16(pa0.v, vf0, acc, 0, 0, 0);
            acc = __builtin_amdgcn_mfma_f32_32x32x16_bf16(pa1.v, vf1, acc, 0, 0, 0);
        }
        if (t < 15) {
            #pragma unroll
            for (int j = 0; j < 8; ++j) Vlds[bb ^ 1][dc + j][token] = vvn[j];
        }
        __syncthreads();
    }

    // epilogue: normalize and store
    l += __shfl_xor(l, 32);
    float inv = 1.f / l;
    short* ob = o + ((size_t)(b * NN + q0)) * HH + h * 32 + lq;
    #pragma unroll
    for (int r = 0; r < 16; ++r) {
        int qr = (r & 3) + 8 * (r >> 2) + 4 * hi;
        float invr = __shfl(inv, qr);
        ob[(size_t)qr * HH] = f2b(acc[r] * invr);
    }
}

// ---------------- residual + LayerNorm (bf16 io) ----------------
__global__ __launch_bounds__(256) void ln_residual_kernel(short* __restrict__ hio,
                                                          const short* __restrict__ delta,
                                                          const float* __restrict__ g,
                                                          const float* __restrict__ bta) {
    __shared__ float red[4];
    const int row = blockIdx.x;
    const int t = threadIdx.x;
    float v = b2f(hio[(size_t)row * HH + t]) + b2f(delta[(size_t)row * HH + t]);
    float mean = block_sum(v, red) * (1.f / HH);
    float d = v - mean;
    float var = block_sum(d * d, red) * (1.f / HH);
    float rs = rsqrtf(var + 1e-5f);
    hio[(size_t)row * HH + t] = f2b(d * rs * g[t] + bta[t]);
}

// ---------------- allocation (enc in bf16) ----------------
__global__ __launch_bounds__(256) void alloc_kernel(const short* __restrict__ enc,
                                                    const int* __restrict__ idx,
                                                    const float* __restrict__ Wc,
                                                    const float* __restrict__ bc,
                                                    float* __restrict__ out) {
    __shared__ float msum[4][HH];
    __shared__ float ctx_s[HH];
    __shared__ float alloc_s[KSEL];
    __shared__ int   idx_s[KSEL];
    __shared__ float red[4];
    __shared__ float diff_s;
    const int b = blockIdx.x;
    const int t = threadIdx.x;
    const int wid = t >> 6, lane = t & 63;

    for (int k = t; k < KSEL; k += 256) idx_s[k] = idx[b * KSEL + k];
    __syncthreads();

    float c = 0.f;
    for (int k = t; k < KSEL; k += 256) c += (idx_s[k] < NN) ? 1.f : 0.f;
    float cntf = fmaxf(block_sum(c, red), 1.f);

    // gather-mean: wave wid sums k in [wid*128, wid*128+128); lane covers 4 cols
    {
        int c0 = lane * 4;
        float s0 = 0.f, s1 = 0.f, s2 = 0.f, s3 = 0.f;
        for (int k = wid * 128; k < wid * 128 + 128; ++k) {
            int id = idx_s[k];
            if (id < NN) {
                s4v v = *(const s4v*)(enc + (size_t)(b * NN + id) * HH + c0);
                s0 += b2f(v[0]); s1 += b2f(v[1]); s2 += b2f(v[2]); s3 += b2f(v[3]);
            }
        }
        msum[wid][c0] = s0; msum[wid][c0 + 1] = s1;
        msum[wid][c0 + 2] = s2; msum[wid][c0 + 3] = s3;
    }
    __syncthreads();
    float mean = (msum[0][t] + msum[1][t] + msum[2][t] + msum[3][t]) / cntf;
    msum[0][t] = mean;
    __syncthreads();

    float cv = bc[t];
    for (int j = 0; j < HH; ++j) cv = fmaf(msum[0][j], Wc[(size_t)j * HH + t], cv);
    ctx_s[t] = cv;
    __syncthreads();

    float sc[2];
    #pragma unroll
    for (int r = 0; r < 2; ++r) {
        int k = t + r * 256;
        int id = idx_s[k];
        float s = -1e9f;
        if (id < NN) {
            s = 0.f;
            const s8v* row = (const s8v*)(enc + (size_t)(b * NN + id) * HH);
            for (int c8 = 0; c8 < 32; ++c8) {
                s8v v = row[c8];
                #pragma unroll
                for (int j = 0; j < 8; ++j) s = fmaf(ctx_s[c8 * 8 + j], b2f(v[j]), s);
            }
        }
        sc[r] = s;
    }
    float smax = block_max(fmaxf(sc[0], sc[1]), red);
    float e0 = (idx_s[t] < NN)       ? expf(sc[0] - smax) : 0.f;
    float e1 = (idx_s[t + 256] < NN) ? expf(sc[1] - smax) : 0.f;
    float ssum = block_sum(e0 + e1, red);
    float inv = 100.f / ssum;

    float a0 = rintf(e0 * inv);
    float a1 = rintf(e1 * inv);
    alloc_s[t] = a0;
    alloc_s[t + 256] = a1;
    float asum = block_sum(a0 + a1, red);
    if (t == 0) diff_s = 100.f - asum;
    __syncthreads();
    if (t == 0 && idx_s[0] < NN) alloc_s[0] += diff_s;
    __syncthreads();

    float* bw = out + BB * KSEL + (size_t)b * NN;
    for (int n = t; n < NN; n += 256) bw[n] = 0.f;
    __syncthreads();
    for (int k = t; k < KSEL; k += 256) {
        int id = idx_s[k];
        if (id < NN) bw[id] = alloc_s[k];
        out[b * KSEL + k] = (float)idx_s[k];
    }
}

// ---------------- launch ----------------
extern "C" void kernel_launch(void* const* d_in, const int* in_sizes, int n_in,
                              void* d_out, int out_size, void* d_ws, size_t ws_size,
                              hipStream_t stream) {
    const float* x     = (const float*)d_in[0];
    const int*   sel   = (const int*)  d_in[1];
    const float* W_in  = (const float*)d_in[2];
    const float* b_in  = (const float*)d_in[3];
    const float* Wqkv  = (const float*)d_in[4];
    const float* bqkv  = (const float*)d_in[5];
    const float* Wo    = (const float*)d_in[6];
    const float* bo    = (const float*)d_in[7];
    const float* ln1_g = (const float*)d_in[8];
    const float* ln1_b = (const float*)d_in[9];
    const float* W1    = (const float*)d_in[10];
    const float* b1    = (const float*)d_in[11];
    const float* W2    = (const float*)d_in[12];
    const float* b2    = (const float*)d_in[13];
    const float* ln2_g = (const float*)d_in[14];
    const float* ln2_b = (const float*)d_in[15];
    const float* Wc    = (const float*)d_in[16];
    const float* bc    = (const float*)d_in[17];
    float* out = (float*)d_out;

    char* base = (char*)d_ws;
    short* h    = (short*)(base);                       // 8 MB
    short* qkv  = (short*)(base + (8u << 20));          // 24 MB
    short* obuf = (short*)(base + (32u << 20));         // 8 MB
    short* ff   = (short*)(base + (40u << 20));         // 32 MB
    short* xb   = (short*)(base + (76u << 20));         // 2 MB
    short* wt   = (short*)(base + (78u << 20));         // ~3.1 MB
    short* W_inT  = wt;
    short* WqkvT  = W_inT + 256 * 64;
    short* WoT    = WqkvT + LL * 768 * 256;
    short* W1T    = WoT   + LL * 256 * 256;
    short* W2T    = W1T   + LL * 1024 * 256;

    cvt_kernel<<<(MTOT * DIN / 4 + 255) / 256, 256, 0, stream>>>(x, xb, MTOT * DIN / 4);
    wtrans_kernel<<<dim3(256 / 32, 64 / 32), 256, 0, stream>>>(W_in, W_inT, 64, 256);
    for (int l = 0; l < LL; ++l) {
        wtrans_kernel<<<dim3(768 / 32, 256 / 32), 256, 0, stream>>>(
            Wqkv + (size_t)l * HH * 768, WqkvT + (size_t)l * 768 * HH, 256, 768);
        wtrans_kernel<<<dim3(256 / 32, 256 / 32), 256, 0, stream>>>(
            Wo + (size_t)l * HH * HH, WoT + (size_t)l * HH * HH, 256, 256);
        wtrans_kernel<<<dim3(1024 / 32, 256 / 32), 256, 0, stream>>>(
            W1 + (size_t)l * HH * FFD, W1T + (size_t)l * FFD * HH, 256, 1024);
        wtrans_kernel<<<dim3(256 / 32, 1024 / 32), 256, 0, stream>>>(
            W2 + (size_t)l * FFD * HH, W2T + (size_t)l * HH * FFD, 1024, 256);
    }

    gemm_mfma<0,0><<<dim3(HH / 128, MTOT / 128), 256, 0, stream>>>(xb, W_inT, b_in, h, MTOT, DIN, HH);

    for (int l = 0; l < LL; ++l) {
        // qkv projection; Q columns (<256) pre-scaled by 1/sqrt(HD)
        gemm_mfma<0,1><<<dim3(768 / 128, MTOT / 128), 256, 0, stream>>>(
            h, WqkvT + (size_t)l * 768 * HH, bqkv + l * 768, qkv, MTOT, HH, 768);
        attn_mfma<<<BB * NHEAD * 8, 256, 0, stream>>>(qkv, obuf);
        gemm_mfma<0,0><<<dim3(HH / 128, MTOT / 128), 256, 0, stream>>>(
            obuf, WoT + (size_t)l * HH * HH, bo + l * HH, qkv, MTOT, HH, HH);
        ln_residual_kernel<<<MTOT, 256, 0, stream>>>(h, qkv, ln1_g + l * HH, ln1_b + l * HH);
        gemm_mfma<1,0><<<dim3(FFD / 128, MTOT / 128), 256, 0, stream>>>(
            h, W1T + (size_t)l * FFD * HH, b1 + l * FFD, ff, MTOT, HH, FFD);
        gemm_mfma<0,0><<<dim3(HH / 128, MTOT / 128), 256, 0, stream>>>(
            ff, W2T + (size_t)l * HH * FFD, b2 + l * HH, qkv, MTOT, FFD, HH);
        ln_residual_kernel<<<MTOT, 256, 0, stream>>>(h, qkv, ln2_g + l * HH, ln2_b + l * HH);
    }

    alloc_kernel<<<BB, 256, 0, stream>>>(h, sel, Wc, bc, out);
}

// Round 4
// 409.137 us; speedup vs baseline: 6.3768x; 1.1297x over previous
//
#include <hip/hip_runtime.h>
#include <math.h>

#define BB 16
#define NN 1024
#define KSEL 512
#define DIN 64
#define HH 256
#define NHEAD 8
#define HD 32
#define LL 2
#define FFD 1024
#define MTOT (BB*NN)   // 16384

typedef __attribute__((ext_vector_type(8))) short s8v;   // 8 bf16
typedef __attribute__((ext_vector_type(4))) short s4v;
typedef __attribute__((ext_vector_type(4))) float f4v;
typedef __attribute__((ext_vector_type(16))) float f16x;

__device__ __forceinline__ float b2f(short u) {
    union { unsigned int i; float f; } v;
    v.i = ((unsigned int)(unsigned short)u) << 16;
    return v.f;
}
__device__ __forceinline__ short f2b(float f) {
    union { float f; unsigned int i; } v;
    v.f = f;
    unsigned int r = v.i + 0x7fffu + ((v.i >> 16) & 1u);
    return (short)(r >> 16);
}
__device__ __forceinline__ unsigned cvtpk_bf16(float a, float b) {
    unsigned r;
    asm("v_cvt_pk_bf16_f32 %0, %1, %2" : "=v"(r) : "v"(a), "v"(b));
    return r;
}

#define GLOAD16(g, l) __builtin_amdgcn_global_load_lds( \
    (const __attribute__((address_space(1))) unsigned int*)(const void*)(g), \
    (__attribute__((address_space(3))) unsigned int*)(l), 16, 0, 0)

// ---------------- block reduce helpers ----------------
__device__ __forceinline__ float block_sum(float v, float* red) {
    #pragma unroll
    for (int o = 32; o; o >>= 1) v += __shfl_down(v, o, 64);
    int wid = threadIdx.x >> 6;
    __syncthreads();
    if ((threadIdx.x & 63) == 0) red[wid] = v;
    __syncthreads();
    return red[0] + red[1] + red[2] + red[3];
}
__device__ __forceinline__ float block_max(float v, float* red) {
    #pragma unroll
    for (int o = 32; o; o >>= 1) v = fmaxf(v, __shfl_down(v, o, 64));
    int wid = threadIdx.x >> 6;
    __syncthreads();
    if ((threadIdx.x & 63) == 0) red[wid] = v;
    __syncthreads();
    return fmaxf(fmaxf(red[0], red[1]), fmaxf(red[2], red[3]));
}

// ---------------- convert fp32 -> bf16 (x input) ----------------
__global__ __launch_bounds__(256) void cvt_kernel(const float* __restrict__ in,
                                                  short* __restrict__ out, int n4) {
    int i = blockIdx.x * 256 + threadIdx.x;
    if (i >= n4) return;
    f4v v = *(const f4v*)(in + (size_t)i * 4);
    s4v o;
    o[0] = f2b(v[0]); o[1] = f2b(v[1]); o[2] = f2b(v[2]); o[3] = f2b(v[3]);
    *(s4v*)(out + (size_t)i * 4) = o;
}

// ---------------- fused weight transpose+convert (all matrices, one launch) ----------------
struct WtDesc {
    const float* src[9];
    short* dst[9];
    int K[9], N[9], tb[9];
};
__global__ __launch_bounds__(256) void wtrans_all(WtDesc d) {
    __shared__ float s[32][33];
    const int bid = blockIdx.x;
    int si = 0;
    #pragma unroll
    for (int i = 1; i < 9; ++i) si = (bid >= d.tb[i]) ? i : si;
    const float* in = d.src[si];
    short* out = d.dst[si];
    const int K = d.K[si], N = d.N[si];
    const int lt = bid - d.tb[si];
    const int tn = N >> 5;
    const int bk = (lt / tn) * 32, bn = (lt % tn) * 32;
    const int c = threadIdx.x & 31, r8 = threadIdx.x >> 5;
    #pragma unroll
    for (int i = 0; i < 4; ++i) {
        int r = r8 + i * 8;
        s[r][c] = in[(size_t)(bk + r) * N + bn + c];
    }
    __syncthreads();
    #pragma unroll
    for (int i = 0; i < 4; ++i) {
        int r = r8 + i * 8;
        out[(size_t)(bn + r) * K + bk + c] = f2b(s[c][r]);
    }
}

// ---------------- bf16 MFMA GEMM: C[M,N] = A[M,K] @ BT[N,K]^T + bias ----------------
template<int RELU, int QSCALE>
__global__ __launch_bounds__(256) void gemm_mfma(const short* __restrict__ A,
                                                 const short* __restrict__ BT,
                                                 const float* __restrict__ bias,
                                                 short* __restrict__ C,
                                                 int M, int K, int N) {
    __shared__ __align__(16) short Alds[128 * 32];
    __shared__ __align__(16) short Blds[128 * 32];
    const int tid = threadIdx.x, lane = tid & 63, wid = tid >> 6;
    const int bm = blockIdx.y * 128, bn = blockIdx.x * 128;
    const int wr = wid >> 1, wc = wid & 1;
    f4v acc[4][4] = {};

    const int row0 = (wid * 2 + 0) * 16 + (lane >> 2);
    const int row1 = (wid * 2 + 1) * 16 + (lane >> 2);
    const int sc0 = ((lane & 3) ^ (row0 & 3)) * 8;
    const int sc1 = ((lane & 3) ^ (row1 & 3)) * 8;
    short* aldst0 = Alds + (wid * 2 + 0) * 512;
    short* aldst1 = Alds + (wid * 2 + 1) * 512;
    short* bldst0 = Blds + (wid * 2 + 0) * 512;
    short* bldst1 = Blds + (wid * 2 + 1) * 512;
    const short* aB = A + (size_t)bm * K;
    const short* bB = BT + (size_t)bn * K;

    const int frow = lane & 15, fs = lane >> 4;

    for (int k0 = 0; k0 < K; k0 += 32) {
        GLOAD16(aB + (size_t)row0 * K + k0 + sc0, aldst0);
        GLOAD16(aB + (size_t)row1 * K + k0 + sc1, aldst1);
        GLOAD16(bB + (size_t)row0 * K + k0 + sc0, bldst0);
        GLOAD16(bB + (size_t)row1 * K + k0 + sc1, bldst1);
        __syncthreads();
        s8v af[4], bf[4];
        #pragma unroll
        for (int m = 0; m < 4; ++m) {
            int row = wr * 64 + m * 16 + frow;
            af[m] = *(const s8v*)((const char*)Alds + row * 64 + ((fs ^ (row & 3)) * 16));
        }
        #pragma unroll
        for (int n = 0; n < 4; ++n) {
            int row = wc * 64 + n * 16 + frow;
            bf[n] = *(const s8v*)((const char*)Blds + row * 64 + ((fs ^ (row & 3)) * 16));
        }
        #pragma unroll
        for (int m = 0; m < 4; ++m)
            #pragma unroll
            for (int n = 0; n < 4; ++n)
                acc[m][n] = __builtin_amdgcn_mfma_f32_16x16x32_bf16(af[m], bf[n], acc[m][n], 0, 0, 0);
        __syncthreads();
    }
    #pragma unroll
    for (int m = 0; m < 4; ++m) {
        int rbase = bm + wr * 64 + m * 16 + (lane >> 4) * 4;
        #pragma unroll
        for (int n = 0; n < 4; ++n) {
            int col = bn + wc * 64 + n * 16 + (lane & 15);
            float bv = bias[col];
            #pragma unroll
            for (int r = 0; r < 4; ++r) {
                float v = acc[m][n][r] + bv;
                if (QSCALE) { if (col < 256) v *= 0.17677669529663687f; }
                if (RELU) v = fmaxf(v, 0.f);
                C[(size_t)(rbase + r) * N + col] = f2b(v);
            }
        }
    }
}

// ---------------- MFMA flash attention (swapped QK^T, in-register softmax) ----------------
__global__ __launch_bounds__(256) void attn_mfma(const short* __restrict__ qkv,
                                                 short* __restrict__ o) {
    __shared__ __align__(16) short Klds[2][4][64][8];
    __shared__ __align__(16) short Vlds[2][32][72];
    const int tid = threadIdx.x, lane = tid & 63, wid = tid >> 6;
    const int hi = lane >> 5, lq = lane & 31;
    const int qt = blockIdx.x & 7;
    const int h  = (blockIdx.x >> 3) & 7;
    const int b  = blockIdx.x >> 6;
    const int q0 = qt * 128 + wid * 32;
    const short* qkvb = qkv + (size_t)b * NN * 768;

    s8v qf0, qf1;
    {
        const short* qrow = qkvb + (size_t)(q0 + lq) * 768 + h * 32 + hi * 8;
        qf0 = *(const s8v*)qrow;
        qf1 = *(const s8v*)(qrow + 16);
    }

    const int token = tid & 63, cK = tid >> 6, dc = cK * 8;

    float m = -1e30f, l = 0.f;
    f16x acc = {};

    {
        const short* kvrow = qkvb + (size_t)token * 768 + 256 + h * 32;
        GLOAD16(kvrow + cK * 8, &Klds[0][cK][token][0]);
        s8v vv = *(const s8v*)(kvrow + 256 + dc);
        #pragma unroll
        for (int j = 0; j < 8; ++j) Vlds[0][dc + j][token] = vv[j];
    }
    __syncthreads();

    for (int t = 0; t < 16; ++t) {
        const int bb = t & 1;
        s8v vvn;
        if (t < 15) {
            const short* kvrow = qkvb + (size_t)((t + 1) * 64 + token) * 768 + 256 + h * 32;
            GLOAD16(kvrow + cK * 8, &Klds[bb ^ 1][cK][token][0]);
            vvn = *(const s8v*)(kvrow + 256 + dc);
        }
        #pragma unroll
        for (int kt = 0; kt < 2; ++kt) {
            const s8v kf0 = *(const s8v*)&Klds[bb][hi][kt * 32 + lq][0];
            const s8v kf1 = *(const s8v*)&Klds[bb][2 + hi][kt * 32 + lq][0];
            f16x p = {};
            p = __builtin_amdgcn_mfma_f32_32x32x16_bf16(kf0, qf0, p, 0, 0, 0);
            p = __builtin_amdgcn_mfma_f32_32x32x16_bf16(kf1, qf1, p, 0, 0, 0);
            float tmax = p[0];
            #pragma unroll
            for (int r = 1; r < 16; ++r) tmax = fmaxf(tmax, p[r]);
            tmax = fmaxf(tmax, __shfl_xor(tmax, 32));
            if (__any(tmax > m + 8.f)) {
                float mn = fmaxf(m, tmax);
                float f = __expf(m - mn);
                l *= f;
                #pragma unroll
                for (int r = 0; r < 16; ++r)
                    acc[r] *= __shfl(f, (r & 3) + 8 * (r >> 2) + 4 * hi);
                m = mn;
            }
            float ps = 0.f;
            #pragma unroll
            for (int r = 0; r < 16; ++r) { p[r] = __expf(p[r] - m); ps += p[r]; }
            l += ps;
            unsigned w[8];
            #pragma unroll
            for (int i = 0; i < 8; ++i) w[i] = cvtpk_bf16(p[2 * i], p[2 * i + 1]);
            asm volatile("v_permlane32_swap_b32 %0, %1" : "+v"(w[0]), "+v"(w[2]));
            asm volatile("v_permlane32_swap_b32 %0, %1" : "+v"(w[1]), "+v"(w[3]));
            asm volatile("v_permlane32_swap_b32 %0, %1" : "+v"(w[4]), "+v"(w[6]));
            asm volatile("v_permlane32_swap_b32 %0, %1" : "+v"(w[5]), "+v"(w[7]));
            union { unsigned u[4]; s8v v; } pa0, pa1;
            pa0.u[0] = w[0]; pa0.u[1] = w[1]; pa0.u[2] = w[2]; pa0.u[3] = w[3];
            pa1.u[0] = w[4]; pa1.u[1] = w[5]; pa1.u[2] = w[6]; pa1.u[3] = w[7];
            const s8v vf0 = *(const s8v*)&Vlds[bb][lq][kt * 32 + hi * 8];
            const s8v vf1 = *(const s8v*)&Vlds[bb][lq][kt * 32 + 16 + hi * 8];
            acc = __builtin_amdgcn_mfma_f32_32x32x16_bf16(pa0.v, vf0, acc, 0, 0, 0);
            acc = __builtin_amdgcn_mfma_f32_32x32x16_bf16(pa1.v, vf1, acc, 0, 0, 0);
        }
        if (t < 15) {
            #pragma unroll
            for (int j = 0; j < 8; ++j) Vlds[bb ^ 1][dc + j][token] = vvn[j];
        }
        __syncthreads();
    }

    l += __shfl_xor(l, 32);
    float inv = 1.f / l;
    short* ob = o + ((size_t)(b * NN + q0)) * HH + h * 32 + lq;
    #pragma unroll
    for (int r = 0; r < 16; ++r) {
        int qr = (r & 3) + 8 * (r >> 2) + 4 * hi;
        float invr = __shfl(inv, qr);
        ob[(size_t)qr * HH] = f2b(acc[r] * invr);
    }
}

// ---------------- residual + LayerNorm, wave-per-row (bf16 io) ----------------
__global__ __launch_bounds__(256) void ln_residual_kernel(short* __restrict__ hio,
                                                          const short* __restrict__ delta,
                                                          const float* __restrict__ g,
                                                          const float* __restrict__ bta) {
    const int w = threadIdx.x >> 6, lane = threadIdx.x & 63;
    const size_t row = (size_t)blockIdx.x * 4 + w;
    const int c0 = lane * 4;
    s4v hv = *(const s4v*)(hio + row * HH + c0);
    s4v dv = *(const s4v*)(delta + row * HH + c0);
    float v[4];
    float ps = 0.f;
    #pragma unroll
    for (int i = 0; i < 4; ++i) { v[i] = b2f(hv[i]) + b2f(dv[i]); ps += v[i]; }
    #pragma unroll
    for (int o = 32; o; o >>= 1) ps += __shfl_xor(ps, o);
    float mean = ps * (1.f / HH);
    float pv = 0.f;
    #pragma unroll
    for (int i = 0; i < 4; ++i) { v[i] -= mean; pv += v[i] * v[i]; }
    #pragma unroll
    for (int o = 32; o; o >>= 1) pv += __shfl_xor(pv, o);
    float rs = rsqrtf(pv * (1.f / HH) + 1e-5f);
    const f4v gv = *(const f4v*)(g + c0);
    const f4v bv = *(const f4v*)(bta + c0);
    s4v ov;
    #pragma unroll
    for (int i = 0; i < 4; ++i) ov[i] = f2b(v[i] * rs * gv[i] + bv[i]);
    *(s4v*)(hio + row * HH + c0) = ov;
}

// ---------------- allocation, stage A: partial gather-means ----------------
// grid: BB*16 blocks; block (b,s) sums 32 selected rows over all 256 cols.
__global__ __launch_bounds__(256) void alloc_mean_part(const short* __restrict__ enc,
                                                       const int* __restrict__ idx,
                                                       float* __restrict__ psum) {
    __shared__ int ids[32];
    const int b = blockIdx.x >> 4, s = blockIdx.x & 15;
    const int t = threadIdx.x;
    if (t < 32) ids[t] = idx[b * KSEL + s * 32 + t];
    __syncthreads();
    float sum = 0.f;
    #pragma unroll
    for (int i = 0; i < 32; ++i) {
        int id = ids[i];                 // wave-uniform -> uniform branch
        if (id < NN) sum += b2f(enc[(size_t)(b * NN + id) * HH + t]);
    }
    psum[(size_t)blockIdx.x * HH + t] = sum;
}

// ---------------- allocation, stage B: mean reduce + count + ctx GEMV ----------------
__global__ __launch_bounds__(256) void alloc_ctx(const float* __restrict__ psum,
                                                 const int* __restrict__ idx,
                                                 const float* __restrict__ Wc,
                                                 const float* __restrict__ bc,
                                                 float* __restrict__ ctxg) {
    __shared__ float mean_s[HH];
    __shared__ float red[4];
    const int b = blockIdx.x, t = threadIdx.x;
    int i0 = idx[b * KSEL + t], i1 = idx[b * KSEL + 256 + t];
    float c = (i0 < NN ? 1.f : 0.f) + (i1 < NN ? 1.f : 0.f);
    float cnt = fmaxf(block_sum(c, red), 1.f);
    float s = 0.f;
    #pragma unroll
    for (int p = 0; p < 16; ++p) s += psum[(size_t)(b * 16 + p) * HH + t];
    mean_s[t] = s / cnt;
    __syncthreads();
    float cv = bc[t];
    #pragma unroll 8
    for (int j = 0; j < HH; ++j) cv = fmaf(mean_s[j], Wc[(size_t)j * HH + t], cv);
    ctxg[b * HH + t] = cv;
}

// ---------------- allocation, stage C: per-index scores (wave per k) ----------------
// grid: BB*8 blocks; wave w of block (b,s) computes 16 scores.
__global__ __launch_bounds__(256) void alloc_scores(const short* __restrict__ enc,
                                                    const int* __restrict__ idx,
                                                    const float* __restrict__ ctxg,
                                                    float* __restrict__ scores) {
    const int b = blockIdx.x >> 3, s = blockIdx.x & 7;
    const int t = threadIdx.x, lane = t & 63, w = t >> 6;
    const f4v cv = *(const f4v*)(ctxg + b * HH + lane * 4);
    #pragma unroll 4
    for (int i = 0; i < 16; ++i) {
        int k = s * 64 + w * 16 + i;
        int id = idx[b * KSEL + k];
        float sc = -1e9f;
        if (id < NN) {
            s4v v = *(const s4v*)(enc + (size_t)(b * NN + id) * HH + lane * 4);
            float p = cv[0] * b2f(v[0]) + cv[1] * b2f(v[1]) + cv[2] * b2f(v[2]) + cv[3] * b2f(v[3]);
            #pragma unroll
            for (int o = 32; o; o >>= 1) p += __shfl_xor(p, o);
            sc = p;
        }
        if (lane == 0) scores[b * KSEL + k] = sc;
    }
}

// ---------------- allocation, stage D: softmax + round + fix + scatter ----------------
__global__ __launch_bounds__(256) void alloc_final(const int* __restrict__ idx,
                                                   const float* __restrict__ scores,
                                                   float* __restrict__ out) {
    __shared__ float alloc_s[KSEL];
    __shared__ float red[4];
    __shared__ float diff_s;
    const int b = blockIdx.x, t = threadIdx.x;
    int i0 = idx[b * KSEL + t], i1 = idx[b * KSEL + 256 + t];
    float s0 = scores[b * KSEL + t], s1 = scores[b * KSEL + 256 + t];
    float smax = block_max(fmaxf(s0, s1), red);
    float e0 = (i0 < NN) ? __expf(s0 - smax) : 0.f;
    float e1 = (i1 < NN) ? __expf(s1 - smax) : 0.f;
    float ssum = block_sum(e0 + e1, red);
    float inv = 100.f / ssum;
    float a0 = rintf(e0 * inv);
    float a1 = rintf(e1 * inv);
    alloc_s[t] = a0;
    alloc_s[t + 256] = a1;
    float asum = block_sum(a0 + a1, red);
    if (t == 0) diff_s = 100.f - asum;
    __syncthreads();
    if (t == 0 && i0 < NN) alloc_s[0] += diff_s;   // idx[b][0] always valid (len >= K/2)
    __syncthreads();

    float* bw = out + BB * KSEL + (size_t)b * NN;
    #pragma unroll
    for (int n = t; n < NN; n += 256) bw[n] = 0.f;
    __syncthreads();
    out[b * KSEL + t] = (float)i0;
    out[b * KSEL + 256 + t] = (float)i1;
    if (i0 < NN) bw[i0] = alloc_s[t];
    if (i1 < NN) bw[i1] = alloc_s[t + 256];
}

// ---------------- launch ----------------
extern "C" void kernel_launch(void* const* d_in, const int* in_sizes, int n_in,
                              void* d_out, int out_size, void* d_ws, size_t ws_size,
                              hipStream_t stream) {
    const float* x     = (const float*)d_in[0];
    const int*   sel   = (const int*)  d_in[1];
    const float* W_in  = (const float*)d_in[2];
    const float* b_in  = (const float*)d_in[3];
    const float* Wqkv  = (const float*)d_in[4];
    const float* bqkv  = (const float*)d_in[5];
    const float* Wo    = (const float*)d_in[6];
    const float* bo    = (const float*)d_in[7];
    const float* ln1_g = (const float*)d_in[8];
    const float* ln1_b = (const float*)d_in[9];
    const float* W1    = (const float*)d_in[10];
    const float* b1    = (const float*)d_in[11];
    const float* W2    = (const float*)d_in[12];
    const float* b2    = (const float*)d_in[13];
    const float* ln2_g = (const float*)d_in[14];
    const float* ln2_b = (const float*)d_in[15];
    const float* Wc    = (const float*)d_in[16];
    const float* bc    = (const float*)d_in[17];
    float* out = (float*)d_out;

    char* base = (char*)d_ws;
    short* h    = (short*)(base);                       // 8 MB
    short* qkv  = (short*)(base + (8u << 20));          // 24 MB
    short* obuf = (short*)(base + (32u << 20));         // 8 MB
    short* ff   = (short*)(base + (40u << 20));         // 32 MB (reused by alloc scratch)
    short* xb   = (short*)(base + (76u << 20));         // 2 MB
    short* wt   = (short*)(base + (78u << 20));         // ~3.1 MB
    short* W_inT  = wt;
    short* WqkvT  = W_inT + 256 * 64;
    short* WoT    = WqkvT + LL * 768 * 256;
    short* W1T    = WoT   + LL * 256 * 256;
    short* W2T    = W1T   + LL * 1024 * 256;

    // alloc-phase scratch overlays the ff region (free by then)
    float* psum   = (float*)(base + (40u << 20));       // 16*16*256 f32
    float* ctxg   = psum + BB * 16 * HH;                // 16*256 f32
    float* scores = ctxg + BB * HH;                     // 16*512 f32

    cvt_kernel<<<(MTOT * DIN / 4 + 255) / 256, 256, 0, stream>>>(x, xb, MTOT * DIN / 4);

    // fused weight transpose: 9 segments, 1552 tiles
    {
        WtDesc d;
        const float* srcs[9] = { W_in, Wqkv, Wqkv + (size_t)HH * 768, Wo, Wo + (size_t)HH * HH,
                                 W1, W1 + (size_t)HH * FFD, W2, W2 + (size_t)FFD * HH };
        short* dsts[9] = { W_inT, WqkvT, WqkvT + 768 * 256, WoT, WoT + 256 * 256,
                           W1T, W1T + 1024 * 256, W2T, W2T + 256 * 1024 };
        int Ks[9] = { 64, 256, 256, 256, 256, 256, 256, 1024, 1024 };
        int Ns[9] = { 256, 768, 768, 256, 256, 1024, 1024, 256, 256 };
        int tb = 0;
        for (int i = 0; i < 9; ++i) {
            d.src[i] = srcs[i]; d.dst[i] = dsts[i];
            d.K[i] = Ks[i]; d.N[i] = Ns[i]; d.tb[i] = tb;
            tb += (Ks[i] >> 5) * (Ns[i] >> 5);
        }
        wtrans_all<<<tb, 256, 0, stream>>>(d);
    }

    gemm_mfma<0,0><<<dim3(HH / 128, MTOT / 128), 256, 0, stream>>>(xb, W_inT, b_in, h, MTOT, DIN, HH);

    for (int l = 0; l < LL; ++l) {
        gemm_mfma<0,1><<<dim3(768 / 128, MTOT / 128), 256, 0, stream>>>(
            h, WqkvT + (size_t)l * 768 * HH, bqkv + l * 768, qkv, MTOT, HH, 768);
        attn_mfma<<<BB * NHEAD * 8, 256, 0, stream>>>(qkv, obuf);
        gemm_mfma<0,0><<<dim3(HH / 128, MTOT / 128), 256, 0, stream>>>(
            obuf, WoT + (size_t)l * HH * HH, bo + l * HH, qkv, MTOT, HH, HH);
        ln_residual_kernel<<<MTOT / 4, 256, 0, stream>>>(h, qkv, ln1_g + l * HH, ln1_b + l * HH);
        gemm_mfma<1,0><<<dim3(FFD / 128, MTOT / 128), 256, 0, stream>>>(
            h, W1T + (size_t)l * FFD * HH, b1 + l * FFD, ff, MTOT, HH, FFD);
        gemm_mfma<0,0><<<dim3(HH / 128, MTOT / 128), 256, 0, stream>>>(
            ff, W2T + (size_t)l * HH * FFD, b2 + l * HH, qkv, MTOT, FFD, HH);
        ln_residual_kernel<<<MTOT / 4, 256, 0, stream>>>(h, qkv, ln2_g + l * HH, ln2_b + l * HH);
    }

    alloc_mean_part<<<BB * 16, 256, 0, stream>>>(h, sel, psum);
    alloc_ctx<<<BB, 256, 0, stream>>>(psum, sel, Wc, bc, ctxg);
    alloc_scores<<<BB * 8, 256, 0, stream>>>(h, sel, ctxg, scores);
    alloc_final<<<BB, 256, 0, stream>>>(sel, scores, out);
}

// Round 5
// 400.370 us; speedup vs baseline: 6.5165x; 1.0219x over previous
//
#include <hip/hip_runtime.h>
#include <math.h>

#define BB 16
#define NN 1024
#define KSEL 512
#define DIN 64
#define HH 256
#define NHEAD 8
#define HD 32
#define LL 2
#define FFD 1024
#define MTOT (BB*NN)   // 16384

typedef __attribute__((ext_vector_type(8))) short s8v;   // 8 bf16
typedef __attribute__((ext_vector_type(4))) short s4v;
typedef __attribute__((ext_vector_type(4))) float f4v;
typedef __attribute__((ext_vector_type(16))) float f16x;

// 1/sqrt(32) * log2(e): QK^T scores land in log2 domain -> native exp2
#define QK_SCALE 0.25503485f

__device__ __forceinline__ float b2f(short u) {
    union { unsigned int i; float f; } v;
    v.i = ((unsigned int)(unsigned short)u) << 16;
    return v.f;
}
__device__ __forceinline__ short f2b(float f) {
    union { float f; unsigned int i; } v;
    v.f = f;
    unsigned int r = v.i + 0x7fffu + ((v.i >> 16) & 1u);
    return (short)(r >> 16);
}
__device__ __forceinline__ unsigned cvtpk_bf16(float a, float b) {
    unsigned r;
    asm("v_cvt_pk_bf16_f32 %0, %1, %2" : "=v"(r) : "v"(a), "v"(b));
    return r;
}

#define GLOAD16(g, l) __builtin_amdgcn_global_load_lds( \
    (const __attribute__((address_space(1))) unsigned int*)(const void*)(g), \
    (__attribute__((address_space(3))) unsigned int*)(l), 16, 0, 0)

// ---------------- block reduce helpers ----------------
__device__ __forceinline__ float block_sum(float v, float* red) {
    #pragma unroll
    for (int o = 32; o; o >>= 1) v += __shfl_down(v, o, 64);
    int wid = threadIdx.x >> 6;
    __syncthreads();
    if ((threadIdx.x & 63) == 0) red[wid] = v;
    __syncthreads();
    return red[0] + red[1] + red[2] + red[3];
}
__device__ __forceinline__ float block_max(float v, float* red) {
    #pragma unroll
    for (int o = 32; o; o >>= 1) v = fmaxf(v, __shfl_down(v, o, 64));
    int wid = threadIdx.x >> 6;
    __syncthreads();
    if ((threadIdx.x & 63) == 0) red[wid] = v;
    __syncthreads();
    return fmaxf(fmaxf(red[0], red[1]), fmaxf(red[2], red[3]));
}

// ---------------- convert fp32 -> bf16 (x input) ----------------
__global__ __launch_bounds__(256) void cvt_kernel(const float* __restrict__ in,
                                                  short* __restrict__ out, int n4) {
    int i = blockIdx.x * 256 + threadIdx.x;
    if (i >= n4) return;
    f4v v = *(const f4v*)(in + (size_t)i * 4);
    s4v o;
    o[0] = f2b(v[0]); o[1] = f2b(v[1]); o[2] = f2b(v[2]); o[3] = f2b(v[3]);
    *(s4v*)(out + (size_t)i * 4) = o;
}

// ---------------- fused weight transpose+convert (all matrices, one launch) ----------------
struct WtDesc {
    const float* src[9];
    short* dst[9];
    int K[9], N[9], tb[9];
};
__global__ __launch_bounds__(256) void wtrans_all(WtDesc d) {
    __shared__ float s[32][33];
    const int bid = blockIdx.x;
    int si = 0;
    #pragma unroll
    for (int i = 1; i < 9; ++i) si = (bid >= d.tb[i]) ? i : si;
    const float* in = d.src[si];
    short* out = d.dst[si];
    const int K = d.K[si], N = d.N[si];
    const int lt = bid - d.tb[si];
    const int tn = N >> 5;
    const int bk = (lt / tn) * 32, bn = (lt % tn) * 32;
    const int c = threadIdx.x & 31, r8 = threadIdx.x >> 5;
    #pragma unroll
    for (int i = 0; i < 4; ++i) {
        int r = r8 + i * 8;
        s[r][c] = in[(size_t)(bk + r) * N + bn + c];
    }
    __syncthreads();
    #pragma unroll
    for (int i = 0; i < 4; ++i) {
        int r = r8 + i * 8;
        out[(size_t)(bn + r) * K + bk + c] = f2b(s[c][r]);
    }
}

// ---------------- bf16 MFMA GEMM: C[M,N] = A[M,K] @ BT[N,K]^T + bias ----------------
// 128x128 tile, BK=64, 4 waves (2x2), 16x16x32 mfma, global_load_lds staging,
// 8-slot XOR swizzle, chunked XCD swizzle on 1D grid (grid % 8 == 0).
template<int RELU, int QSCALE>
__global__ __launch_bounds__(256) void gemm_mfma(const short* __restrict__ A,
                                                 const short* __restrict__ BT,
                                                 const float* __restrict__ bias,
                                                 short* __restrict__ C,
                                                 int M, int K, int N,
                                                 int nbx, int cpx) {
    __shared__ __align__(16) short Alds[128 * 64];
    __shared__ __align__(16) short Blds[128 * 64];
    const int tid = threadIdx.x, lane = tid & 63, wid = tid >> 6;
    const int wg = blockIdx.x;
    const int lid = (wg & 7) * cpx + (wg >> 3);
    const int bx = lid % nbx, by = lid / nbx;
    const int bm = by * 128, bn = bx * 128;
    const int wr = wid >> 1, wc = wid & 1;
    f4v acc[4][4] = {};

    const short* aB = A + (size_t)bm * K;
    const short* bB = BT + (size_t)bn * K;
    const int frow = lane & 15, fs = lane >> 4;

    // staging coords: round i stages chunk range [wid*64 + i*256, +64)
    int rrow[4], rsrc[4], rdst[4];
    #pragma unroll
    for (int i = 0; i < 4; ++i) {
        int cb = wid * 64 + i * 256;
        int c = cb + lane;
        rrow[i] = c >> 3;
        rsrc[i] = ((c & 7) ^ (rrow[i] & 7)) * 8;
        rdst[i] = cb * 8;   // short offset of chunk base (wave-uniform)
    }

    for (int k0 = 0; k0 < K; k0 += 64) {
        #pragma unroll
        for (int i = 0; i < 4; ++i)
            GLOAD16(aB + (size_t)rrow[i] * K + k0 + rsrc[i], Alds + rdst[i]);
        #pragma unroll
        for (int i = 0; i < 4; ++i)
            GLOAD16(bB + (size_t)rrow[i] * K + k0 + rsrc[i], Blds + rdst[i]);
        __syncthreads();
        #pragma unroll
        for (int kk = 0; kk < 2; ++kk) {
            s8v af[4], bf[4];
            #pragma unroll
            for (int m = 0; m < 4; ++m) {
                int row = wr * 64 + m * 16 + frow;
                af[m] = *(const s8v*)(Alds + row * 64 + (((kk * 4 + fs) ^ (row & 7)) * 8));
            }
            #pragma unroll
            for (int n = 0; n < 4; ++n) {
                int row = wc * 64 + n * 16 + frow;
                bf[n] = *(const s8v*)(Blds + row * 64 + (((kk * 4 + fs) ^ (row & 7)) * 8));
            }
            __builtin_amdgcn_s_setprio(1);
            #pragma unroll
            for (int m = 0; m < 4; ++m)
                #pragma unroll
                for (int n = 0; n < 4; ++n)
                    acc[m][n] = __builtin_amdgcn_mfma_f32_16x16x32_bf16(af[m], bf[n], acc[m][n], 0, 0, 0);
            __builtin_amdgcn_s_setprio(0);
        }
        __syncthreads();
    }
    #pragma unroll
    for (int m = 0; m < 4; ++m) {
        int rbase = bm + wr * 64 + m * 16 + (lane >> 4) * 4;
        #pragma unroll
        for (int n = 0; n < 4; ++n) {
            int col = bn + wc * 64 + n * 16 + (lane & 15);
            float bv = bias[col];
            #pragma unroll
            for (int r = 0; r < 4; ++r) {
                float v = acc[m][n][r] + bv;
                if (QSCALE) { if (col < 256) v *= QK_SCALE; }
                if (RELU) v = fmaxf(v, 0.f);
                C[(size_t)(rbase + r) * N + col] = f2b(v);
            }
        }
    }
}

// ---------------- MFMA flash attention (swapped QK^T, in-register softmax) ----------------
// 512 thr = 8 waves; wave w: 32 q rows; block covers q-tile of 256 -> K/V staged once per 8 waves.
// Q pre-scaled by log2(e)/sqrt(HD): softmax in exp2 domain.
__global__ __launch_bounds__(512) void attn_mfma(const short* __restrict__ qkv,
                                                 short* __restrict__ o) {
    __shared__ __align__(16) short Klds[2][4][64][8];   // [buf][hd-chunk][token][8hd]
    __shared__ __align__(16) short Vlds[2][32][72];     // [buf][d][token padded]
    const int tid = threadIdx.x, lane = tid & 63, wid = tid >> 6;
    const int hi = lane >> 5, lq = lane & 31;
    // chunked XCD swizzle: all 4 q-tiles of a (b,h) land on one XCD
    const int wg = blockIdx.x;
    const int lid = (wg & 7) * 64 + (wg >> 3);
    const int qt = lid & 3;
    const int h  = (lid >> 2) & 7;
    const int b  = lid >> 5;
    const int q0 = qt * 256 + wid * 32;
    const short* qkvb = qkv + (size_t)b * NN * 768;

    s8v qf0, qf1;
    {
        const short* qrow = qkvb + (size_t)(q0 + lq) * 768 + h * 32 + hi * 8;
        qf0 = *(const s8v*)qrow;
        qf1 = *(const s8v*)(qrow + 16);
    }

    const int token = tid & 63, cK = (tid >> 6) & 3, dc = cK * 8;
    const bool stager = tid < 256;

    float m = -1e30f, l = 0.f;
    f16x acc = {};

    if (stager) {
        const short* kvrow = qkvb + (size_t)token * 768 + 256 + h * 32;
        GLOAD16(kvrow + cK * 8, &Klds[0][cK][token][0]);
        s8v vv = *(const s8v*)(kvrow + 256 + dc);
        #pragma unroll
        for (int j = 0; j < 8; ++j) Vlds[0][dc + j][token] = vv[j];
    }
    __syncthreads();

    for (int t = 0; t < 16; ++t) {
        const int bb = t & 1;
        s8v vvn;
        if (t < 15 && stager) {
            const short* kvrow = qkvb + (size_t)((t + 1) * 64 + token) * 768 + 256 + h * 32;
            GLOAD16(kvrow + cK * 8, &Klds[bb ^ 1][cK][token][0]);
            vvn = *(const s8v*)(kvrow + 256 + dc);
        }
        #pragma unroll
        for (int kt = 0; kt < 2; ++kt) {
            const s8v kf0 = *(const s8v*)&Klds[bb][hi][kt * 32 + lq][0];
            const s8v kf1 = *(const s8v*)&Klds[bb][2 + hi][kt * 32 + lq][0];
            f16x p = {};
            __builtin_amdgcn_s_setprio(1);
            p = __builtin_amdgcn_mfma_f32_32x32x16_bf16(kf0, qf0, p, 0, 0, 0);
            p = __builtin_amdgcn_mfma_f32_32x32x16_bf16(kf1, qf1, p, 0, 0, 0);
            __builtin_amdgcn_s_setprio(0);
            // row max, tree (v_max3-friendly)
            float a0 = fmaxf(fmaxf(p[0], p[1]), fmaxf(p[2], p[3]));
            float a1 = fmaxf(fmaxf(p[4], p[5]), fmaxf(p[6], p[7]));
            float a2 = fmaxf(fmaxf(p[8], p[9]), fmaxf(p[10], p[11]));
            float a3 = fmaxf(fmaxf(p[12], p[13]), fmaxf(p[14], p[15]));
            float tmax = fmaxf(fmaxf(a0, a1), fmaxf(a2, a3));
            tmax = fmaxf(tmax, __shfl_xor(tmax, 32));
            if (__any(tmax > m + 8.f)) {        // defer-max (p bounded by 2^8)
                float mn = fmaxf(m, tmax);
                float f = exp2f(m - mn);
                l *= f;
                #pragma unroll
                for (int r = 0; r < 16; ++r)
                    acc[r] *= __shfl(f, (r & 3) + 8 * (r >> 2) + 4 * hi);
                m = mn;
            }
            float ps0 = 0.f, ps1 = 0.f, ps2 = 0.f, ps3 = 0.f;
            #pragma unroll
            for (int r = 0; r < 16; r += 4) {
                p[r]     = exp2f(p[r] - m);     ps0 += p[r];
                p[r + 1] = exp2f(p[r + 1] - m); ps1 += p[r + 1];
                p[r + 2] = exp2f(p[r + 2] - m); ps2 += p[r + 2];
                p[r + 3] = exp2f(p[r + 3] - m); ps3 += p[r + 3];
            }
            l += (ps0 + ps1) + (ps2 + ps3);
            unsigned w[8];
            #pragma unroll
            for (int i = 0; i < 8; ++i) w[i] = cvtpk_bf16(p[2 * i], p[2 * i + 1]);
            asm volatile("v_permlane32_swap_b32 %0, %1" : "+v"(w[0]), "+v"(w[2]));
            asm volatile("v_permlane32_swap_b32 %0, %1" : "+v"(w[1]), "+v"(w[3]));
            asm volatile("v_permlane32_swap_b32 %0, %1" : "+v"(w[4]), "+v"(w[6]));
            asm volatile("v_permlane32_swap_b32 %0, %1" : "+v"(w[5]), "+v"(w[7]));
            union { unsigned u[4]; s8v v; } pa0, pa1;
            pa0.u[0] = w[0]; pa0.u[1] = w[1]; pa0.u[2] = w[2]; pa0.u[3] = w[3];
            pa1.u[0] = w[4]; pa1.u[1] = w[5]; pa1.u[2] = w[6]; pa1.u[3] = w[7];
            const s8v vf0 = *(const s8v*)&Vlds[bb][lq][kt * 32 + hi * 8];
            const s8v vf1 = *(const s8v*)&Vlds[bb][lq][kt * 32 + 16 + hi * 8];
            __builtin_amdgcn_s_setprio(1);
            acc = __builtin_amdgcn_mfma_f32_32x32x16_bf16(pa0.v, vf0, acc, 0, 0, 0);
            acc = __builtin_amdgcn_mfma_f32_32x32x16_bf16(pa1.v, vf1, acc, 0, 0, 0);
            __builtin_amdgcn_s_setprio(0);
        }
        if (t < 15 && stager) {
            #pragma unroll
            for (int j = 0; j < 8; ++j) Vlds[bb ^ 1][dc + j][token] = vvn[j];
        }
        __syncthreads();
    }

    l += __shfl_xor(l, 32);
    float inv = 1.f / l;
    short* ob = o + ((size_t)(b * NN + q0)) * HH + h * 32 + lq;
    #pragma unroll
    for (int r = 0; r < 16; ++r) {
        int qr = (r & 3) + 8 * (r >> 2) + 4 * hi;
        float invr = __shfl(inv, qr);
        ob[(size_t)qr * HH] = f2b(acc[r] * invr);
    }
}

// ---------------- residual + LayerNorm, wave-per-row (bf16 io) ----------------
__global__ __launch_bounds__(256) void ln_residual_kernel(short* __restrict__ hio,
                                                          const short* __restrict__ delta,
                                                          const float* __restrict__ g,
                                                          const float* __restrict__ bta) {
    const int w = threadIdx.x >> 6, lane = threadIdx.x & 63;
    const size_t row = (size_t)blockIdx.x * 4 + w;
    const int c0 = lane * 4;
    s4v hv = *(const s4v*)(hio + row * HH + c0);
    s4v dv = *(const s4v*)(delta + row * HH + c0);
    float v[4];
    float ps = 0.f;
    #pragma unroll
    for (int i = 0; i < 4; ++i) { v[i] = b2f(hv[i]) + b2f(dv[i]); ps += v[i]; }
    #pragma unroll
    for (int o = 32; o; o >>= 1) ps += __shfl_xor(ps, o);
    float mean = ps * (1.f / HH);
    float pv = 0.f;
    #pragma unroll
    for (int i = 0; i < 4; ++i) { v[i] -= mean; pv += v[i] * v[i]; }
    #pragma unroll
    for (int o = 32; o; o >>= 1) pv += __shfl_xor(pv, o);
    float rs = rsqrtf(pv * (1.f / HH) + 1e-5f);
    const f4v gv = *(const f4v*)(g + c0);
    const f4v bv = *(const f4v*)(bta + c0);
    s4v ov;
    #pragma unroll
    for (int i = 0; i < 4; ++i) ov[i] = f2b(v[i] * rs * gv[i] + bv[i]);
    *(s4v*)(hio + row * HH + c0) = ov;
}

// ---------------- allocation, stage A: partial gather-means ----------------
__global__ __launch_bounds__(256) void alloc_mean_part(const short* __restrict__ enc,
                                                       const int* __restrict__ idx,
                                                       float* __restrict__ psum) {
    __shared__ int ids[32];
    const int b = blockIdx.x >> 4, s = blockIdx.x & 15;
    const int t = threadIdx.x;
    if (t < 32) ids[t] = idx[b * KSEL + s * 32 + t];
    __syncthreads();
    float sum = 0.f;
    #pragma unroll
    for (int i = 0; i < 32; ++i) {
        int id = ids[i];
        if (id < NN) sum += b2f(enc[(size_t)(b * NN + id) * HH + t]);
    }
    psum[(size_t)blockIdx.x * HH + t] = sum;
}

// ---------------- allocation, stage B: mean reduce + count + ctx GEMV ----------------
__global__ __launch_bounds__(256) void alloc_ctx(const float* __restrict__ psum,
                                                 const int* __restrict__ idx,
                                                 const float* __restrict__ Wc,
                                                 const float* __restrict__ bc,
                                                 float* __restrict__ ctxg) {
    __shared__ float mean_s[HH];
    __shared__ float red[4];
    const int b = blockIdx.x, t = threadIdx.x;
    int i0 = idx[b * KSEL + t], i1 = idx[b * KSEL + 256 + t];
    float c = (i0 < NN ? 1.f : 0.f) + (i1 < NN ? 1.f : 0.f);
    float cnt = fmaxf(block_sum(c, red), 1.f);
    float s = 0.f;
    #pragma unroll
    for (int p = 0; p < 16; ++p) s += psum[(size_t)(b * 16 + p) * HH + t];
    mean_s[t] = s / cnt;
    __syncthreads();
    float cv = bc[t];
    #pragma unroll 8
    for (int j = 0; j < HH; ++j) cv = fmaf(mean_s[j], Wc[(size_t)j * HH + t], cv);
    ctxg[b * HH + t] = cv;
}

// ---------------- allocation, stage C: per-index scores (wave per k) ----------------
__global__ __launch_bounds__(256) void alloc_scores(const short* __restrict__ enc,
                                                    const int* __restrict__ idx,
                                                    const float* __restrict__ ctxg,
                                                    float* __restrict__ scores) {
    const int b = blockIdx.x >> 3, s = blockIdx.x & 7;
    const int t = threadIdx.x, lane = t & 63, w = t >> 6;
    const f4v cv = *(const f4v*)(ctxg + b * HH + lane * 4);
    #pragma unroll 4
    for (int i = 0; i < 16; ++i) {
        int k = s * 64 + w * 16 + i;
        int id = idx[b * KSEL + k];
        float sc = -1e9f;
        if (id < NN) {
            s4v v = *(const s4v*)(enc + (size_t)(b * NN + id) * HH + lane * 4);
            float p = cv[0] * b2f(v[0]) + cv[1] * b2f(v[1]) + cv[2] * b2f(v[2]) + cv[3] * b2f(v[3]);
            #pragma unroll
            for (int o = 32; o; o >>= 1) p += __shfl_xor(p, o);
            sc = p;
        }
        if (lane == 0) scores[b * KSEL + k] = sc;
    }
}

// ---------------- allocation, stage D: softmax + round + fix + scatter ----------------
__global__ __launch_bounds__(256) void alloc_final(const int* __restrict__ idx,
                                                   const float* __restrict__ scores,
                                                   float* __restrict__ out) {
    __shared__ float alloc_s[KSEL];
    __shared__ float red[4];
    __shared__ float diff_s;
    const int b = blockIdx.x, t = threadIdx.x;
    int i0 = idx[b * KSEL + t], i1 = idx[b * KSEL + 256 + t];
    float s0 = scores[b * KSEL + t], s1 = scores[b * KSEL + 256 + t];
    float smax = block_max(fmaxf(s0, s1), red);
    float e0 = (i0 < NN) ? __expf(s0 - smax) : 0.f;
    float e1 = (i1 < NN) ? __expf(s1 - smax) : 0.f;
    float ssum = block_sum(e0 + e1, red);
    float inv = 100.f / ssum;
    float a0 = rintf(e0 * inv);
    float a1 = rintf(e1 * inv);
    alloc_s[t] = a0;
    alloc_s[t + 256] = a1;
    float asum = block_sum(a0 + a1, red);
    if (t == 0) diff_s = 100.f - asum;
    __syncthreads();
    if (t == 0 && i0 < NN) alloc_s[0] += diff_s;   // idx[b][0] always valid (len >= K/2)
    __syncthreads();

    float* bw = out + BB * KSEL + (size_t)b * NN;
    #pragma unroll
    for (int n = t; n < NN; n += 256) bw[n] = 0.f;
    __syncthreads();
    out[b * KSEL + t] = (float)i0;
    out[b * KSEL + 256 + t] = (float)i1;
    if (i0 < NN) bw[i0] = alloc_s[t];
    if (i1 < NN) bw[i1] = alloc_s[t + 256];
}

// ---------------- launch ----------------
extern "C" void kernel_launch(void* const* d_in, const int* in_sizes, int n_in,
                              void* d_out, int out_size, void* d_ws, size_t ws_size,
                              hipStream_t stream) {
    const float* x     = (const float*)d_in[0];
    const int*   sel   = (const int*)  d_in[1];
    const float* W_in  = (const float*)d_in[2];
    const float* b_in  = (const float*)d_in[3];
    const float* Wqkv  = (const float*)d_in[4];
    const float* bqkv  = (const float*)d_in[5];
    const float* Wo    = (const float*)d_in[6];
    const float* bo    = (const float*)d_in[7];
    const float* ln1_g = (const float*)d_in[8];
    const float* ln1_b = (const float*)d_in[9];
    const float* W1    = (const float*)d_in[10];
    const float* b1    = (const float*)d_in[11];
    const float* W2    = (const float*)d_in[12];
    const float* b2    = (const float*)d_in[13];
    const float* ln2_g = (const float*)d_in[14];
    const float* ln2_b = (const float*)d_in[15];
    const float* Wc    = (const float*)d_in[16];
    const float* bc    = (const float*)d_in[17];
    float* out = (float*)d_out;

    char* base = (char*)d_ws;
    short* h    = (short*)(base);                       // 8 MB
    short* qkv  = (short*)(base + (8u << 20));          // 24 MB
    short* obuf = (short*)(base + (32u << 20));         // 8 MB
    short* ff   = (short*)(base + (40u << 20));         // 32 MB (reused by alloc scratch)
    short* xb   = (short*)(base + (76u << 20));         // 2 MB
    short* wt   = (short*)(base + (78u << 20));         // ~3.1 MB
    short* W_inT  = wt;
    short* WqkvT  = W_inT + 256 * 64;
    short* WoT    = WqkvT + LL * 768 * 256;
    short* W1T    = WoT   + LL * 256 * 256;
    short* W2T    = W1T   + LL * 1024 * 256;

    float* psum   = (float*)(base + (40u << 20));       // 16*16*256 f32
    float* ctxg   = psum + BB * 16 * HH;                // 16*256 f32
    float* scores = ctxg + BB * HH;                     // 16*512 f32

    cvt_kernel<<<(MTOT * DIN / 4 + 255) / 256, 256, 0, stream>>>(x, xb, MTOT * DIN / 4);

    {
        WtDesc d;
        const float* srcs[9] = { W_in, Wqkv, Wqkv + (size_t)HH * 768, Wo, Wo + (size_t)HH * HH,
                                 W1, W1 + (size_t)HH * FFD, W2, W2 + (size_t)FFD * HH };
        short* dsts[9] = { W_inT, WqkvT, WqkvT + 768 * 256, WoT, WoT + 256 * 256,
                           W1T, W1T + 1024 * 256, W2T, W2T + 256 * 1024 };
        int Ks[9] = { 64, 256, 256, 256, 256, 256, 256, 1024, 1024 };
        int Ns[9] = { 256, 768, 768, 256, 256, 1024, 1024, 256, 256 };
        int tb = 0;
        for (int i = 0; i < 9; ++i) {
            d.src[i] = srcs[i]; d.dst[i] = dsts[i];
            d.K[i] = Ks[i]; d.N[i] = Ns[i]; d.tb[i] = tb;
            tb += (Ks[i] >> 5) * (Ns[i] >> 5);
        }
        wtrans_all<<<tb, 256, 0, stream>>>(d);
    }

    // h = x @ W_in + b_in          grid 2*128=256
    gemm_mfma<0,0><<<256, 256, 0, stream>>>(xb, W_inT, b_in, h, MTOT, DIN, HH, 2, 32);

    for (int l = 0; l < LL; ++l) {
        // qkv projection; Q columns pre-scaled by log2(e)/sqrt(HD).  grid 6*128=768
        gemm_mfma<0,1><<<768, 256, 0, stream>>>(
            h, WqkvT + (size_t)l * 768 * HH, bqkv + l * 768, qkv, MTOT, HH, 768, 6, 96);
        attn_mfma<<<BB * NHEAD * 4, 512, 0, stream>>>(qkv, obuf);
        gemm_mfma<0,0><<<256, 256, 0, stream>>>(
            obuf, WoT + (size_t)l * HH * HH, bo + l * HH, qkv, MTOT, HH, HH, 2, 32);
        ln_residual_kernel<<<MTOT / 4, 256, 0, stream>>>(h, qkv, ln1_g + l * HH, ln1_b + l * HH);
        gemm_mfma<1,0><<<1024, 256, 0, stream>>>(
            h, W1T + (size_t)l * FFD * HH, b1 + l * FFD, ff, MTOT, HH, FFD, 8, 128);
        gemm_mfma<0,0><<<256, 256, 0, stream>>>(
            ff, W2T + (size_t)l * HH * FFD, b2 + l * HH, qkv, MTOT, FFD, HH, 2, 32);
        ln_residual_kernel<<<MTOT / 4, 256, 0, stream>>>(h, qkv, ln2_g + l * HH, ln2_b + l * HH);
    }

    alloc_mean_part<<<BB * 16, 256, 0, stream>>>(h, sel, psum);
    alloc_ctx<<<BB, 256, 0, stream>>>(psum, sel, Wc, bc, ctxg);
    alloc_scores<<<BB * 8, 256, 0, stream>>>(h, sel, ctxg, scores);
    alloc_final<<<BB, 256, 0, stream>>>(sel, scores, out);
}

// Round 7
// 353.578 us; speedup vs baseline: 7.3788x; 1.1323x over previous
//
#include <hip/hip_runtime.h>
#include <math.h>

#define BB 16
#define NN 1024
#define KSEL 512
#define DIN 64
#define HH 256
#define NHEAD 8
#define HD 32
#define LL 2
#define FFD 1024
#define MTOT (BB*NN)   // 16384

typedef __attribute__((ext_vector_type(8))) short s8v;   // 8 bf16
typedef __attribute__((ext_vector_type(4))) short s4v;
typedef __attribute__((ext_vector_type(4))) float f4v;
typedef __attribute__((ext_vector_type(16))) float f16x;

// 1/sqrt(32) * log2(e): QK^T scores land in log2 domain -> native exp2
#define QK_SCALE 0.25503485f

__device__ __forceinline__ float b2f(short u) {
    union { unsigned int i; float f; } v;
    v.i = ((unsigned int)(unsigned short)u) << 16;
    return v.f;
}
__device__ __forceinline__ short f2b(float f) {
    union { float f; unsigned int i; } v;
    v.f = f;
    unsigned int r = v.i + 0x7fffu + ((v.i >> 16) & 1u);
    return (short)(r >> 16);
}
__device__ __forceinline__ unsigned cvtpk_bf16(float a, float b) {
    unsigned r;
    asm("v_cvt_pk_bf16_f32 %0, %1, %2" : "=v"(r) : "v"(a), "v"(b));
    return r;
}

#define GLOAD16(g, l) __builtin_amdgcn_global_load_lds( \
    (const __attribute__((address_space(1))) unsigned int*)(const void*)(g), \
    (__attribute__((address_space(3))) unsigned int*)(l), 16, 0, 0)

// ---------------- block reduce helpers ----------------
__device__ __forceinline__ float block_sum(float v, float* red) {
    #pragma unroll
    for (int o = 32; o; o >>= 1) v += __shfl_down(v, o, 64);
    int wid = threadIdx.x >> 6;
    __syncthreads();
    if ((threadIdx.x & 63) == 0) red[wid] = v;
    __syncthreads();
    return red[0] + red[1] + red[2] + red[3];
}
__device__ __forceinline__ float block_max(float v, float* red) {
    #pragma unroll
    for (int o = 32; o; o >>= 1) v = fmaxf(v, __shfl_down(v, o, 64));
    int wid = threadIdx.x >> 6;
    __syncthreads();
    if ((threadIdx.x & 63) == 0) red[wid] = v;
    __syncthreads();
    return fmaxf(fmaxf(red[0], red[1]), fmaxf(red[2], red[3]));
}

// ---------------- convert fp32 -> bf16 (x input) ----------------
__global__ __launch_bounds__(256) void cvt_kernel(const float* __restrict__ in,
                                                  short* __restrict__ out, int n4) {
    int i = blockIdx.x * 256 + threadIdx.x;
    if (i >= n4) return;
    f4v v = *(const f4v*)(in + (size_t)i * 4);
    s4v o;
    o[0] = f2b(v[0]); o[1] = f2b(v[1]); o[2] = f2b(v[2]); o[3] = f2b(v[3]);
    *(s4v*)(out + (size_t)i * 4) = o;
}

// ---------------- fused weight transpose+convert (all matrices, one launch) ----------------
struct WtDesc {
    const float* src[9];
    short* dst[9];
    int K[9], N[9], tb[9];
};
__global__ __launch_bounds__(256) void wtrans_all(WtDesc d) {
    __shared__ float s[32][33];
    const int bid = blockIdx.x;
    int si = 0;
    #pragma unroll
    for (int i = 1; i < 9; ++i) si = (bid >= d.tb[i]) ? i : si;
    const float* in = d.src[si];
    short* out = d.dst[si];
    const int K = d.K[si], N = d.N[si];
    const int lt = bid - d.tb[si];
    const int tn = N >> 5;
    const int bk = (lt / tn) * 32, bn = (lt % tn) * 32;
    const int c = threadIdx.x & 31, r8 = threadIdx.x >> 5;
    #pragma unroll
    for (int i = 0; i < 4; ++i) {
        int r = r8 + i * 8;
        s[r][c] = in[(size_t)(bk + r) * N + bn + c];
    }
    __syncthreads();
    #pragma unroll
    for (int i = 0; i < 4; ++i) {
        int r = r8 + i * 8;
        out[(size_t)(bn + r) * K + bk + c] = f2b(s[c][r]);
    }
}

// ---------------- bf16 MFMA GEMM: C[M,N] = A[M,K] @ BT[N,K]^T + bias ----------------
// 128xBN tile (BN = 64 or 128), BK=64, 4 waves (2x2), 16x16x32 mfma,
// global_load_lds staging, 8-slot XOR swizzle, chunked XCD swizzle (grid % 8 == 0).
template<int BN, int RELU, int QSCALE>
__global__ __launch_bounds__(256) void gemm_mfma(const short* __restrict__ A,
                                                 const short* __restrict__ BT,
                                                 const float* __restrict__ bias,
                                                 short* __restrict__ C,
                                                 int M, int K, int N,
                                                 int nbx, int cpx) {
    __shared__ __align__(16) short Alds[128 * 64];
    __shared__ __align__(16) short Blds[BN * 64];
    const int tid = threadIdx.x, lane = tid & 63, wid = tid >> 6;
    const int wg = blockIdx.x;
    const int lid = (wg & 7) * cpx + (wg >> 3);
    const int bx = lid % nbx, by = lid / nbx;
    const int bm = by * 128, bn = bx * BN;
    const int wr = wid >> 1, wc = wid & 1;
    const int NF = BN / 32;
    f4v acc[4][NF] = {};

    const short* aB = A + (size_t)bm * K;
    const short* bB = BT + (size_t)bn * K;
    const int frow = lane & 15, fs = lane >> 4;

    for (int k0 = 0; k0 < K; k0 += 64) {
        #pragma unroll
        for (int i = 0; i < 4; ++i) {
            int cb = wid * 64 + i * 256;
            int c = cb + lane;
            int row = c >> 3;
            GLOAD16(aB + (size_t)row * K + k0 + (((c & 7) ^ (row & 7)) * 8), Alds + cb * 8);
        }
        #pragma unroll
        for (int i = 0; i < NF; ++i) {
            int cb = wid * 64 + i * 256;
            int c = cb + lane;
            int row = c >> 3;
            GLOAD16(bB + (size_t)row * K + k0 + (((c & 7) ^ (row & 7)) * 8), Blds + cb * 8);
        }
        __syncthreads();
        #pragma unroll
        for (int kk = 0; kk < 2; ++kk) {
            s8v af[4], bf[NF];
            #pragma unroll
            for (int m = 0; m < 4; ++m) {
                int row = wr * 64 + m * 16 + frow;
                af[m] = *(const s8v*)(Alds + row * 64 + (((kk * 4 + fs) ^ (row & 7)) * 8));
            }
            #pragma unroll
            for (int n = 0; n < NF; ++n) {
                int row = wc * (BN / 2) + n * 16 + frow;
                bf[n] = *(const s8v*)(Blds + row * 64 + (((kk * 4 + fs) ^ (row & 7)) * 8));
            }
            __builtin_amdgcn_s_setprio(1);
            #pragma unroll
            for (int m = 0; m < 4; ++m)
                #pragma unroll
                for (int n = 0; n < NF; ++n)
                    acc[m][n] = __builtin_amdgcn_mfma_f32_16x16x32_bf16(af[m], bf[n], acc[m][n], 0, 0, 0);
            __builtin_amdgcn_s_setprio(0);
        }
        __syncthreads();
    }
    #pragma unroll
    for (int m = 0; m < 4; ++m) {
        int rbase = bm + wr * 64 + m * 16 + (lane >> 4) * 4;
        #pragma unroll
        for (int n = 0; n < NF; ++n) {
            int col = bn + wc * (BN / 2) + n * 16 + (lane & 15);
            float bv = bias[col];
            #pragma unroll
            for (int r = 0; r < 4; ++r) {
                float v = acc[m][n][r] + bv;
                if (QSCALE) { if (col < 256) v *= QK_SCALE; }
                if (RELU) v = fmaxf(v, 0.f);
                C[(size_t)(rbase + r) * N + col] = f2b(v);
            }
        }
    }
}

// ---------------- MFMA flash attention (swapped QK^T, no-max softmax) ----------------
// 512 thr = 8 waves; wave w: 32 q rows; q-tile 256; KV tile 128 tokens, double-buffered.
// Q pre-scaled by log2(e)/sqrt(HD) -> scores in log2 domain, |s| <~ 5 for LN'd
// activations, so p = exp2(s) directly (softmax is shift-invariant; fp32 exp2
// safe to s=127). Kills max-tree / defer-branch / rescale / subtract.
__global__ __launch_bounds__(512) void attn_mfma(const short* __restrict__ qkv,
                                                 short* __restrict__ o) {
    __shared__ __align__(16) short Klds[2][4][128][8];   // [buf][hd-chunk][token][8hd]
    __shared__ __align__(16) short Vlds[2][32][136];     // [buf][d][token padded, 16B-aligned]
    const int tid = threadIdx.x, lane = tid & 63, wid = tid >> 6;
    const int hi = lane >> 5, lq = lane & 31;
    const int wg = blockIdx.x;
    const int lid = (wg & 7) * 64 + (wg >> 3);   // chunked XCD swizzle
    const int qt = lid & 3;
    const int h  = (lid >> 2) & 7;
    const int b  = lid >> 5;
    const int q0 = qt * 256 + wid * 32;
    const short* qkvb = qkv + (size_t)b * NN * 768;

    s8v qf0, qf1;
    {
        const short* qrow = qkvb + (size_t)(q0 + lq) * 768 + h * 32 + hi * 8;
        qf0 = *(const s8v*)qrow;
        qf1 = *(const s8v*)(qrow + 16);
    }

    const int token = tid & 127, cK = tid >> 7, dc = cK * 8;
    const f16x fz = {};

    float l = 0.f;
    f16x acc = {};

    {   // prologue: stage tile 0
        const short* kvrow = qkvb + (size_t)token * 768 + 256 + h * 32;
        GLOAD16(kvrow + cK * 8, &Klds[0][cK][token][0]);
        s8v vv = *(const s8v*)(kvrow + 256 + dc);
        #pragma unroll
        for (int j = 0; j < 8; ++j) Vlds[0][dc + j][token] = vv[j];
    }
    __syncthreads();

    for (int t = 0; t < 8; ++t) {
        const int bb = t & 1;
        s8v vvn;
        if (t < 7) {
            const short* kvrow = qkvb + (size_t)((t + 1) * 128 + token) * 768 + 256 + h * 32;
            GLOAD16(kvrow + cK * 8, &Klds[bb ^ 1][cK][token][0]);
            vvn = *(const s8v*)(kvrow + 256 + dc);
        }
        #pragma unroll
        for (int kt = 0; kt < 4; ++kt) {
            const s8v kf0 = *(const s8v*)&Klds[bb][hi][kt * 32 + lq][0];
            const s8v kf1 = *(const s8v*)&Klds[bb][2 + hi][kt * 32 + lq][0];
            __builtin_amdgcn_s_setprio(1);
            f16x p = __builtin_amdgcn_mfma_f32_32x32x16_bf16(kf0, qf0, fz, 0, 0, 0);
            p = __builtin_amdgcn_mfma_f32_32x32x16_bf16(kf1, qf1, p, 0, 0, 0);
            __builtin_amdgcn_s_setprio(0);
            float l0 = 0.f, l1 = 0.f, l2 = 0.f, l3 = 0.f;
            #pragma unroll
            for (int r = 0; r < 16; r += 4) {
                p[r]     = __builtin_amdgcn_exp2f(p[r]);     l0 += p[r];
                p[r + 1] = __builtin_amdgcn_exp2f(p[r + 1]); l1 += p[r + 1];
                p[r + 2] = __builtin_amdgcn_exp2f(p[r + 2]); l2 += p[r + 2];
                p[r + 3] = __builtin_amdgcn_exp2f(p[r + 3]); l3 += p[r + 3];
            }
            l += (l0 + l1) + (l2 + l3);
            unsigned w[8];
            #pragma unroll
            for (int i = 0; i < 8; ++i) w[i] = cvtpk_bf16(p[2 * i], p[2 * i + 1]);
            asm volatile("v_permlane32_swap_b32 %0, %1" : "+v"(w[0]), "+v"(w[2]));
            asm volatile("v_permlane32_swap_b32 %0, %1" : "+v"(w[1]), "+v"(w[3]));
            asm volatile("v_permlane32_swap_b32 %0, %1" : "+v"(w[4]), "+v"(w[6]));
            asm volatile("v_permlane32_swap_b32 %0, %1" : "+v"(w[5]), "+v"(w[7]));
            union { unsigned u[4]; s8v v; } pa0, pa1;
            pa0.u[0] = w[0]; pa0.u[1] = w[1]; pa0.u[2] = w[2]; pa0.u[3] = w[3];
            pa1.u[0] = w[4]; pa1.u[1] = w[5]; pa1.u[2] = w[6]; pa1.u[3] = w[7];
            const s8v vf0 = *(const s8v*)&Vlds[bb][lq][kt * 32 + hi * 8];
            const s8v vf1 = *(const s8v*)&Vlds[bb][lq][kt * 32 + 16 + hi * 8];
            __builtin_amdgcn_s_setprio(1);
            acc = __builtin_amdgcn_mfma_f32_32x32x16_bf16(pa0.v, vf0, acc, 0, 0, 0);
            acc = __builtin_amdgcn_mfma_f32_32x32x16_bf16(pa1.v, vf1, acc, 0, 0, 0);
            __builtin_amdgcn_s_setprio(0);
        }
        if (t < 7) {
            #pragma unroll
            for (int j = 0; j < 8; ++j) Vlds[bb ^ 1][dc + j][token] = vvn[j];
        }
        __syncthreads();
    }

    l += __shfl_xor(l, 32);
    float inv = 1.f / l;
    short* ob = o + ((size_t)(b * NN + q0)) * HH + h * 32 + lq;
    #pragma unroll
    for (int r = 0; r < 16; ++r) {
        int qr = (r & 3) + 8 * (r >> 2) + 4 * hi;
        float invr = __shfl(inv, qr);
        ob[(size_t)qr * HH] = f2b(acc[r] * invr);
    }
}

// ---------------- residual + LayerNorm, wave-per-row (bf16 io) ----------------
__global__ __launch_bounds__(256) void ln_residual_kernel(short* __restrict__ hio,
                                                          const short* __restrict__ delta,
                                                          const float* __restrict__ g,
                                                          const float* __restrict__ bta) {
    const int w = threadIdx.x >> 6, lane = threadIdx.x & 63;
    const size_t row = (size_t)blockIdx.x * 4 + w;
    const int c0 = lane * 4;
    s4v hv = *(const s4v*)(hio + row * HH + c0);
    s4v dv = *(const s4v*)(delta + row * HH + c0);
    float v[4];
    float ps = 0.f;
    #pragma unroll
    for (int i = 0; i < 4; ++i) { v[i] = b2f(hv[i]) + b2f(dv[i]); ps += v[i]; }
    #pragma unroll
    for (int o = 32; o; o >>= 1) ps += __shfl_xor(ps, o);
    float mean = ps * (1.f / HH);
    float pv = 0.f;
    #pragma unroll
    for (int i = 0; i < 4; ++i) { v[i] -= mean; pv += v[i] * v[i]; }
    #pragma unroll
    for (int o = 32; o; o >>= 1) pv += __shfl_xor(pv, o);
    float rs = rsqrtf(pv * (1.f / HH) + 1e-5f);
    const f4v gv = *(const f4v*)(g + c0);
    const f4v bv = *(const f4v*)(bta + c0);
    s4v ov;
    #pragma unroll
    for (int i = 0; i < 4; ++i) ov[i] = f2b(v[i] * rs * gv[i] + bv[i]);
    *(s4v*)(hio + row * HH + c0) = ov;
}

// ---------------- allocation, stage A: partial gather-means ----------------
__global__ __launch_bounds__(256) void alloc_mean_part(const short* __restrict__ enc,
                                                       const int* __restrict__ idx,
                                                       float* __restrict__ psum) {
    __shared__ int ids[32];
    const int b = blockIdx.x >> 4, s = blockIdx.x & 15;
    const int t = threadIdx.x;
    if (t < 32) ids[t] = idx[b * KSEL + s * 32 + t];
    __syncthreads();
    float sum = 0.f;
    #pragma unroll
    for (int i = 0; i < 32; ++i) {
        int id = ids[i];
        if (id < NN) sum += b2f(enc[(size_t)(b * NN + id) * HH + t]);
    }
    psum[(size_t)blockIdx.x * HH + t] = sum;
}

// ---------------- allocation, stage B: mean reduce + count + ctx GEMV ----------------
__global__ __launch_bounds__(256) void alloc_ctx(const float* __restrict__ psum,
                                                 const int* __restrict__ idx,
                                                 const float* __restrict__ Wc,
                                                 const float* __restrict__ bc,
                                                 float* __restrict__ ctxg) {
    __shared__ float mean_s[HH];
    __shared__ float red[4];
    const int b = blockIdx.x, t = threadIdx.x;
    int i0 = idx[b * KSEL + t], i1 = idx[b * KSEL + 256 + t];
    float c = (i0 < NN ? 1.f : 0.f) + (i1 < NN ? 1.f : 0.f);
    float cnt = fmaxf(block_sum(c, red), 1.f);
    float s = 0.f;
    #pragma unroll
    for (int p = 0; p < 16; ++p) s += psum[(size_t)(b * 16 + p) * HH + t];
    mean_s[t] = s / cnt;
    __syncthreads();
    float cv = bc[t];
    #pragma unroll 8
    for (int j = 0; j < HH; ++j) cv = fmaf(mean_s[j], Wc[(size_t)j * HH + t], cv);
    ctxg[b * HH + t] = cv;
}

// ---------------- allocation, stage C: per-index scores (wave per k) ----------------
__global__ __launch_bounds__(256) void alloc_scores(const short* __restrict__ enc,
                                                    const int* __restrict__ idx,
                                                    const float* __restrict__ ctxg,
                                                    float* __restrict__ scores) {
    const int b = blockIdx.x >> 3, s = blockIdx.x & 7;
    const int t = threadIdx.x, lane = t & 63, w = t >> 6;
    const f4v cv = *(const f4v*)(ctxg + b * HH + lane * 4);
    #pragma unroll 4
    for (int i = 0; i < 16; ++i) {
        int k = s * 64 + w * 16 + i;
        int id = idx[b * KSEL + k];
        float sc = -1e9f;
        if (id < NN) {
            s4v v = *(const s4v*)(enc + (size_t)(b * NN + id) * HH + lane * 4);
            float p = cv[0] * b2f(v[0]) + cv[1] * b2f(v[1]) + cv[2] * b2f(v[2]) + cv[3] * b2f(v[3]);
            #pragma unroll
            for (int o = 32; o; o >>= 1) p += __shfl_xor(p, o);
            sc = p;
        }
        if (lane == 0) scores[b * KSEL + k] = sc;
    }
}

// ---------------- allocation, stage D: softmax + round + fix + scatter ----------------
__global__ __launch_bounds__(256) void alloc_final(const int* __restrict__ idx,
                                                   const float* __restrict__ scores,
                                                   float* __restrict__ out) {
    __shared__ float alloc_s[KSEL];
    __shared__ float red[4];
    __shared__ float diff_s;
    const int b = blockIdx.x, t = threadIdx.x;
    int i0 = idx[b * KSEL + t], i1 = idx[b * KSEL + 256 + t];
    float s0 = scores[b * KSEL + t], s1 = scores[b * KSEL + 256 + t];
    float smax = block_max(fmaxf(s0, s1), red);
    float e0 = (i0 < NN) ? __expf(s0 - smax) : 0.f;
    float e1 = (i1 < NN) ? __expf(s1 - smax) : 0.f;
    float ssum = block_sum(e0 + e1, red);
    float inv = 100.f / ssum;
    float a0 = rintf(e0 * inv);
    float a1 = rintf(e1 * inv);
    alloc_s[t] = a0;
    alloc_s[t + 256] = a1;
    float asum = block_sum(a0 + a1, red);
    if (t == 0) diff_s = 100.f - asum;
    __syncthreads();
    if (t == 0 && i0 < NN) alloc_s[0] += diff_s;   // idx[b][0] always valid (len >= K/2)
    __syncthreads();

    float* bw = out + BB * KSEL + (size_t)b * NN;
    #pragma unroll
    for (int n = t; n < NN; n += 256) bw[n] = 0.f;
    __syncthreads();
    out[b * KSEL + t] = (float)i0;
    out[b * KSEL + 256 + t] = (float)i1;
    if (i0 < NN) bw[i0] = alloc_s[t];
    if (i1 < NN) bw[i1] = alloc_s[t + 256];
}

// ---------------- launch ----------------
extern "C" void kernel_launch(void* const* d_in, const int* in_sizes, int n_in,
                              void* d_out, int out_size, void* d_ws, size_t ws_size,
                              hipStream_t stream) {
    const float* x     = (const float*)d_in[0];
    const int*   sel   = (const int*)  d_in[1];
    const float* W_in  = (const float*)d_in[2];
    const float* b_in  = (const float*)d_in[3];
    const float* Wqkv  = (const float*)d_in[4];
    const float* bqkv  = (const float*)d_in[5];
    const float* Wo    = (const float*)d_in[6];
    const float* bo    = (const float*)d_in[7];
    const float* ln1_g = (const float*)d_in[8];
    const float* ln1_b = (const float*)d_in[9];
    const float* W1    = (const float*)d_in[10];
    const float* b1    = (const float*)d_in[11];
    const float* W2    = (const float*)d_in[12];
    const float* b2    = (const float*)d_in[13];
    const float* ln2_g = (const float*)d_in[14];
    const float* ln2_b = (const float*)d_in[15];
    const float* Wc    = (const float*)d_in[16];
    const float* bc    = (const float*)d_in[17];
    float* out = (float*)d_out;

    char* base = (char*)d_ws;
    short* h    = (short*)(base);                       // 8 MB
    short* qkv  = (short*)(base + (8u << 20));          // 24 MB
    short* obuf = (short*)(base + (32u << 20));         // 8 MB
    short* ff   = (short*)(base + (40u << 20));         // 32 MB (reused by alloc scratch)
    short* xb   = (short*)(base + (76u << 20));         // 2 MB
    short* wt   = (short*)(base + (78u << 20));         // ~3.1 MB
    short* W_inT  = wt;
    short* WqkvT  = W_inT + 256 * 64;
    short* WoT    = WqkvT + LL * 768 * 256;
    short* W1T    = WoT   + LL * 256 * 256;
    short* W2T    = W1T   + LL * 1024 * 256;

    float* psum   = (float*)(base + (40u << 20));       // 16*16*256 f32
    float* ctxg   = psum + BB * 16 * HH;                // 16*256 f32
    float* scores = ctxg + BB * HH;                     // 16*512 f32

    cvt_kernel<<<(MTOT * DIN / 4 + 255) / 256, 256, 0, stream>>>(x, xb, MTOT * DIN / 4);

    {
        WtDesc d;
        const float* srcs[9] = { W_in, Wqkv, Wqkv + (size_t)HH * 768, Wo, Wo + (size_t)HH * HH,
                                 W1, W1 + (size_t)HH * FFD, W2, W2 + (size_t)FFD * HH };
        short* dsts[9] = { W_inT, WqkvT, WqkvT + 768 * 256, WoT, WoT + 256 * 256,
                           W1T, W1T + 1024 * 256, W2T, W2T + 256 * 1024 };
        int Ks[9] = { 64, 256, 256, 256, 256, 256, 256, 1024, 1024 };
        int Ns[9] = { 256, 768, 768, 256, 256, 1024, 1024, 256, 256 };
        int tb = 0;
        for (int i = 0; i < 9; ++i) {
            d.src[i] = srcs[i]; d.dst[i] = dsts[i];
            d.K[i] = Ks[i]; d.N[i] = Ns[i]; d.tb[i] = tb;
            tb += (Ks[i] >> 5) * (Ns[i] >> 5);
        }
        wtrans_all<<<tb, 256, 0, stream>>>(d);
    }

    // h = x @ W_in + b_in     BN=64: grid 4*128=512
    gemm_mfma<64,0,0><<<512, 256, 0, stream>>>(xb, W_inT, b_in, h, MTOT, DIN, HH, 4, 64);

    for (int l = 0; l < LL; ++l) {
        // qkv projection; Q columns pre-scaled by log2(e)/sqrt(HD).  grid 6*128=768
        gemm_mfma<128,0,1><<<768, 256, 0, stream>>>(
            h, WqkvT + (size_t)l * 768 * HH, bqkv + l * 768, qkv, MTOT, HH, 768, 6, 96);
        attn_mfma<<<BB * NHEAD * 4, 512, 0, stream>>>(qkv, obuf);
        gemm_mfma<64,0,0><<<512, 256, 0, stream>>>(
            obuf, WoT + (size_t)l * HH * HH, bo + l * HH, qkv, MTOT, HH, HH, 4, 64);
        ln_residual_kernel<<<MTOT / 4, 256, 0, stream>>>(h, qkv, ln1_g + l * HH, ln1_b + l * HH);
        gemm_mfma<128,1,0><<<1024, 256, 0, stream>>>(
            h, W1T + (size_t)l * FFD * HH, b1 + l * FFD, ff, MTOT, HH, FFD, 8, 128);
        gemm_mfma<64,0,0><<<512, 256, 0, stream>>>(
            ff, W2T + (size_t)l * HH * FFD, b2 + l * HH, qkv, MTOT, FFD, HH, 4, 64);
        ln_residual_kernel<<<MTOT / 4, 256, 0, stream>>>(h, qkv, ln2_g + l * HH, ln2_b + l * HH);
    }

    alloc_mean_part<<<BB * 16, 256, 0, stream>>>(h, sel, psum);
    alloc_ctx<<<BB, 256, 0, stream>>>(psum, sel, Wc, bc, ctxg);
    alloc_scores<<<BB * 8, 256, 0, stream>>>(h, sel, ctxg, scores);
    alloc_final<<<BB, 256, 0, stream>>>(sel, scores, out);
}

// Round 8
// 329.066 us; speedup vs baseline: 7.9285x; 1.0745x over previous
//
#include <hip/hip_runtime.h>
#include <math.h>

#define BB 16
#define NN 1024
#define KSEL 512
#define DIN 64
#define HH 256
#define NHEAD 8
#define HD 32
#define LL 2
#define FFD 1024
#define MTOT (BB*NN)   // 16384

typedef __attribute__((ext_vector_type(8))) short s8v;   // 8 bf16
typedef __attribute__((ext_vector_type(4))) short s4v;
typedef __attribute__((ext_vector_type(4))) float f4v;
typedef __attribute__((ext_vector_type(16))) float f16x;

// 1/sqrt(32) * log2(e): QK^T scores land in log2 domain -> native exp2
#define QK_SCALE 0.25503485f

__device__ __forceinline__ float b2f(short u) {
    union { unsigned int i; float f; } v;
    v.i = ((unsigned int)(unsigned short)u) << 16;
    return v.f;
}
__device__ __forceinline__ short f2b(float f) {
    union { float f; unsigned int i; } v;
    v.f = f;
    unsigned int r = v.i + 0x7fffu + ((v.i >> 16) & 1u);
    return (short)(r >> 16);
}
__device__ __forceinline__ unsigned cvtpk_bf16(float a, float b) {
    unsigned r;
    asm("v_cvt_pk_bf16_f32 %0, %1, %2" : "=v"(r) : "v"(a), "v"(b));
    return r;
}

#define GLOAD16(g, l) __builtin_amdgcn_global_load_lds( \
    (const __attribute__((address_space(1))) unsigned int*)(const void*)(g), \
    (__attribute__((address_space(3))) unsigned int*)(l), 16, 0, 0)

// ---------------- fused weight transpose+convert + x-cvt (one launch) ----------------
struct WtDesc {
    const float* src[9];
    short* dst[9];
    int K[9], N[9], tb[9];
    const float* x;       // cvt source
    short* xb;            // cvt dest
    int cvt_tb;           // first cvt block
};
__global__ __launch_bounds__(256) void wtrans_all(WtDesc d) {
    __shared__ float s[32][33];
    const int bid = blockIdx.x;
    if (bid >= d.cvt_tb) {
        int i = (bid - d.cvt_tb) * 256 + threadIdx.x;   // 4-elem chunk index
        f4v v = *(const f4v*)(d.x + (size_t)i * 4);
        s4v o;
        o[0] = f2b(v[0]); o[1] = f2b(v[1]); o[2] = f2b(v[2]); o[3] = f2b(v[3]);
        *(s4v*)(d.xb + (size_t)i * 4) = o;
        return;
    }
    int si = 0;
    #pragma unroll
    for (int i = 1; i < 9; ++i) si = (bid >= d.tb[i]) ? i : si;
    const float* in = d.src[si];
    short* out = d.dst[si];
    const int K = d.K[si], N = d.N[si];
    const int lt = bid - d.tb[si];
    const int tn = N >> 5;
    const int bk = (lt / tn) * 32, bn = (lt % tn) * 32;
    const int c = threadIdx.x & 31, r8 = threadIdx.x >> 5;
    #pragma unroll
    for (int i = 0; i < 4; ++i) {
        int r = r8 + i * 8;
        s[r][c] = in[(size_t)(bk + r) * N + bn + c];
    }
    __syncthreads();
    #pragma unroll
    for (int i = 0; i < 4; ++i) {
        int r = r8 + i * 8;
        out[(size_t)(bn + r) * K + bk + c] = f2b(s[c][r]);
    }
}

// ---------------- bf16 MFMA GEMM: C[M,N] = A[M,K] @ BT[N,K]^T + bias ----------------
// 128xBN tile (BN = 64 or 128), BK=64, 4 waves (2x2), 16x16x32 mfma,
// global_load_lds staging, 8-slot XOR swizzle, chunked XCD swizzle (grid % 8 == 0).
template<int BN, int RELU, int QSCALE>
__global__ __launch_bounds__(256) void gemm_mfma(const short* __restrict__ A,
                                                 const short* __restrict__ BT,
                                                 const float* __restrict__ bias,
                                                 short* __restrict__ C,
                                                 int M, int K, int N,
                                                 int nbx, int cpx) {
    __shared__ __align__(16) short Alds[128 * 64];
    __shared__ __align__(16) short Blds[BN * 64];
    const int tid = threadIdx.x, lane = tid & 63, wid = tid >> 6;
    const int wg = blockIdx.x;
    const int lid = (wg & 7) * cpx + (wg >> 3);
    const int bx = lid % nbx, by = lid / nbx;
    const int bm = by * 128, bn = bx * BN;
    const int wr = wid >> 1, wc = wid & 1;
    const int NF = BN / 32;
    f4v acc[4][NF] = {};

    const short* aB = A + (size_t)bm * K;
    const short* bB = BT + (size_t)bn * K;
    const int frow = lane & 15, fs = lane >> 4;

    for (int k0 = 0; k0 < K; k0 += 64) {
        #pragma unroll
        for (int i = 0; i < 4; ++i) {
            int cb = wid * 64 + i * 256;
            int c = cb + lane;
            int row = c >> 3;
            GLOAD16(aB + (size_t)row * K + k0 + (((c & 7) ^ (row & 7)) * 8), Alds + cb * 8);
        }
        #pragma unroll
        for (int i = 0; i < NF; ++i) {
            int cb = wid * 64 + i * 256;
            int c = cb + lane;
            int row = c >> 3;
            GLOAD16(bB + (size_t)row * K + k0 + (((c & 7) ^ (row & 7)) * 8), Blds + cb * 8);
        }
        __syncthreads();
        #pragma unroll
        for (int kk = 0; kk < 2; ++kk) {
            s8v af[4], bf[NF];
            #pragma unroll
            for (int m = 0; m < 4; ++m) {
                int row = wr * 64 + m * 16 + frow;
                af[m] = *(const s8v*)(Alds + row * 64 + (((kk * 4 + fs) ^ (row & 7)) * 8));
            }
            #pragma unroll
            for (int n = 0; n < NF; ++n) {
                int row = wc * (BN / 2) + n * 16 + frow;
                bf[n] = *(const s8v*)(Blds + row * 64 + (((kk * 4 + fs) ^ (row & 7)) * 8));
            }
            __builtin_amdgcn_s_setprio(1);
            #pragma unroll
            for (int m = 0; m < 4; ++m)
                #pragma unroll
                for (int n = 0; n < NF; ++n)
                    acc[m][n] = __builtin_amdgcn_mfma_f32_16x16x32_bf16(af[m], bf[n], acc[m][n], 0, 0, 0);
            __builtin_amdgcn_s_setprio(0);
        }
        __syncthreads();
    }
    #pragma unroll
    for (int m = 0; m < 4; ++m) {
        int rbase = bm + wr * 64 + m * 16 + (lane >> 4) * 4;
        #pragma unroll
        for (int n = 0; n < NF; ++n) {
            int col = bn + wc * (BN / 2) + n * 16 + (lane & 15);
            float bv = bias[col];
            #pragma unroll
            for (int r = 0; r < 4; ++r) {
                float v = acc[m][n][r] + bv;
                if (QSCALE) { if (col < 256) v *= QK_SCALE; }
                if (RELU) v = fmaxf(v, 0.f);
                C[(size_t)(rbase + r) * N + col] = f2b(v);
            }
        }
    }
}

// ---------------- fused GEMM + residual + LayerNorm ----------------
// BM=64, BN=256 (= full row), BK=64, 4 waves (2 row x 2 col), 2-phase dbuf.
// h = LN(h + A@BT^T + bias) * g + beta, written in place to h.
__global__ __launch_bounds__(256) void gemm_ln(const short* __restrict__ A,
                                               const short* __restrict__ BT,
                                               const float* __restrict__ bias,
                                               short* __restrict__ h,
                                               const float* __restrict__ g,
                                               const float* __restrict__ beta,
                                               int K) {
    __shared__ __align__(16) short Alds[2][64 * 64];
    __shared__ __align__(16) short Blds[2][256 * 64];
    __shared__ float lred[64][2][2];   // [row][wc][{sum, sumsq}]
    const int tid = threadIdx.x, lane = tid & 63, wid = tid >> 6;
    const int wr = wid >> 1, wc = wid & 1;
    const int bm = blockIdx.x * 64;
    const int frow = lane & 15, fs = lane >> 4;
    f4v acc[2][8] = {};

    const short* aB = A + (size_t)bm * K;

    // stage A: 2 rounds of 256 x 16B; B: 8 rounds
    #define STAGE_AB(buf, k0)                                                            \
        {                                                                                \
            _Pragma("unroll")                                                            \
            for (int i = 0; i < 2; ++i) {                                                \
                int u = i * 256 + tid;                                                   \
                int row = u >> 3;                                                        \
                GLOAD16(aB + (size_t)row * K + (k0) + (((u & 7) ^ (row & 7)) * 8),       \
                        Alds[buf] + u * 8);                                              \
            }                                                                            \
            _Pragma("unroll")                                                            \
            for (int i = 0; i < 8; ++i) {                                                \
                int u = i * 256 + tid;                                                   \
                int row = u >> 3;                                                        \
                GLOAD16(BT + (size_t)row * K + (k0) + (((u & 7) ^ (row & 7)) * 8),       \
                        Blds[buf] + u * 8);                                              \
            }                                                                            \
        }

    STAGE_AB(0, 0);
    __syncthreads();
    int cur = 0;
    for (int k0 = 0; k0 < K; k0 += 64) {
        if (k0 + 64 < K) STAGE_AB(cur ^ 1, k0 + 64);
        #pragma unroll
        for (int kk = 0; kk < 2; ++kk) {
            s8v af[2], bf[8];
            #pragma unroll
            for (int m = 0; m < 2; ++m) {
                int row = wr * 32 + m * 16 + frow;
                af[m] = *(const s8v*)(Alds[cur] + row * 64 + (((kk * 4 + fs) ^ (row & 7)) * 8));
            }
            #pragma unroll
            for (int n = 0; n < 8; ++n) {
                int row = wc * 128 + n * 16 + frow;
                bf[n] = *(const s8v*)(Blds[cur] + row * 64 + (((kk * 4 + fs) ^ (row & 7)) * 8));
            }
            __builtin_amdgcn_s_setprio(1);
            #pragma unroll
            for (int m = 0; m < 2; ++m)
                #pragma unroll
                for (int n = 0; n < 8; ++n)
                    acc[m][n] = __builtin_amdgcn_mfma_f32_16x16x32_bf16(af[m], bf[n], acc[m][n], 0, 0, 0);
            __builtin_amdgcn_s_setprio(0);
        }
        __syncthreads();
        cur ^= 1;
    }
    #undef STAGE_AB

    // epilogue: v = acc + bias + h; row stats; LN write
    float s1[2][4], s2[2][4];
    #pragma unroll
    for (int m = 0; m < 2; ++m) {
        #pragma unroll
        for (int r = 0; r < 4; ++r) { s1[m][r] = 0.f; s2[m][r] = 0.f; }
    }
    #pragma unroll
    for (int m = 0; m < 2; ++m) {
        #pragma unroll
        for (int n = 0; n < 8; ++n) {
            int gc = wc * 128 + n * 16 + frow;
            float bv = bias[gc];
            #pragma unroll
            for (int r = 0; r < 4; ++r) {
                int gr = bm + wr * 32 + m * 16 + (lane >> 4) * 4 + r;
                float v = acc[m][n][r] + bv + b2f(h[(size_t)gr * HH + gc]);
                acc[m][n][r] = v;
                s1[m][r] += v;
                s2[m][r] += v * v;
            }
        }
    }
    #pragma unroll
    for (int m = 0; m < 2; ++m) {
        #pragma unroll
        for (int r = 0; r < 4; ++r) {
            float a = s1[m][r], bq = s2[m][r];
            #pragma unroll
            for (int off = 1; off < 16; off <<= 1) {
                a += __shfl_xor(a, off);
                bq += __shfl_xor(bq, off);
            }
            s1[m][r] = a; s2[m][r] = bq;
            if (frow == 0) {
                int lr = wr * 32 + m * 16 + (lane >> 4) * 4 + r;
                lred[lr][wc][0] = a;
                lred[lr][wc][1] = bq;
            }
        }
    }
    __syncthreads();
    #pragma unroll
    for (int m = 0; m < 2; ++m) {
        #pragma unroll
        for (int r = 0; r < 4; ++r) {
            int lr = wr * 32 + m * 16 + (lane >> 4) * 4 + r;
            float t1 = lred[lr][0][0] + lred[lr][1][0];
            float t2 = lred[lr][0][1] + lred[lr][1][1];
            float mean = t1 * (1.f / HH);
            float var = t2 * (1.f / HH) - mean * mean;
            float rs = rsqrtf(var + 1e-5f);
            int gr = bm + lr;
            #pragma unroll
            for (int n = 0; n < 8; ++n) {
                int gc = wc * 128 + n * 16 + frow;
                h[(size_t)gr * HH + gc] = f2b((acc[m][n][r] - mean) * rs * g[gc] + beta[gc]);
            }
        }
    }
}

// ---------------- MFMA flash attention (swapped QK^T, no-max softmax) ----------------
// 512 thr = 8 waves; wave w: 32 q rows; q-tile 256; KV tile 128 tokens, double-buffered.
// Q pre-scaled by log2(e)/sqrt(HD) -> scores in log2 domain, |s| <~ 5 for LN'd
// activations, so p = exp2(s) directly (softmax is shift-invariant; fp32 exp2
// safe to s=127). Kills max-tree / defer-branch / rescale / subtract.
__global__ __launch_bounds__(512) void attn_mfma(const short* __restrict__ qkv,
                                                 short* __restrict__ o) {
    __shared__ __align__(16) short Klds[2][4][128][8];   // [buf][hd-chunk][token][8hd]
    __shared__ __align__(16) short Vlds[2][32][136];     // [buf][d][token padded, 16B-aligned]
    const int tid = threadIdx.x, lane = tid & 63, wid = tid >> 6;
    const int hi = lane >> 5, lq = lane & 31;
    const int wg = blockIdx.x;
    const int lid = (wg & 7) * 64 + (wg >> 3);   // chunked XCD swizzle
    const int qt = lid & 3;
    const int h  = (lid >> 2) & 7;
    const int b  = lid >> 5;
    const int q0 = qt * 256 + wid * 32;
    const short* qkvb = qkv + (size_t)b * NN * 768;

    s8v qf0, qf1;
    {
        const short* qrow = qkvb + (size_t)(q0 + lq) * 768 + h * 32 + hi * 8;
        qf0 = *(const s8v*)qrow;
        qf1 = *(const s8v*)(qrow + 16);
    }

    const int token = tid & 127, cK = tid >> 7, dc = cK * 8;
    const f16x fz = {};

    float l = 0.f;
    f16x acc = {};

    {   // prologue: stage tile 0
        const short* kvrow = qkvb + (size_t)token * 768 + 256 + h * 32;
        GLOAD16(kvrow + cK * 8, &Klds[0][cK][token][0]);
        s8v vv = *(const s8v*)(kvrow + 256 + dc);
        #pragma unroll
        for (int j = 0; j < 8; ++j) Vlds[0][dc + j][token] = vv[j];
    }
    __syncthreads();

    for (int t = 0; t < 8; ++t) {
        const int bb = t & 1;
        s8v vvn;
        if (t < 7) {
            const short* kvrow = qkvb + (size_t)((t + 1) * 128 + token) * 768 + 256 + h * 32;
            GLOAD16(kvrow + cK * 8, &Klds[bb ^ 1][cK][token][0]);
            vvn = *(const s8v*)(kvrow + 256 + dc);
        }
        #pragma unroll
        for (int kt = 0; kt < 4; ++kt) {
            const s8v kf0 = *(const s8v*)&Klds[bb][hi][kt * 32 + lq][0];
            const s8v kf1 = *(const s8v*)&Klds[bb][2 + hi][kt * 32 + lq][0];
            __builtin_amdgcn_s_setprio(1);
            f16x p = __builtin_amdgcn_mfma_f32_32x32x16_bf16(kf0, qf0, fz, 0, 0, 0);
            p = __builtin_amdgcn_mfma_f32_32x32x16_bf16(kf1, qf1, p, 0, 0, 0);
            __builtin_amdgcn_s_setprio(0);
            float l0 = 0.f, l1 = 0.f, l2 = 0.f, l3 = 0.f;
            #pragma unroll
            for (int r = 0; r < 16; r += 4) {
                p[r]     = __builtin_amdgcn_exp2f(p[r]);     l0 += p[r];
                p[r + 1] = __builtin_amdgcn_exp2f(p[r + 1]); l1 += p[r + 1];
                p[r + 2] = __builtin_amdgcn_exp2f(p[r + 2]); l2 += p[r + 2];
                p[r + 3] = __builtin_amdgcn_exp2f(p[r + 3]); l3 += p[r + 3];
            }
            l += (l0 + l1) + (l2 + l3);
            unsigned w[8];
            #pragma unroll
            for (int i = 0; i < 8; ++i) w[i] = cvtpk_bf16(p[2 * i], p[2 * i + 1]);
            asm volatile("v_permlane32_swap_b32 %0, %1" : "+v"(w[0]), "+v"(w[2]));
            asm volatile("v_permlane32_swap_b32 %0, %1" : "+v"(w[1]), "+v"(w[3]));
            asm volatile("v_permlane32_swap_b32 %0, %1" : "+v"(w[4]), "+v"(w[6]));
            asm volatile("v_permlane32_swap_b32 %0, %1" : "+v"(w[5]), "+v"(w[7]));
            union { unsigned u[4]; s8v v; } pa0, pa1;
            pa0.u[0] = w[0]; pa0.u[1] = w[1]; pa0.u[2] = w[2]; pa0.u[3] = w[3];
            pa1.u[0] = w[4]; pa1.u[1] = w[5]; pa1.u[2] = w[6]; pa1.u[3] = w[7];
            const s8v vf0 = *(const s8v*)&Vlds[bb][lq][kt * 32 + hi * 8];
            const s8v vf1 = *(const s8v*)&Vlds[bb][lq][kt * 32 + 16 + hi * 8];
            __builtin_amdgcn_s_setprio(1);
            acc = __builtin_amdgcn_mfma_f32_32x32x16_bf16(pa0.v, vf0, acc, 0, 0, 0);
            acc = __builtin_amdgcn_mfma_f32_32x32x16_bf16(pa1.v, vf1, acc, 0, 0, 0);
            __builtin_amdgcn_s_setprio(0);
        }
        if (t < 7) {
            #pragma unroll
            for (int j = 0; j < 8; ++j) Vlds[bb ^ 1][dc + j][token] = vvn[j];
        }
        __syncthreads();
    }

    l += __shfl_xor(l, 32);
    float inv = 1.f / l;
    short* ob = o + ((size_t)(b * NN + q0)) * HH + h * 32 + lq;
    #pragma unroll
    for (int r = 0; r < 16; ++r) {
        int qr = (r & 3) + 8 * (r >> 2) + 4 * hi;
        float invr = __shfl(inv, qr);
        ob[(size_t)qr * HH] = f2b(acc[r] * invr);
    }
}

// ---------------- fused allocation: all stages in one kernel (block per batch) ----------------
__global__ __launch_bounds__(1024) void alloc_all(const short* __restrict__ enc,
                                                  const int* __restrict__ idx,
                                                  const float* __restrict__ Wc,
                                                  const float* __restrict__ bc,
                                                  float* __restrict__ out) {
    __shared__ float part[16][HH];     // 16 KB
    __shared__ float mean_s[HH];
    __shared__ float ctx_s[HH];
    __shared__ float sc_s[KSEL];
    __shared__ float alloc_s[KSEL];
    __shared__ int   idx_s[KSEL];
    __shared__ float red[16];
    __shared__ float cnt_s, smax_s, ssum_s, diff_s;
    const int b = blockIdx.x, t = threadIdx.x;
    const int w = t >> 6, lane = t & 63;

    if (t < KSEL) idx_s[t] = idx[b * KSEL + t];
    __syncthreads();

    // count valid (threads < 512 contribute)
    {
        float c = (t < KSEL && idx_s[t] < NN) ? 1.f : 0.f;
        #pragma unroll
        for (int o = 32; o; o >>= 1) c += __shfl_xor(c, o);
        if (lane == 0) red[w] = c;
        __syncthreads();
        if (t == 0) {
            float s = 0.f;
            #pragma unroll
            for (int i = 0; i < 16; ++i) s += red[i];
            cnt_s = fmaxf(s, 1.f);
        }
    }

    // gather partial sums: wave w handles k in [w*32, w*32+32), lane covers 4 cols
    {
        const int c0 = lane * 4;
        float s0 = 0.f, s1 = 0.f, s2 = 0.f, s3 = 0.f;
        #pragma unroll
        for (int i = 0; i < 32; ++i) {
            int id = idx_s[w * 32 + i];
            if (id < NN) {
                s4v v = *(const s4v*)(enc + (size_t)(b * NN + id) * HH + c0);
                s0 += b2f(v[0]); s1 += b2f(v[1]); s2 += b2f(v[2]); s3 += b2f(v[3]);
            }
        }
        part[w][c0] = s0; part[w][c0 + 1] = s1; part[w][c0 + 2] = s2; part[w][c0 + 3] = s3;
    }
    __syncthreads();
    if (t < HH) {
        float s = 0.f;
        #pragma unroll
        for (int p = 0; p < 16; ++p) s += part[p][t];
        mean_s[t] = s / cnt_s;
    }
    __syncthreads();
    if (t < HH) {
        float cv = bc[t];
        #pragma unroll 8
        for (int j = 0; j < HH; ++j) cv = fmaf(mean_s[j], Wc[(size_t)j * HH + t], cv);
        ctx_s[t] = cv;
    }
    __syncthreads();

    // scores: wave w handles indices k in [w*32, w*32+32), 64-lane dot each
    {
        const f4v cv = *(const f4v*)(ctx_s + lane * 4);
        for (int i = 0; i < 32; ++i) {
            int k = w * 32 + i;
            int id = idx_s[k];
            float sc = -1e9f;
            if (id < NN) {
                s4v v = *(const s4v*)(enc + (size_t)(b * NN + id) * HH + lane * 4);
                float p = cv[0] * b2f(v[0]) + cv[1] * b2f(v[1]) + cv[2] * b2f(v[2]) + cv[3] * b2f(v[3]);
                #pragma unroll
                for (int o = 32; o; o >>= 1) p += __shfl_xor(p, o);
                sc = p;
            }
            if (lane == 0) sc_s[k] = sc;
        }
    }
    __syncthreads();

    // softmax over 512 + round + fix + scatter
    float myv = (t < KSEL) ? sc_s[t] : -1e9f;
    {
        float m = myv;
        #pragma unroll
        for (int o = 32; o; o >>= 1) m = fmaxf(m, __shfl_xor(m, o));
        if (lane == 0) red[w] = m;
        __syncthreads();
        if (t == 0) {
            float mm = red[0];
            #pragma unroll
            for (int i = 1; i < 16; ++i) mm = fmaxf(mm, red[i]);
            smax_s = mm;
        }
        __syncthreads();
    }
    float e = (t < KSEL && idx_s[t] < NN) ? __expf(myv - smax_s) : 0.f;
    {
        float s = e;
        #pragma unroll
        for (int o = 32; o; o >>= 1) s += __shfl_xor(s, o);
        if (lane == 0) red[w] = s;
        __syncthreads();
        if (t == 0) {
            float ss = 0.f;
            #pragma unroll
            for (int i = 0; i < 16; ++i) ss += red[i];
            ssum_s = ss;
        }
        __syncthreads();
    }
    float a = rintf(e * (100.f / ssum_s));
    if (t < KSEL) alloc_s[t] = a;
    {
        float s = (t < KSEL) ? a : 0.f;
        #pragma unroll
        for (int o = 32; o; o >>= 1) s += __shfl_xor(s, o);
        if (lane == 0) red[w] = s;
        __syncthreads();
        if (t == 0) {
            float ss = 0.f;
            #pragma unroll
            for (int i = 0; i < 16; ++i) ss += red[i];
            diff_s = 100.f - ss;
        }
        __syncthreads();
        if (t == 0 && idx_s[0] < NN) alloc_s[0] += diff_s;
    }

    float* bw = out + BB * KSEL + (size_t)b * NN;
    bw[t] = 0.f;                        // 1024 threads cover NN exactly
    __syncthreads();
    if (t < KSEL) {
        int id = idx_s[t];
        out[b * KSEL + t] = (float)id;
        if (id < NN) bw[id] = alloc_s[t];
    }
}

// ---------------- launch ----------------
extern "C" void kernel_launch(void* const* d_in, const int* in_sizes, int n_in,
                              void* d_out, int out_size, void* d_ws, size_t ws_size,
                              hipStream_t stream) {
    const float* x     = (const float*)d_in[0];
    const int*   sel   = (const int*)  d_in[1];
    const float* W_in  = (const float*)d_in[2];
    const float* b_in  = (const float*)d_in[3];
    const float* Wqkv  = (const float*)d_in[4];
    const float* bqkv  = (const float*)d_in[5];
    const float* Wo    = (const float*)d_in[6];
    const float* bo    = (const float*)d_in[7];
    const float* ln1_g = (const float*)d_in[8];
    const float* ln1_b = (const float*)d_in[9];
    const float* W1    = (const float*)d_in[10];
    const float* b1    = (const float*)d_in[11];
    const float* W2    = (const float*)d_in[12];
    const float* b2    = (const float*)d_in[13];
    const float* ln2_g = (const float*)d_in[14];
    const float* ln2_b = (const float*)d_in[15];
    const float* Wc    = (const float*)d_in[16];
    const float* bc    = (const float*)d_in[17];
    float* out = (float*)d_out;

    char* base = (char*)d_ws;
    short* h    = (short*)(base);                       // 8 MB
    short* qkv  = (short*)(base + (8u << 20));          // 24 MB
    short* obuf = (short*)(base + (32u << 20));         // 8 MB
    short* ff   = (short*)(base + (40u << 20));         // 32 MB
    short* xb   = (short*)(base + (76u << 20));         // 2 MB
    short* wt   = (short*)(base + (78u << 20));         // ~3.1 MB
    short* W_inT  = wt;
    short* WqkvT  = W_inT + 256 * 64;
    short* WoT    = WqkvT + LL * 768 * 256;
    short* W1T    = WoT   + LL * 256 * 256;
    short* W2T    = W1T   + LL * 1024 * 256;

    // fused weight transpose + x conversion: 9 segments (1552 tiles) + 1024 cvt blocks
    {
        WtDesc d;
        const float* srcs[9] = { W_in, Wqkv, Wqkv + (size_t)HH * 768, Wo, Wo + (size_t)HH * HH,
                                 W1, W1 + (size_t)HH * FFD, W2, W2 + (size_t)FFD * HH };
        short* dsts[9] = { W_inT, WqkvT, WqkvT + 768 * 256, WoT, WoT + 256 * 256,
                           W1T, W1T + 1024 * 256, W2T, W2T + 256 * 1024 };
        int Ks[9] = { 64, 256, 256, 256, 256, 256, 256, 1024, 1024 };
        int Ns[9] = { 256, 768, 768, 256, 256, 1024, 1024, 256, 256 };
        int tb = 0;
        for (int i = 0; i < 9; ++i) {
            d.src[i] = srcs[i]; d.dst[i] = dsts[i];
            d.K[i] = Ks[i]; d.N[i] = Ns[i]; d.tb[i] = tb;
            tb += (Ks[i] >> 5) * (Ns[i] >> 5);
        }
        d.x = x; d.xb = xb; d.cvt_tb = tb;
        wtrans_all<<<tb + MTOT * DIN / 1024, 256, 0, stream>>>(d);
    }

    // h = x @ W_in + b_in     BN=64: grid 4*128=512
    gemm_mfma<64,0,0><<<512, 256, 0, stream>>>(xb, W_inT, b_in, h, MTOT, DIN, HH, 4, 64);

    for (int l = 0; l < LL; ++l) {
        // qkv projection; Q columns pre-scaled by log2(e)/sqrt(HD).  grid 6*128=768
        gemm_mfma<128,0,1><<<768, 256, 0, stream>>>(
            h, WqkvT + (size_t)l * 768 * HH, bqkv + l * 768, qkv, MTOT, HH, 768, 6, 96);
        attn_mfma<<<BB * NHEAD * 4, 512, 0, stream>>>(qkv, obuf);
        // o-proj + residual + LN1 fused (block per 64 rows, full row width)
        gemm_ln<<<MTOT / 64, 256, 0, stream>>>(
            obuf, WoT + (size_t)l * HH * HH, bo + l * HH, h, ln1_g + l * HH, ln1_b + l * HH, HH);
        gemm_mfma<128,1,0><<<1024, 256, 0, stream>>>(
            h, W1T + (size_t)l * FFD * HH, b1 + l * FFD, ff, MTOT, HH, FFD, 8, 128);
        // ffn2 + residual + LN2 fused
        gemm_ln<<<MTOT / 64, 256, 0, stream>>>(
            ff, W2T + (size_t)l * HH * FFD, b2 + l * HH, h, ln2_g + l * HH, ln2_b + l * HH, FFD);
    }

    alloc_all<<<BB, 1024, 0, stream>>>(h, sel, Wc, bc, out);
}

// Round 9
// 328.434 us; speedup vs baseline: 7.9437x; 1.0019x over previous
//
#include <hip/hip_runtime.h>
#include <math.h>

#define BB 16
#define NN 1024
#define KSEL 512
#define DIN 64
#define HH 256
#define NHEAD 8
#define HD 32
#define LL 2
#define FFD 1024
#define MTOT (BB*NN)   // 16384

typedef __attribute__((ext_vector_type(8))) short s8v;   // 8 bf16
typedef __attribute__((ext_vector_type(4))) short s4v;
typedef __attribute__((ext_vector_type(4))) float f4v;
typedef __attribute__((ext_vector_type(16))) float f16x;

// 1/sqrt(32) * log2(e): QK^T scores land in log2 domain -> native exp2
#define QK_SCALE 0.25503485f

__device__ __forceinline__ float b2f(short u) {
    union { unsigned int i; float f; } v;
    v.i = ((unsigned int)(unsigned short)u) << 16;
    return v.f;
}
__device__ __forceinline__ short f2b(float f) {
    union { float f; unsigned int i; } v;
    v.f = f;
    unsigned int r = v.i + 0x7fffu + ((v.i >> 16) & 1u);
    return (short)(r >> 16);
}
__device__ __forceinline__ unsigned cvtpk_bf16(float a, float b) {
    unsigned r;
    asm("v_cvt_pk_bf16_f32 %0, %1, %2" : "=v"(r) : "v"(a), "v"(b));
    return r;
}

#define GLOAD16(g, l) __builtin_amdgcn_global_load_lds( \
    (const __attribute__((address_space(1))) unsigned int*)(const void*)(g), \
    (__attribute__((address_space(3))) unsigned int*)(l), 16, 0, 0)

// ---------------- fused weight transpose+convert + x-cvt (one launch) ----------------
struct WtDesc {
    const float* src[9];
    short* dst[9];
    int K[9], N[9], tb[9];
    const float* x;       // cvt source
    short* xb;            // cvt dest
    int cvt_tb;           // first cvt block
};
__global__ __launch_bounds__(256) void wtrans_all(WtDesc d) {
    __shared__ float s[32][33];
    const int bid = blockIdx.x;
    if (bid >= d.cvt_tb) {
        int i = (bid - d.cvt_tb) * 256 + threadIdx.x;   // 4-elem chunk index
        f4v v = *(const f4v*)(d.x + (size_t)i * 4);
        s4v o;
        o[0] = f2b(v[0]); o[1] = f2b(v[1]); o[2] = f2b(v[2]); o[3] = f2b(v[3]);
        *(s4v*)(d.xb + (size_t)i * 4) = o;
        return;
    }
    int si = 0;
    #pragma unroll
    for (int i = 1; i < 9; ++i) si = (bid >= d.tb[i]) ? i : si;
    const float* in = d.src[si];
    short* out = d.dst[si];
    const int K = d.K[si], N = d.N[si];
    const int lt = bid - d.tb[si];
    const int tn = N >> 5;
    const int bk = (lt / tn) * 32, bn = (lt % tn) * 32;
    const int c = threadIdx.x & 31, r8 = threadIdx.x >> 5;
    #pragma unroll
    for (int i = 0; i < 4; ++i) {
        int r = r8 + i * 8;
        s[r][c] = in[(size_t)(bk + r) * N + bn + c];
    }
    __syncthreads();
    #pragma unroll
    for (int i = 0; i < 4; ++i) {
        int r = r8 + i * 8;
        out[(size_t)(bn + r) * K + bk + c] = f2b(s[c][r]);
    }
}

// ---------------- bf16 MFMA GEMM: C[M,N] = A[M,K] @ BT[N,K]^T + bias ----------------
// 128xBN tile (BN = 64 or 128), BK=64, 4 waves (2x2), 16x16x32 mfma,
// global_load_lds staging, 8-slot XOR swizzle, chunked XCD swizzle (grid % 8 == 0).
template<int BN, int RELU, int QSCALE>
__global__ __launch_bounds__(256) void gemm_mfma(const short* __restrict__ A,
                                                 const short* __restrict__ BT,
                                                 const float* __restrict__ bias,
                                                 short* __restrict__ C,
                                                 int M, int K, int N,
                                                 int nbx, int cpx) {
    __shared__ __align__(16) short Alds[128 * 64];
    __shared__ __align__(16) short Blds[BN * 64];
    const int tid = threadIdx.x, lane = tid & 63, wid = tid >> 6;
    const int wg = blockIdx.x;
    const int lid = (wg & 7) * cpx + (wg >> 3);
    const int bx = lid % nbx, by = lid / nbx;
    const int bm = by * 128, bn = bx * BN;
    const int wr = wid >> 1, wc = wid & 1;
    const int NF = BN / 32;
    f4v acc[4][NF] = {};

    const short* aB = A + (size_t)bm * K;
    const short* bB = BT + (size_t)bn * K;
    const int frow = lane & 15, fs = lane >> 4;

    for (int k0 = 0; k0 < K; k0 += 64) {
        #pragma unroll
        for (int i = 0; i < 4; ++i) {
            int cb = wid * 64 + i * 256;
            int c = cb + lane;
            int row = c >> 3;
            GLOAD16(aB + (size_t)row * K + k0 + (((c & 7) ^ (row & 7)) * 8), Alds + cb * 8);
        }
        #pragma unroll
        for (int i = 0; i < NF; ++i) {
            int cb = wid * 64 + i * 256;
            int c = cb + lane;
            int row = c >> 3;
            GLOAD16(bB + (size_t)row * K + k0 + (((c & 7) ^ (row & 7)) * 8), Blds + cb * 8);
        }
        __syncthreads();
        #pragma unroll
        for (int kk = 0; kk < 2; ++kk) {
            s8v af[4], bf[NF];
            #pragma unroll
            for (int m = 0; m < 4; ++m) {
                int row = wr * 64 + m * 16 + frow;
                af[m] = *(const s8v*)(Alds + row * 64 + (((kk * 4 + fs) ^ (row & 7)) * 8));
            }
            #pragma unroll
            for (int n = 0; n < NF; ++n) {
                int row = wc * (BN / 2) + n * 16 + frow;
                bf[n] = *(const s8v*)(Blds + row * 64 + (((kk * 4 + fs) ^ (row & 7)) * 8));
            }
            __builtin_amdgcn_s_setprio(1);
            #pragma unroll
            for (int m = 0; m < 4; ++m)
                #pragma unroll
                for (int n = 0; n < NF; ++n)
                    acc[m][n] = __builtin_amdgcn_mfma_f32_16x16x32_bf16(af[m], bf[n], acc[m][n], 0, 0, 0);
            __builtin_amdgcn_s_setprio(0);
        }
        __syncthreads();
    }
    #pragma unroll
    for (int m = 0; m < 4; ++m) {
        int rbase = bm + wr * 64 + m * 16 + (lane >> 4) * 4;
        #pragma unroll
        for (int n = 0; n < NF; ++n) {
            int col = bn + wc * (BN / 2) + n * 16 + (lane & 15);
            float bv = bias[col];
            #pragma unroll
            for (int r = 0; r < 4; ++r) {
                float v = acc[m][n][r] + bv;
                if (QSCALE) { if (col < 256) v *= QK_SCALE; }
                if (RELU) v = fmaxf(v, 0.f);
                C[(size_t)(rbase + r) * N + col] = f2b(v);
            }
        }
    }
}

// ---------------- fused GEMM + residual + LayerNorm ----------------
// BM=64, BN=256 (= full row), BK=64, 4 waves (2 row x 2 col), 2-phase dbuf.
// h = LN(h + A@BT^T + bias) * g + beta, written in place to h.
__global__ __launch_bounds__(256) void gemm_ln(const short* __restrict__ A,
                                               const short* __restrict__ BT,
                                               const float* __restrict__ bias,
                                               short* __restrict__ h,
                                               const float* __restrict__ g,
                                               const float* __restrict__ beta,
                                               int K) {
    __shared__ __align__(16) short Alds[2][64 * 64];
    __shared__ __align__(16) short Blds[2][256 * 64];
    __shared__ float lred[64][2][2];   // [row][wc][{sum, sumsq}]
    const int tid = threadIdx.x, lane = tid & 63, wid = tid >> 6;
    const int wr = wid >> 1, wc = wid & 1;
    const int bm = blockIdx.x * 64;
    const int frow = lane & 15, fs = lane >> 4;
    f4v acc[2][8] = {};

    const short* aB = A + (size_t)bm * K;

    // stage A: 2 rounds of 256 x 16B; B: 8 rounds
    #define STAGE_AB(buf, k0)                                                            \
        {                                                                                \
            _Pragma("unroll")                                                            \
            for (int i = 0; i < 2; ++i) {                                                \
                int u = i * 256 + tid;                                                   \
                int row = u >> 3;                                                        \
                GLOAD16(aB + (size_t)row * K + (k0) + (((u & 7) ^ (row & 7)) * 8),       \
                        Alds[buf] + u * 8);                                              \
            }                                                                            \
            _Pragma("unroll")                                                            \
            for (int i = 0; i < 8; ++i) {                                                \
                int u = i * 256 + tid;                                                   \
                int row = u >> 3;                                                        \
                GLOAD16(BT + (size_t)row * K + (k0) + (((u & 7) ^ (row & 7)) * 8),       \
                        Blds[buf] + u * 8);                                              \
            }                                                                            \
        }

    STAGE_AB(0, 0);
    __syncthreads();
    int cur = 0;
    for (int k0 = 0; k0 < K; k0 += 64) {
        if (k0 + 64 < K) STAGE_AB(cur ^ 1, k0 + 64);
        #pragma unroll
        for (int kk = 0; kk < 2; ++kk) {
            s8v af[2], bf[8];
            #pragma unroll
            for (int m = 0; m < 2; ++m) {
                int row = wr * 32 + m * 16 + frow;
                af[m] = *(const s8v*)(Alds[cur] + row * 64 + (((kk * 4 + fs) ^ (row & 7)) * 8));
            }
            #pragma unroll
            for (int n = 0; n < 8; ++n) {
                int row = wc * 128 + n * 16 + frow;
                bf[n] = *(const s8v*)(Blds[cur] + row * 64 + (((kk * 4 + fs) ^ (row & 7)) * 8));
            }
            __builtin_amdgcn_s_setprio(1);
            #pragma unroll
            for (int m = 0; m < 2; ++m)
                #pragma unroll
                for (int n = 0; n < 8; ++n)
                    acc[m][n] = __builtin_amdgcn_mfma_f32_16x16x32_bf16(af[m], bf[n], acc[m][n], 0, 0, 0);
            __builtin_amdgcn_s_setprio(0);
        }
        __syncthreads();
        cur ^= 1;
    }
    #undef STAGE_AB

    // epilogue: v = acc + bias + h; row stats; LN write
    float s1[2][4], s2[2][4];
    #pragma unroll
    for (int m = 0; m < 2; ++m) {
        #pragma unroll
        for (int r = 0; r < 4; ++r) { s1[m][r] = 0.f; s2[m][r] = 0.f; }
    }
    #pragma unroll
    for (int m = 0; m < 2; ++m) {
        #pragma unroll
        for (int n = 0; n < 8; ++n) {
            int gc = wc * 128 + n * 16 + frow;
            float bv = bias[gc];
            #pragma unroll
            for (int r = 0; r < 4; ++r) {
                int gr = bm + wr * 32 + m * 16 + (lane >> 4) * 4 + r;
                float v = acc[m][n][r] + bv + b2f(h[(size_t)gr * HH + gc]);
                acc[m][n][r] = v;
                s1[m][r] += v;
                s2[m][r] += v * v;
            }
        }
    }
    #pragma unroll
    for (int m = 0; m < 2; ++m) {
        #pragma unroll
        for (int r = 0; r < 4; ++r) {
            float a = s1[m][r], bq = s2[m][r];
            #pragma unroll
            for (int off = 1; off < 16; off <<= 1) {
                a += __shfl_xor(a, off);
                bq += __shfl_xor(bq, off);
            }
            s1[m][r] = a; s2[m][r] = bq;
            if (frow == 0) {
                int lr = wr * 32 + m * 16 + (lane >> 4) * 4 + r;
                lred[lr][wc][0] = a;
                lred[lr][wc][1] = bq;
            }
        }
    }
    __syncthreads();
    #pragma unroll
    for (int m = 0; m < 2; ++m) {
        #pragma unroll
        for (int r = 0; r < 4; ++r) {
            int lr = wr * 32 + m * 16 + (lane >> 4) * 4 + r;
            float t1 = lred[lr][0][0] + lred[lr][1][0];
            float t2 = lred[lr][0][1] + lred[lr][1][1];
            float mean = t1 * (1.f / HH);
            float var = t2 * (1.f / HH) - mean * mean;
            float rs = rsqrtf(var + 1e-5f);
            int gr = bm + lr;
            #pragma unroll
            for (int n = 0; n < 8; ++n) {
                int gc = wc * 128 + n * 16 + frow;
                h[(size_t)gr * HH + gc] = f2b((acc[m][n][r] - mean) * rs * g[gc] + beta[gc]);
            }
        }
    }
}

// ---------------- MFMA flash attention (swapped QK^T, no-max softmax) ----------------
// 512 thr = 8 waves; wave w: 32 q rows; q-tile 256; KV tile 128 tokens, double-buffered.
// Q pre-scaled by log2(e)/sqrt(HD) -> scores in log2 domain, |s| <~ 5 for LN'd
// activations, so p = exp2(s) directly (softmax is shift-invariant; fp32 exp2
// safe to s=127). Kills max-tree / defer-branch / rescale / subtract.
__global__ __launch_bounds__(512) void attn_mfma(const short* __restrict__ qkv,
                                                 short* __restrict__ o) {
    __shared__ __align__(16) short Klds[2][4][128][8];   // [buf][hd-chunk][token][8hd]
    __shared__ __align__(16) short Vlds[2][32][136];     // [buf][d][token padded, 16B-aligned]
    const int tid = threadIdx.x, lane = tid & 63, wid = tid >> 6;
    const int hi = lane >> 5, lq = lane & 31;
    const int wg = blockIdx.x;
    const int lid = (wg & 7) * 64 + (wg >> 3);   // chunked XCD swizzle
    const int qt = lid & 3;
    const int h  = (lid >> 2) & 7;
    const int b  = lid >> 5;
    const int q0 = qt * 256 + wid * 32;
    const short* qkvb = qkv + (size_t)b * NN * 768;

    s8v qf0, qf1;
    {
        const short* qrow = qkvb + (size_t)(q0 + lq) * 768 + h * 32 + hi * 8;
        qf0 = *(const s8v*)qrow;
        qf1 = *(const s8v*)(qrow + 16);
    }

    const int token = tid & 127, cK = tid >> 7, dc = cK * 8;
    const f16x fz = {};

    float l = 0.f;
    f16x acc = {};

    {   // prologue: stage tile 0
        const short* kvrow = qkvb + (size_t)token * 768 + 256 + h * 32;
        GLOAD16(kvrow + cK * 8, &Klds[0][cK][token][0]);
        s8v vv = *(const s8v*)(kvrow + 256 + dc);
        #pragma unroll
        for (int j = 0; j < 8; ++j) Vlds[0][dc + j][token] = vv[j];
    }
    __syncthreads();

    for (int t = 0; t < 8; ++t) {
        const int bb = t & 1;
        s8v vvn;
        if (t < 7) {
            const short* kvrow = qkvb + (size_t)((t + 1) * 128 + token) * 768 + 256 + h * 32;
            GLOAD16(kvrow + cK * 8, &Klds[bb ^ 1][cK][token][0]);
            vvn = *(const s8v*)(kvrow + 256 + dc);
        }
        #pragma unroll
        for (int kt = 0; kt < 4; ++kt) {
            const s8v kf0 = *(const s8v*)&Klds[bb][hi][kt * 32 + lq][0];
            const s8v kf1 = *(const s8v*)&Klds[bb][2 + hi][kt * 32 + lq][0];
            __builtin_amdgcn_s_setprio(1);
            f16x p = __builtin_amdgcn_mfma_f32_32x32x16_bf16(kf0, qf0, fz, 0, 0, 0);
            p = __builtin_amdgcn_mfma_f32_32x32x16_bf16(kf1, qf1, p, 0, 0, 0);
            __builtin_amdgcn_s_setprio(0);
            float l0 = 0.f, l1 = 0.f, l2 = 0.f, l3 = 0.f;
            #pragma unroll
            for (int r = 0; r < 16; r += 4) {
                p[r]     = __builtin_amdgcn_exp2f(p[r]);     l0 += p[r];
                p[r + 1] = __builtin_amdgcn_exp2f(p[r + 1]); l1 += p[r + 1];
                p[r + 2] = __builtin_amdgcn_exp2f(p[r + 2]); l2 += p[r + 2];
                p[r + 3] = __builtin_amdgcn_exp2f(p[r + 3]); l3 += p[r + 3];
            }
            l += (l0 + l1) + (l2 + l3);
            unsigned w[8];
            #pragma unroll
            for (int i = 0; i < 8; ++i) w[i] = cvtpk_bf16(p[2 * i], p[2 * i + 1]);
            asm volatile("v_permlane32_swap_b32 %0, %1" : "+v"(w[0]), "+v"(w[2]));
            asm volatile("v_permlane32_swap_b32 %0, %1" : "+v"(w[1]), "+v"(w[3]));
            asm volatile("v_permlane32_swap_b32 %0, %1" : "+v"(w[4]), "+v"(w[6]));
            asm volatile("v_permlane32_swap_b32 %0, %1" : "+v"(w[5]), "+v"(w[7]));
            union { unsigned u[4]; s8v v; } pa0, pa1;
            pa0.u[0] = w[0]; pa0.u[1] = w[1]; pa0.u[2] = w[2]; pa0.u[3] = w[3];
            pa1.u[0] = w[4]; pa1.u[1] = w[5]; pa1.u[2] = w[6]; pa1.u[3] = w[7];
            const s8v vf0 = *(const s8v*)&Vlds[bb][lq][kt * 32 + hi * 8];
            const s8v vf1 = *(const s8v*)&Vlds[bb][lq][kt * 32 + 16 + hi * 8];
            __builtin_amdgcn_s_setprio(1);
            acc = __builtin_amdgcn_mfma_f32_32x32x16_bf16(pa0.v, vf0, acc, 0, 0, 0);
            acc = __builtin_amdgcn_mfma_f32_32x32x16_bf16(pa1.v, vf1, acc, 0, 0, 0);
            __builtin_amdgcn_s_setprio(0);
        }
        if (t < 7) {
            #pragma unroll
            for (int j = 0; j < 8; ++j) Vlds[bb ^ 1][dc + j][token] = vvn[j];
        }
        __syncthreads();
    }

    l += __shfl_xor(l, 32);
    float inv = 1.f / l;
    short* ob = o + ((size_t)(b * NN + q0)) * HH + h * 32 + lq;
    #pragma unroll
    for (int r = 0; r < 16; ++r) {
        int qr = (r & 3) + 8 * (r >> 2) + 4 * hi;
        float invr = __shfl(inv, qr);
        ob[(size_t)qr * HH] = f2b(acc[r] * invr);
    }
}

// ---------------- fused allocation: all stages, latency-tuned (block per batch) ----------------
__global__ __launch_bounds__(1024) void alloc_all(const short* __restrict__ enc,
                                                  const int* __restrict__ idx,
                                                  const float* __restrict__ Wc,
                                                  const float* __restrict__ bc,
                                                  float* __restrict__ out) {
    __shared__ float part[16][HH];     // 16 KB; reused: gather partials, then ctx partials
    __shared__ float mean_s[HH];
    __shared__ float ctx_s[HH];
    __shared__ float sc_s[KSEL];
    __shared__ float alloc_s[KSEL];
    __shared__ int   idx_s[KSEL];
    __shared__ float red[16];
    __shared__ float cnt_s, smax_s, ssum_s, diff_s;
    const int b = blockIdx.x, t = threadIdx.x;
    const int w = t >> 6, lane = t & 63;

    if (t < KSEL) idx_s[t] = idx[b * KSEL + t];
    __syncthreads();

    // count valid
    {
        float c = (t < KSEL && idx_s[t] < NN) ? 1.f : 0.f;
        #pragma unroll
        for (int o = 32; o; o >>= 1) c += __shfl_xor(c, o);
        if (lane == 0) red[w] = c;
    }
    // gather partial sums: wave w handles k in [w*32, w*32+32), lane covers 4 cols
    {
        const int c0 = lane * 4;
        float s0 = 0.f, s1 = 0.f, s2 = 0.f, s3 = 0.f;
        #pragma unroll
        for (int i = 0; i < 32; ++i) {
            int id = idx_s[w * 32 + i];
            if (id < NN) {
                s4v v = *(const s4v*)(enc + (size_t)(b * NN + id) * HH + c0);
                s0 += b2f(v[0]); s1 += b2f(v[1]); s2 += b2f(v[2]); s3 += b2f(v[3]);
            }
        }
        part[w][c0] = s0; part[w][c0 + 1] = s1; part[w][c0 + 2] = s2; part[w][c0 + 3] = s3;
    }
    __syncthreads();
    if (t == 0) {
        float s = 0.f;
        #pragma unroll
        for (int i = 0; i < 16; ++i) s += red[i];
        cnt_s = fmaxf(s, 1.f);
    }
    __syncthreads();
    if (t < HH) {
        float s = 0.f;
        #pragma unroll
        for (int p = 0; p < 16; ++p) s += part[p][t];
        mean_s[t] = s / cnt_s;
    }
    __syncthreads();

    // ctx GEMV, wave-parallel: wave w covers j in [w*16, w*16+16); lane covers 4 cols.
    // Each Wc row is a contiguous 1KB line -> one coalesced fetch per (w,jj).
    {
        const int c0 = lane * 4;
        f4v pc = {};
        #pragma unroll
        for (int jj = 0; jj < 16; ++jj) {
            int j = w * 16 + jj;
            float mj = mean_s[j];
            const f4v wr = *(const f4v*)(Wc + (size_t)j * HH + c0);
            pc[0] = fmaf(mj, wr[0], pc[0]);
            pc[1] = fmaf(mj, wr[1], pc[1]);
            pc[2] = fmaf(mj, wr[2], pc[2]);
            pc[3] = fmaf(mj, wr[3], pc[3]);
        }
        part[w][c0] = pc[0]; part[w][c0 + 1] = pc[1];
        part[w][c0 + 2] = pc[2]; part[w][c0 + 3] = pc[3];
    }
    __syncthreads();
    if (t < HH) {
        float s = bc[t];
        #pragma unroll
        for (int p = 0; p < 16; ++p) s += part[p][t];
        ctx_s[t] = s;
    }
    __syncthreads();

    // scores: wave w handles indices k in [w*32, w*32+32), 64-lane dot each; unroll 4
    {
        const f4v cv = *(const f4v*)(ctx_s + lane * 4);
        #pragma unroll 4
        for (int i = 0; i < 32; ++i) {
            int k = w * 32 + i;
            int id = idx_s[k];
            float sc = -1e9f;
            if (id < NN) {
                s4v v = *(const s4v*)(enc + (size_t)(b * NN + id) * HH + lane * 4);
                float p = cv[0] * b2f(v[0]) + cv[1] * b2f(v[1]) + cv[2] * b2f(v[2]) + cv[3] * b2f(v[3]);
                #pragma unroll
                for (int o = 32; o; o >>= 1) p += __shfl_xor(p, o);
                sc = p;
            }
            if (lane == 0) sc_s[k] = sc;
        }
    }
    __syncthreads();

    // softmax over 512 + round + fix + scatter
    float myv = (t < KSEL) ? sc_s[t] : -1e9f;
    {
        float m = myv;
        #pragma unroll
        for (int o = 32; o; o >>= 1) m = fmaxf(m, __shfl_xor(m, o));
        if (lane == 0) red[w] = m;
        __syncthreads();
        if (t == 0) {
            float mm = red[0];
            #pragma unroll
            for (int i = 1; i < 16; ++i) mm = fmaxf(mm, red[i]);
            smax_s = mm;
        }
        __syncthreads();
    }
    float e = (t < KSEL && idx_s[t] < NN) ? __expf(myv - smax_s) : 0.f;
    {
        float s = e;
        #pragma unroll
        for (int o = 32; o; o >>= 1) s += __shfl_xor(s, o);
        if (lane == 0) red[w] = s;
        __syncthreads();
        if (t == 0) {
            float ss = 0.f;
            #pragma unroll
            for (int i = 0; i < 16; ++i) ss += red[i];
            ssum_s = ss;
        }
        __syncthreads();
    }
    float a = rintf(e * (100.f / ssum_s));
    if (t < KSEL) alloc_s[t] = a;
    {
        float s = (t < KSEL) ? a : 0.f;
        #pragma unroll
        for (int o = 32; o; o >>= 1) s += __shfl_xor(s, o);
        if (lane == 0) red[w] = s;
        __syncthreads();
        if (t == 0) {
            float ss = 0.f;
            #pragma unroll
            for (int i = 0; i < 16; ++i) ss += red[i];
            diff_s = 100.f - ss;
        }
        __syncthreads();
        if (t == 0 && idx_s[0] < NN) alloc_s[0] += diff_s;
    }

    float* bw = out + BB * KSEL + (size_t)b * NN;
    bw[t] = 0.f;                        // 1024 threads cover NN exactly
    __syncthreads();
    if (t < KSEL) {
        int id = idx_s[t];
        out[b * KSEL + t] = (float)id;
        if (id < NN) bw[id] = alloc_s[t];
    }
}

// ---------------- launch ----------------
extern "C" void kernel_launch(void* const* d_in, const int* in_sizes, int n_in,
                              void* d_out, int out_size, void* d_ws, size_t ws_size,
                              hipStream_t stream) {
    const float* x     = (const float*)d_in[0];
    const int*   sel   = (const int*)  d_in[1];
    const float* W_in  = (const float*)d_in[2];
    const float* b_in  = (const float*)d_in[3];
    const float* Wqkv  = (const float*)d_in[4];
    const float* bqkv  = (const float*)d_in[5];
    const float* Wo    = (const float*)d_in[6];
    const float* bo    = (const float*)d_in[7];
    const float* ln1_g = (const float*)d_in[8];
    const float* ln1_b = (const float*)d_in[9];
    const float* W1    = (const float*)d_in[10];
    const float* b1    = (const float*)d_in[11];
    const float* W2    = (const float*)d_in[12];
    const float* b2    = (const float*)d_in[13];
    const float* ln2_g = (const float*)d_in[14];
    const float* ln2_b = (const float*)d_in[15];
    const float* Wc    = (const float*)d_in[16];
    const float* bc    = (const float*)d_in[17];
    float* out = (float*)d_out;

    char* base = (char*)d_ws;
    short* h    = (short*)(base);                       // 8 MB
    short* qkv  = (short*)(base + (8u << 20));          // 24 MB
    short* obuf = (short*)(base + (32u << 20));         // 8 MB
    short* ff   = (short*)(base + (40u << 20));         // 32 MB
    short* xb   = (short*)(base + (76u << 20));         // 2 MB
    short* wt   = (short*)(base + (78u << 20));         // ~3.1 MB
    short* W_inT  = wt;
    short* WqkvT  = W_inT + 256 * 64;
    short* WoT    = WqkvT + LL * 768 * 256;
    short* W1T    = WoT   + LL * 256 * 256;
    short* W2T    = W1T   + LL * 1024 * 256;

    // fused weight transpose + x conversion: 9 segments (1552 tiles) + 1024 cvt blocks
    {
        WtDesc d;
        const float* srcs[9] = { W_in, Wqkv, Wqkv + (size_t)HH * 768, Wo, Wo + (size_t)HH * HH,
                                 W1, W1 + (size_t)HH * FFD, W2, W2 + (size_t)FFD * HH };
        short* dsts[9] = { W_inT, WqkvT, WqkvT + 768 * 256, WoT, WoT + 256 * 256,
                           W1T, W1T + 1024 * 256, W2T, W2T + 256 * 1024 };
        int Ks[9] = { 64, 256, 256, 256, 256, 256, 256, 1024, 1024 };
        int Ns[9] = { 256, 768, 768, 256, 256, 1024, 1024, 256, 256 };
        int tb = 0;
        for (int i = 0; i < 9; ++i) {
            d.src[i] = srcs[i]; d.dst[i] = dsts[i];
            d.K[i] = Ks[i]; d.N[i] = Ns[i]; d.tb[i] = tb;
            tb += (Ks[i] >> 5) * (Ns[i] >> 5);
        }
        d.x = x; d.xb = xb; d.cvt_tb = tb;
        wtrans_all<<<tb + MTOT * DIN / 1024, 256, 0, stream>>>(d);
    }

    // h = x @ W_in + b_in     BN=64: grid 4*128=512
    gemm_mfma<64,0,0><<<512, 256, 0, stream>>>(xb, W_inT, b_in, h, MTOT, DIN, HH, 4, 64);

    for (int l = 0; l < LL; ++l) {
        // qkv projection; Q columns pre-scaled by log2(e)/sqrt(HD).  grid 6*128=768
        gemm_mfma<128,0,1><<<768, 256, 0, stream>>>(
            h, WqkvT + (size_t)l * 768 * HH, bqkv + l * 768, qkv, MTOT, HH, 768, 6, 96);
        attn_mfma<<<BB * NHEAD * 4, 512, 0, stream>>>(qkv, obuf);
        // o-proj + residual + LN1 fused (block per 64 rows, full row width)
        gemm_ln<<<MTOT / 64, 256, 0, stream>>>(
            obuf, WoT + (size_t)l * HH * HH, bo + l * HH, h, ln1_g + l * HH, ln1_b + l * HH, HH);
        gemm_mfma<128,1,0><<<1024, 256, 0, stream>>>(
            h, W1T + (size_t)l * FFD * HH, b1 + l * FFD, ff, MTOT, HH, FFD, 8, 128);
        // ffn2 + residual + LN2 fused
        gemm_ln<<<MTOT / 64, 256, 0, stream>>>(
            ff, W2T + (size_t)l * HH * FFD, b2 + l * HH, h, ln2_g + l * HH, ln2_b + l * HH, FFD);
    }

    alloc_all<<<BB, 1024, 0, stream>>>(h, sel, Wc, bc, out);
}

// Round 10
// 323.605 us; speedup vs baseline: 8.0623x; 1.0149x over previous
//
#include <hip/hip_runtime.h>
#include <math.h>

#define BB 16
#define NN 1024
#define KSEL 512
#define DIN 64
#define HH 256
#define NHEAD 8
#define HD 32
#define LL 2
#define FFD 1024
#define MTOT (BB*NN)   // 16384

typedef __attribute__((ext_vector_type(8))) short s8v;   // 8 bf16
typedef __attribute__((ext_vector_type(4))) short s4v;
typedef __attribute__((ext_vector_type(4))) float f4v;
typedef __attribute__((ext_vector_type(16))) float f16x;

// 1/sqrt(32) * log2(e): QK^T scores land in log2 domain -> native exp2
#define QK_SCALE 0.25503485f

__device__ __forceinline__ float b2f(short u) {
    union { unsigned int i; float f; } v;
    v.i = ((unsigned int)(unsigned short)u) << 16;
    return v.f;
}
__device__ __forceinline__ short f2b(float f) {
    union { float f; unsigned int i; } v;
    v.f = f;
    unsigned int r = v.i + 0x7fffu + ((v.i >> 16) & 1u);
    return (short)(r >> 16);
}
__device__ __forceinline__ unsigned cvtpk_bf16(float a, float b) {
    unsigned r;
    asm("v_cvt_pk_bf16_f32 %0, %1, %2" : "=v"(r) : "v"(a), "v"(b));
    return r;
}

#define GLOAD16(g, l) __builtin_amdgcn_global_load_lds( \
    (const __attribute__((address_space(1))) unsigned int*)(const void*)(g), \
    (__attribute__((address_space(3))) unsigned int*)(l), 16, 0, 0)

// ---------------- fused weight transpose+convert + x-cvt (one launch) ----------------
struct WtDesc {
    const float* src[9];
    short* dst[9];
    int K[9], N[9], tb[9];
    const float* x;       // cvt source
    short* xb;            // cvt dest
    int cvt_tb;           // first cvt block
};
__global__ __launch_bounds__(256) void wtrans_all(WtDesc d) {
    __shared__ float s[32][33];
    const int bid = blockIdx.x;
    if (bid >= d.cvt_tb) {
        int i = (bid - d.cvt_tb) * 256 + threadIdx.x;   // 4-elem chunk index
        f4v v = *(const f4v*)(d.x + (size_t)i * 4);
        s4v o;
        o[0] = f2b(v[0]); o[1] = f2b(v[1]); o[2] = f2b(v[2]); o[3] = f2b(v[3]);
        *(s4v*)(d.xb + (size_t)i * 4) = o;
        return;
    }
    int si = 0;
    #pragma unroll
    for (int i = 1; i < 9; ++i) si = (bid >= d.tb[i]) ? i : si;
    const float* in = d.src[si];
    short* out = d.dst[si];
    const int K = d.K[si], N = d.N[si];
    const int lt = bid - d.tb[si];
    const int tn = N >> 5;
    const int bk = (lt / tn) * 32, bn = (lt % tn) * 32;
    const int c = threadIdx.x & 31, r8 = threadIdx.x >> 5;
    #pragma unroll
    for (int i = 0; i < 4; ++i) {
        int r = r8 + i * 8;
        s[r][c] = in[(size_t)(bk + r) * N + bn + c];
    }
    __syncthreads();
    #pragma unroll
    for (int i = 0; i < 4; ++i) {
        int r = r8 + i * 8;
        out[(size_t)(bn + r) * K + bk + c] = f2b(s[c][r]);
    }
}

// ---------------- bf16 MFMA GEMM: C[M,N] = A[M,K] @ BT[N,K]^T + bias ----------------
// 128xBN tile (BN = 64 or 128), BK=64, 4 waves (2x2), 16x16x32 mfma,
// global_load_lds staging, 8-slot XOR swizzle, chunked XCD swizzle (grid % 8 == 0).
template<int BN, int RELU, int QSCALE>
__global__ __launch_bounds__(256) void gemm_mfma(const short* __restrict__ A,
                                                 const short* __restrict__ BT,
                                                 const float* __restrict__ bias,
                                                 short* __restrict__ C,
                                                 int M, int K, int N,
                                                 int nbx, int cpx) {
    __shared__ __align__(16) short Alds[128 * 64];
    __shared__ __align__(16) short Blds[BN * 64];
    const int tid = threadIdx.x, lane = tid & 63, wid = tid >> 6;
    const int wg = blockIdx.x;
    const int lid = (wg & 7) * cpx + (wg >> 3);
    const int bx = lid % nbx, by = lid / nbx;
    const int bm = by * 128, bn = bx * BN;
    const int wr = wid >> 1, wc = wid & 1;
    const int NF = BN / 32;
    f4v acc[4][NF] = {};

    const short* aB = A + (size_t)bm * K;
    const short* bB = BT + (size_t)bn * K;
    const int frow = lane & 15, fs = lane >> 4;

    for (int k0 = 0; k0 < K; k0 += 64) {
        #pragma unroll
        for (int i = 0; i < 4; ++i) {
            int cb = wid * 64 + i * 256;
            int c = cb + lane;
            int row = c >> 3;
            GLOAD16(aB + (size_t)row * K + k0 + (((c & 7) ^ (row & 7)) * 8), Alds + cb * 8);
        }
        #pragma unroll
        for (int i = 0; i < NF; ++i) {
            int cb = wid * 64 + i * 256;
            int c = cb + lane;
            int row = c >> 3;
            GLOAD16(bB + (size_t)row * K + k0 + (((c & 7) ^ (row & 7)) * 8), Blds + cb * 8);
        }
        __syncthreads();
        #pragma unroll
        for (int kk = 0; kk < 2; ++kk) {
            s8v af[4], bf[NF];
            #pragma unroll
            for (int m = 0; m < 4; ++m) {
                int row = wr * 64 + m * 16 + frow;
                af[m] = *(const s8v*)(Alds + row * 64 + (((kk * 4 + fs) ^ (row & 7)) * 8));
            }
            #pragma unroll
            for (int n = 0; n < NF; ++n) {
                int row = wc * (BN / 2) + n * 16 + frow;
                bf[n] = *(const s8v*)(Blds + row * 64 + (((kk * 4 + fs) ^ (row & 7)) * 8));
            }
            __builtin_amdgcn_s_setprio(1);
            #pragma unroll
            for (int m = 0; m < 4; ++m)
                #pragma unroll
                for (int n = 0; n < NF; ++n)
                    acc[m][n] = __builtin_amdgcn_mfma_f32_16x16x32_bf16(af[m], bf[n], acc[m][n], 0, 0, 0);
            __builtin_amdgcn_s_setprio(0);
        }
        __syncthreads();
    }
    #pragma unroll
    for (int m = 0; m < 4; ++m) {
        int rbase = bm + wr * 64 + m * 16 + (lane >> 4) * 4;
        #pragma unroll
        for (int n = 0; n < NF; ++n) {
            int col = bn + wc * (BN / 2) + n * 16 + (lane & 15);
            float bv = bias[col];
            #pragma unroll
            for (int r = 0; r < 4; ++r) {
                float v = acc[m][n][r] + bv;
                if (QSCALE) { if (col < 256) v *= QK_SCALE; }
                if (RELU) v = fmaxf(v, 0.f);
                C[(size_t)(rbase + r) * N + col] = f2b(v);
            }
        }
    }
}

// ---------------- fused GEMM + residual + LayerNorm (8 waves) ----------------
// BM=64, BN=256 (= full row), BK=64, 8 waves (2 row x 4 col), 2-phase dbuf.
// h = LN(h + A@BT^T + bias) * g + beta, written in place to h.
// 512 threads: grid 256 blocks = 1 block/CU -> 8 waves/CU (was 4).
__global__ __launch_bounds__(512) void gemm_ln(const short* __restrict__ A,
                                               const short* __restrict__ BT,
                                               const float* __restrict__ bias,
                                               short* __restrict__ h,
                                               const float* __restrict__ g,
                                               const float* __restrict__ beta,
                                               int K) {
    __shared__ __align__(16) short Alds[2][64 * 64];
    __shared__ __align__(16) short Blds[2][256 * 64];
    __shared__ float lred[64][4][2];   // [row][wc][{sum, sumsq}]
    const int tid = threadIdx.x, lane = tid & 63, wid = tid >> 6;
    const int wr = wid >> 2, wc = wid & 3;     // 2 x 4 wave grid
    const int bm = blockIdx.x * 64;
    const int frow = lane & 15, fs = lane >> 4;
    f4v acc[2][4] = {};

    const short* aB = A + (size_t)bm * K;

    // stage A: 1 round of 512 x 16B; B: 4 rounds
    #define STAGE_AB(buf, k0)                                                            \
        {                                                                                \
            {                                                                            \
                int u = tid;                                                             \
                int row = u >> 3;                                                        \
                GLOAD16(aB + (size_t)row * K + (k0) + (((u & 7) ^ (row & 7)) * 8),       \
                        Alds[buf] + u * 8);                                              \
            }                                                                            \
            _Pragma("unroll")                                                            \
            for (int i = 0; i < 4; ++i) {                                                \
                int u = i * 512 + tid;                                                   \
                int row = u >> 3;                                                        \
                GLOAD16(BT + (size_t)row * K + (k0) + (((u & 7) ^ (row & 7)) * 8),       \
                        Blds[buf] + u * 8);                                              \
            }                                                                            \
        }

    STAGE_AB(0, 0);
    __syncthreads();
    int cur = 0;
    for (int k0 = 0; k0 < K; k0 += 64) {
        if (k0 + 64 < K) STAGE_AB(cur ^ 1, k0 + 64);
        #pragma unroll
        for (int kk = 0; kk < 2; ++kk) {
            s8v af[2], bf[4];
            #pragma unroll
            for (int m = 0; m < 2; ++m) {
                int row = wr * 32 + m * 16 + frow;
                af[m] = *(const s8v*)(Alds[cur] + row * 64 + (((kk * 4 + fs) ^ (row & 7)) * 8));
            }
            #pragma unroll
            for (int n = 0; n < 4; ++n) {
                int row = wc * 64 + n * 16 + frow;
                bf[n] = *(const s8v*)(Blds[cur] + row * 64 + (((kk * 4 + fs) ^ (row & 7)) * 8));
            }
            __builtin_amdgcn_s_setprio(1);
            #pragma unroll
            for (int m = 0; m < 2; ++m)
                #pragma unroll
                for (int n = 0; n < 4; ++n)
                    acc[m][n] = __builtin_amdgcn_mfma_f32_16x16x32_bf16(af[m], bf[n], acc[m][n], 0, 0, 0);
            __builtin_amdgcn_s_setprio(0);
        }
        __syncthreads();
        cur ^= 1;
    }
    #undef STAGE_AB

    // epilogue: v = acc + bias + h; row stats; LN write
    float s1[2][4], s2[2][4];
    #pragma unroll
    for (int m = 0; m < 2; ++m) {
        #pragma unroll
        for (int r = 0; r < 4; ++r) { s1[m][r] = 0.f; s2[m][r] = 0.f; }
    }
    #pragma unroll
    for (int m = 0; m < 2; ++m) {
        #pragma unroll
        for (int n = 0; n < 4; ++n) {
            int gc = wc * 64 + n * 16 + frow;
            float bv = bias[gc];
            #pragma unroll
            for (int r = 0; r < 4; ++r) {
                int gr = bm + wr * 32 + m * 16 + fs * 4 + r;
                float v = acc[m][n][r] + bv + b2f(h[(size_t)gr * HH + gc]);
                acc[m][n][r] = v;
                s1[m][r] += v;
                s2[m][r] += v * v;
            }
        }
    }
    #pragma unroll
    for (int m = 0; m < 2; ++m) {
        #pragma unroll
        for (int r = 0; r < 4; ++r) {
            float a = s1[m][r], bq = s2[m][r];
            #pragma unroll
            for (int off = 1; off < 16; off <<= 1) {   // reduce over frow (within 16-lane group)
                a += __shfl_xor(a, off);
                bq += __shfl_xor(bq, off);
            }
            if (frow == 0) {
                int lr = wr * 32 + m * 16 + fs * 4 + r;
                lred[lr][wc][0] = a;
                lred[lr][wc][1] = bq;
            }
        }
    }
    __syncthreads();
    #pragma unroll
    for (int m = 0; m < 2; ++m) {
        #pragma unroll
        for (int r = 0; r < 4; ++r) {
            int lr = wr * 32 + m * 16 + fs * 4 + r;
            float t1 = lred[lr][0][0] + lred[lr][1][0] + lred[lr][2][0] + lred[lr][3][0];
            float t2 = lred[lr][0][1] + lred[lr][1][1] + lred[lr][2][1] + lred[lr][3][1];
            float mean = t1 * (1.f / HH);
            float var = t2 * (1.f / HH) - mean * mean;
            float rs = rsqrtf(var + 1e-5f);
            int gr = bm + lr;
            #pragma unroll
            for (int n = 0; n < 4; ++n) {
                int gc = wc * 64 + n * 16 + frow;
                h[(size_t)gr * HH + gc] = f2b((acc[m][n][r] - mean) * rs * g[gc] + beta[gc]);
            }
        }
    }
}

// ---------------- MFMA flash attention (swapped QK^T, no-max softmax) ----------------
// 512 thr = 8 waves; wave w: 32 q rows; q-tile 256; KV tile 128 tokens, double-buffered.
// Q pre-scaled by log2(e)/sqrt(HD) -> scores in log2 domain, |s| <~ 5 for LN'd
// activations, so p = exp2(s) directly (softmax is shift-invariant; fp32 exp2
// safe to s=127). Kills max-tree / defer-branch / rescale / subtract.
__global__ __launch_bounds__(512) void attn_mfma(const short* __restrict__ qkv,
                                                 short* __restrict__ o) {
    __shared__ __align__(16) short Klds[2][4][128][8];   // [buf][hd-chunk][token][8hd]
    __shared__ __align__(16) short Vlds[2][32][136];     // [buf][d][token padded, 16B-aligned]
    const int tid = threadIdx.x, lane = tid & 63, wid = tid >> 6;
    const int hi = lane >> 5, lq = lane & 31;
    const int wg = blockIdx.x;
    const int lid = (wg & 7) * 64 + (wg >> 3);   // chunked XCD swizzle
    const int qt = lid & 3;
    const int h  = (lid >> 2) & 7;
    const int b  = lid >> 5;
    const int q0 = qt * 256 + wid * 32;
    const short* qkvb = qkv + (size_t)b * NN * 768;

    s8v qf0, qf1;
    {
        const short* qrow = qkvb + (size_t)(q0 + lq) * 768 + h * 32 + hi * 8;
        qf0 = *(const s8v*)qrow;
        qf1 = *(const s8v*)(qrow + 16);
    }

    const int token = tid & 127, cK = tid >> 7, dc = cK * 8;
    const f16x fz = {};

    float l = 0.f;
    f16x acc = {};

    {   // prologue: stage tile 0
        const short* kvrow = qkvb + (size_t)token * 768 + 256 + h * 32;
        GLOAD16(kvrow + cK * 8, &Klds[0][cK][token][0]);
        s8v vv = *(const s8v*)(kvrow + 256 + dc);
        #pragma unroll
        for (int j = 0; j < 8; ++j) Vlds[0][dc + j][token] = vv[j];
    }
    __syncthreads();

    for (int t = 0; t < 8; ++t) {
        const int bb = t & 1;
        s8v vvn;
        if (t < 7) {
            const short* kvrow = qkvb + (size_t)((t + 1) * 128 + token) * 768 + 256 + h * 32;
            GLOAD16(kvrow + cK * 8, &Klds[bb ^ 1][cK][token][0]);
            vvn = *(const s8v*)(kvrow + 256 + dc);
        }
        #pragma unroll
        for (int kt = 0; kt < 4; ++kt) {
            const s8v kf0 = *(const s8v*)&Klds[bb][hi][kt * 32 + lq][0];
            const s8v kf1 = *(const s8v*)&Klds[bb][2 + hi][kt * 32 + lq][0];
            __builtin_amdgcn_s_setprio(1);
            f16x p = __builtin_amdgcn_mfma_f32_32x32x16_bf16(kf0, qf0, fz, 0, 0, 0);
            p = __builtin_amdgcn_mfma_f32_32x32x16_bf16(kf1, qf1, p, 0, 0, 0);
            __builtin_amdgcn_s_setprio(0);
            float l0 = 0.f, l1 = 0.f, l2 = 0.f, l3 = 0.f;
            #pragma unroll
            for (int r = 0; r < 16; r += 4) {
                p[r]     = __builtin_amdgcn_exp2f(p[r]);     l0 += p[r];
                p[r + 1] = __builtin_amdgcn_exp2f(p[r + 1]); l1 += p[r + 1];
                p[r + 2] = __builtin_amdgcn_exp2f(p[r + 2]); l2 += p[r + 2];
                p[r + 3] = __builtin_amdgcn_exp2f(p[r + 3]); l3 += p[r + 3];
            }
            l += (l0 + l1) + (l2 + l3);
            unsigned w[8];
            #pragma unroll
            for (int i = 0; i < 8; ++i) w[i] = cvtpk_bf16(p[2 * i], p[2 * i + 1]);
            asm volatile("v_permlane32_swap_b32 %0, %1" : "+v"(w[0]), "+v"(w[2]));
            asm volatile("v_permlane32_swap_b32 %0, %1" : "+v"(w[1]), "+v"(w[3]));
            asm volatile("v_permlane32_swap_b32 %0, %1" : "+v"(w[4]), "+v"(w[6]));
            asm volatile("v_permlane32_swap_b32 %0, %1" : "+v"(w[5]), "+v"(w[7]));
            union { unsigned u[4]; s8v v; } pa0, pa1;
            pa0.u[0] = w[0]; pa0.u[1] = w[1]; pa0.u[2] = w[2]; pa0.u[3] = w[3];
            pa1.u[0] = w[4]; pa1.u[1] = w[5]; pa1.u[2] = w[6]; pa1.u[3] = w[7];
            const s8v vf0 = *(const s8v*)&Vlds[bb][lq][kt * 32 + hi * 8];
            const s8v vf1 = *(const s8v*)&Vlds[bb][lq][kt * 32 + 16 + hi * 8];
            __builtin_amdgcn_s_setprio(1);
            acc = __builtin_amdgcn_mfma_f32_32x32x16_bf16(pa0.v, vf0, acc, 0, 0, 0);
            acc = __builtin_amdgcn_mfma_f32_32x32x16_bf16(pa1.v, vf1, acc, 0, 0, 0);
            __builtin_amdgcn_s_setprio(0);
        }
        if (t < 7) {
            #pragma unroll
            for (int j = 0; j < 8; ++j) Vlds[bb ^ 1][dc + j][token] = vvn[j];
        }
        __syncthreads();
    }

    l += __shfl_xor(l, 32);
    float inv = 1.f / l;
    short* ob = o + ((size_t)(b * NN + q0)) * HH + h * 32 + lq;
    #pragma unroll
    for (int r = 0; r < 16; ++r) {
        int qr = (r & 3) + 8 * (r >> 2) + 4 * hi;
        float invr = __shfl(inv, qr);
        ob[(size_t)qr * HH] = f2b(acc[r] * invr);
    }
}

// ---------------- fused allocation: all stages, latency-tuned (block per batch) ----------------
__global__ __launch_bounds__(1024) void alloc_all(const short* __restrict__ enc,
                                                  const int* __restrict__ idx,
                                                  const float* __restrict__ Wc,
                                                  const float* __restrict__ bc,
                                                  float* __restrict__ out) {
    __shared__ float part[16][HH];     // 16 KB; reused: gather partials, then ctx partials
    __shared__ float mean_s[HH];
    __shared__ float ctx_s[HH];
    __shared__ float sc_s[KSEL];
    __shared__ float alloc_s[KSEL];
    __shared__ int   idx_s[KSEL];
    __shared__ float red[16];
    __shared__ float cnt_s, smax_s, ssum_s, diff_s;
    const int b = blockIdx.x, t = threadIdx.x;
    const int w = t >> 6, lane = t & 63;

    if (t < KSEL) idx_s[t] = idx[b * KSEL + t];
    __syncthreads();

    // count valid
    {
        float c = (t < KSEL && idx_s[t] < NN) ? 1.f : 0.f;
        #pragma unroll
        for (int o = 32; o; o >>= 1) c += __shfl_xor(c, o);
        if (lane == 0) red[w] = c;
    }
    // gather partial sums: wave w handles k in [w*32, w*32+32), lane covers 4 cols
    {
        const int c0 = lane * 4;
        float s0 = 0.f, s1 = 0.f, s2 = 0.f, s3 = 0.f;
        #pragma unroll
        for (int i = 0; i < 32; ++i) {
            int id = idx_s[w * 32 + i];
            if (id < NN) {
                s4v v = *(const s4v*)(enc + (size_t)(b * NN + id) * HH + c0);
                s0 += b2f(v[0]); s1 += b2f(v[1]); s2 += b2f(v[2]); s3 += b2f(v[3]);
            }
        }
        part[w][c0] = s0; part[w][c0 + 1] = s1; part[w][c0 + 2] = s2; part[w][c0 + 3] = s3;
    }
    __syncthreads();
    if (t == 0) {
        float s = 0.f;
        #pragma unroll
        for (int i = 0; i < 16; ++i) s += red[i];
        cnt_s = fmaxf(s, 1.f);
    }
    __syncthreads();
    if (t < HH) {
        float s = 0.f;
        #pragma unroll
        for (int p = 0; p < 16; ++p) s += part[p][t];
        mean_s[t] = s / cnt_s;
    }
    __syncthreads();

    // ctx GEMV, wave-parallel: wave w covers j in [w*16, w*16+16); lane covers 4 cols.
    {
        const int c0 = lane * 4;
        f4v pc = {};
        #pragma unroll
        for (int jj = 0; jj < 16; ++jj) {
            int j = w * 16 + jj;
            float mj = mean_s[j];
            const f4v wr = *(const f4v*)(Wc + (size_t)j * HH + c0);
            pc[0] = fmaf(mj, wr[0], pc[0]);
            pc[1] = fmaf(mj, wr[1], pc[1]);
            pc[2] = fmaf(mj, wr[2], pc[2]);
            pc[3] = fmaf(mj, wr[3], pc[3]);
        }
        part[w][c0] = pc[0]; part[w][c0 + 1] = pc[1];
        part[w][c0 + 2] = pc[2]; part[w][c0 + 3] = pc[3];
    }
    __syncthreads();
    if (t < HH) {
        float s = bc[t];
        #pragma unroll
        for (int p = 0; p < 16; ++p) s += part[p][t];
        ctx_s[t] = s;
    }
    __syncthreads();

    // scores: wave w handles indices k in [w*32, w*32+32), 64-lane dot each; unroll 4
    {
        const f4v cv = *(const f4v*)(ctx_s + lane * 4);
        #pragma unroll 4
        for (int i = 0; i < 32; ++i) {
            int k = w * 32 + i;
            int id = idx_s[k];
            float sc = -1e9f;
            if (id < NN) {
                s4v v = *(const s4v*)(enc + (size_t)(b * NN + id) * HH + lane * 4);
                float p = cv[0] * b2f(v[0]) + cv[1] * b2f(v[1]) + cv[2] * b2f(v[2]) + cv[3] * b2f(v[3]);
                #pragma unroll
                for (int o = 32; o; o >>= 1) p += __shfl_xor(p, o);
                sc = p;
            }
            if (lane == 0) sc_s[k] = sc;
        }
    }
    __syncthreads();

    // softmax over 512 + round + fix + scatter
    float myv = (t < KSEL) ? sc_s[t] : -1e9f;
    {
        float m = myv;
        #pragma unroll
        for (int o = 32; o; o >>= 1) m = fmaxf(m, __shfl_xor(m, o));
        if (lane == 0) red[w] = m;
        __syncthreads();
        if (t == 0) {
            float mm = red[0];
            #pragma unroll
            for (int i = 1; i < 16; ++i) mm = fmaxf(mm, red[i]);
            smax_s = mm;
        }
        __syncthreads();
    }
    float e = (t < KSEL && idx_s[t] < NN) ? __expf(myv - smax_s) : 0.f;
    {
        float s = e;
        #pragma unroll
        for (int o = 32; o; o >>= 1) s += __shfl_xor(s, o);
        if (lane == 0) red[w] = s;
        __syncthreads();
        if (t == 0) {
            float ss = 0.f;
            #pragma unroll
            for (int i = 0; i < 16; ++i) ss += red[i];
            ssum_s = ss;
        }
        __syncthreads();
    }
    float a = rintf(e * (100.f / ssum_s));
    if (t < KSEL) alloc_s[t] = a;
    {
        float s = (t < KSEL) ? a : 0.f;
        #pragma unroll
        for (int o = 32; o; o >>= 1) s += __shfl_xor(s, o);
        if (lane == 0) red[w] = s;
        __syncthreads();
        if (t == 0) {
            float ss = 0.f;
            #pragma unroll
            for (int i = 0; i < 16; ++i) ss += red[i];
            diff_s = 100.f - ss;
        }
        __syncthreads();
        if (t == 0 && idx_s[0] < NN) alloc_s[0] += diff_s;
    }

    float* bw = out + BB * KSEL + (size_t)b * NN;
    bw[t] = 0.f;                        // 1024 threads cover NN exactly
    __syncthreads();
    if (t < KSEL) {
        int id = idx_s[t];
        out[b * KSEL + t] = (float)id;
        if (id < NN) bw[id] = alloc_s[t];
    }
}

// ---------------- launch ----------------
extern "C" void kernel_launch(void* const* d_in, const int* in_sizes, int n_in,
                              void* d_out, int out_size, void* d_ws, size_t ws_size,
                              hipStream_t stream) {
    const float* x     = (const float*)d_in[0];
    const int*   sel   = (const int*)  d_in[1];
    const float* W_in  = (const float*)d_in[2];
    const float* b_in  = (const float*)d_in[3];
    const float* Wqkv  = (const float*)d_in[4];
    const float* bqkv  = (const float*)d_in[5];
    const float* Wo    = (const float*)d_in[6];
    const float* bo    = (const float*)d_in[7];
    const float* ln1_g = (const float*)d_in[8];
    const float* ln1_b = (const float*)d_in[9];
    const float* W1    = (const float*)d_in[10];
    const float* b1    = (const float*)d_in[11];
    const float* W2    = (const float*)d_in[12];
    const float* b2    = (const float*)d_in[13];
    const float* ln2_g = (const float*)d_in[14];
    const float* ln2_b = (const float*)d_in[15];
    const float* Wc    = (const float*)d_in[16];
    const float* bc    = (const float*)d_in[17];
    float* out = (float*)d_out;

    char* base = (char*)d_ws;
    short* h    = (short*)(base);                       // 8 MB
    short* qkv  = (short*)(base + (8u << 20));          // 24 MB
    short* obuf = (short*)(base + (32u << 20));         // 8 MB
    short* ff   = (short*)(base + (40u << 20));         // 32 MB
    short* xb   = (short*)(base + (76u << 20));         // 2 MB
    short* wt   = (short*)(base + (78u << 20));         // ~3.1 MB
    short* W_inT  = wt;
    short* WqkvT  = W_inT + 256 * 64;
    short* WoT    = WqkvT + LL * 768 * 256;
    short* W1T    = WoT   + LL * 256 * 256;
    short* W2T    = W1T   + LL * 1024 * 256;

    // fused weight transpose + x conversion: 9 segments (1552 tiles) + 1024 cvt blocks
    {
        WtDesc d;
        const float* srcs[9] = { W_in, Wqkv, Wqkv + (size_t)HH * 768, Wo, Wo + (size_t)HH * HH,
                                 W1, W1 + (size_t)HH * FFD, W2, W2 + (size_t)FFD * HH };
        short* dsts[9] = { W_inT, WqkvT, WqkvT + 768 * 256, WoT, WoT + 256 * 256,
                           W1T, W1T + 1024 * 256, W2T, W2T + 256 * 1024 };
        int Ks[9] = { 64, 256, 256, 256, 256, 256, 256, 1024, 1024 };
        int Ns[9] = { 256, 768, 768, 256, 256, 1024, 1024, 256, 256 };
        int tb = 0;
        for (int i = 0; i < 9; ++i) {
            d.src[i] = srcs[i]; d.dst[i] = dsts[i];
            d.K[i] = Ks[i]; d.N[i] = Ns[i]; d.tb[i] = tb;
            tb += (Ks[i] >> 5) * (Ns[i] >> 5);
        }
        d.x = x; d.xb = xb; d.cvt_tb = tb;
        wtrans_all<<<tb + MTOT * DIN / 1024, 256, 0, stream>>>(d);
    }

    // h = x @ W_in + b_in     BN=64: grid 4*128=512
    gemm_mfma<64,0,0><<<512, 256, 0, stream>>>(xb, W_inT, b_in, h, MTOT, DIN, HH, 4, 64);

    for (int l = 0; l < LL; ++l) {
        // qkv projection; Q columns pre-scaled by log2(e)/sqrt(HD).  grid 6*128=768
        gemm_mfma<128,0,1><<<768, 256, 0, stream>>>(
            h, WqkvT + (size_t)l * 768 * HH, bqkv + l * 768, qkv, MTOT, HH, 768, 6, 96);
        attn_mfma<<<BB * NHEAD * 4, 512, 0, stream>>>(qkv, obuf);
        // o-proj + residual + LN1 fused (block per 64 rows, full row width, 8 waves)
        gemm_ln<<<MTOT / 64, 512, 0, stream>>>(
            obuf, WoT + (size_t)l * HH * HH, bo + l * HH, h, ln1_g + l * HH, ln1_b + l * HH, HH);
        gemm_mfma<128,1,0><<<1024, 256, 0, stream>>>(
            h, W1T + (size_t)l * FFD * HH, b1 + l * FFD, ff, MTOT, HH, FFD, 8, 128);
        // ffn2 + residual + LN2 fused
        gemm_ln<<<MTOT / 64, 512, 0, stream>>>(
            ff, W2T + (size_t)l * HH * FFD, b2 + l * HH, h, ln2_g + l * HH, ln2_b + l * HH, FFD);
    }

    alloc_all<<<BB, 1024, 0, stream>>>(h, sel, Wc, bc, out);
}

// Round 11
// 323.339 us; speedup vs baseline: 8.0689x; 1.0008x over previous
//
#include <hip/hip_runtime.h>
#include <math.h>

#define BB 16
#define NN 1024
#define KSEL 512
#define DIN 64
#define HH 256
#define NHEAD 8
#define HD 32
#define LL 2
#define FFD 1024
#define MTOT (BB*NN)   // 16384

typedef __attribute__((ext_vector_type(8))) short s8v;   // 8 bf16
typedef __attribute__((ext_vector_type(4))) short s4v;
typedef __attribute__((ext_vector_type(4))) float f4v;
typedef __attribute__((ext_vector_type(16))) float f16x;

// 1/sqrt(32) * log2(e): QK^T scores land in log2 domain -> native exp2
#define QK_SCALE 0.25503485f

__device__ __forceinline__ float b2f(short u) {
    union { unsigned int i; float f; } v;
    v.i = ((unsigned int)(unsigned short)u) << 16;
    return v.f;
}
__device__ __forceinline__ short f2b(float f) {
    union { float f; unsigned int i; } v;
    v.f = f;
    unsigned int r = v.i + 0x7fffu + ((v.i >> 16) & 1u);
    return (short)(r >> 16);
}
__device__ __forceinline__ unsigned cvtpk_bf16(float a, float b) {
    unsigned r;
    asm("v_cvt_pk_bf16_f32 %0, %1, %2" : "=v"(r) : "v"(a), "v"(b));
    return r;
}

#define GLOAD16(g, l) __builtin_amdgcn_global_load_lds( \
    (const __attribute__((address_space(1))) unsigned int*)(const void*)(g), \
    (__attribute__((address_space(3))) unsigned int*)(l), 16, 0, 0)

// ---------------- fused weight transpose+convert + x-cvt (one launch) ----------------
struct WtDesc {
    const float* src[9];
    short* dst[9];
    int K[9], N[9], tb[9];
    const float* x;       // cvt source
    short* xb;            // cvt dest
    int cvt_tb;           // first cvt block
};
__global__ __launch_bounds__(256) void wtrans_all(WtDesc d) {
    __shared__ float s[32][33];
    const int bid = blockIdx.x;
    if (bid >= d.cvt_tb) {
        int i = (bid - d.cvt_tb) * 256 + threadIdx.x;   // 4-elem chunk index
        f4v v = *(const f4v*)(d.x + (size_t)i * 4);
        s4v o;
        o[0] = f2b(v[0]); o[1] = f2b(v[1]); o[2] = f2b(v[2]); o[3] = f2b(v[3]);
        *(s4v*)(d.xb + (size_t)i * 4) = o;
        return;
    }
    int si = 0;
    #pragma unroll
    for (int i = 1; i < 9; ++i) si = (bid >= d.tb[i]) ? i : si;
    const float* in = d.src[si];
    short* out = d.dst[si];
    const int K = d.K[si], N = d.N[si];
    const int lt = bid - d.tb[si];
    const int tn = N >> 5;
    const int bk = (lt / tn) * 32, bn = (lt % tn) * 32;
    const int c = threadIdx.x & 31, r8 = threadIdx.x >> 5;
    #pragma unroll
    for (int i = 0; i < 4; ++i) {
        int r = r8 + i * 8;
        s[r][c] = in[(size_t)(bk + r) * N + bn + c];
    }
    __syncthreads();
    #pragma unroll
    for (int i = 0; i < 4; ++i) {
        int r = r8 + i * 8;
        out[(size_t)(bn + r) * K + bk + c] = f2b(s[c][r]);
    }
}

// ---------------- bf16 MFMA GEMM: C[M,N] = A[M,K] @ BT[N,K]^T + bias ----------------
// 128xBN tile (BN = 64 or 128), BK=64, 4 waves (2x2), 16x16x32 mfma,
// global_load_lds staging, 8-slot XOR swizzle, chunked XCD swizzle (grid % 8 == 0).
template<int BN, int RELU, int QSCALE>
__global__ __launch_bounds__(256) void gemm_mfma(const short* __restrict__ A,
                                                 const short* __restrict__ BT,
                                                 const float* __restrict__ bias,
                                                 short* __restrict__ C,
                                                 int M, int K, int N,
                                                 int nbx, int cpx) {
    __shared__ __align__(16) short Alds[128 * 64];
    __shared__ __align__(16) short Blds[BN * 64];
    const int tid = threadIdx.x, lane = tid & 63, wid = tid >> 6;
    const int wg = blockIdx.x;
    const int lid = (wg & 7) * cpx + (wg >> 3);
    const int bx = lid % nbx, by = lid / nbx;
    const int bm = by * 128, bn = bx * BN;
    const int wr = wid >> 1, wc = wid & 1;
    const int NF = BN / 32;
    f4v acc[4][NF] = {};

    const short* aB = A + (size_t)bm * K;
    const short* bB = BT + (size_t)bn * K;
    const int frow = lane & 15, fs = lane >> 4;

    for (int k0 = 0; k0 < K; k0 += 64) {
        #pragma unroll
        for (int i = 0; i < 4; ++i) {
            int cb = wid * 64 + i * 256;
            int c = cb + lane;
            int row = c >> 3;
            GLOAD16(aB + (size_t)row * K + k0 + (((c & 7) ^ (row & 7)) * 8), Alds + cb * 8);
        }
        #pragma unroll
        for (int i = 0; i < NF; ++i) {
            int cb = wid * 64 + i * 256;
            int c = cb + lane;
            int row = c >> 3;
            GLOAD16(bB + (size_t)row * K + k0 + (((c & 7) ^ (row & 7)) * 8), Blds + cb * 8);
        }
        __syncthreads();
        #pragma unroll
        for (int kk = 0; kk < 2; ++kk) {
            s8v af[4], bf[NF];
            #pragma unroll
            for (int m = 0; m < 4; ++m) {
                int row = wr * 64 + m * 16 + frow;
                af[m] = *(const s8v*)(Alds + row * 64 + (((kk * 4 + fs) ^ (row & 7)) * 8));
            }
            #pragma unroll
            for (int n = 0; n < NF; ++n) {
                int row = wc * (BN / 2) + n * 16 + frow;
                bf[n] = *(const s8v*)(Blds + row * 64 + (((kk * 4 + fs) ^ (row & 7)) * 8));
            }
            __builtin_amdgcn_s_setprio(1);
            #pragma unroll
            for (int m = 0; m < 4; ++m)
                #pragma unroll
                for (int n = 0; n < NF; ++n)
                    acc[m][n] = __builtin_amdgcn_mfma_f32_16x16x32_bf16(af[m], bf[n], acc[m][n], 0, 0, 0);
            __builtin_amdgcn_s_setprio(0);
        }
        __syncthreads();
    }
    #pragma unroll
    for (int m = 0; m < 4; ++m) {
        int rbase = bm + wr * 64 + m * 16 + (lane >> 4) * 4;
        #pragma unroll
        for (int n = 0; n < NF; ++n) {
            int col = bn + wc * (BN / 2) + n * 16 + (lane & 15);
            float bv = bias[col];
            #pragma unroll
            for (int r = 0; r < 4; ++r) {
                float v = acc[m][n][r] + bv;
                if (QSCALE) { if (col < 256) v *= QK_SCALE; }
                if (RELU) v = fmaxf(v, 0.f);
                C[(size_t)(rbase + r) * N + col] = f2b(v);
            }
        }
    }
}

// ---------------- fused GEMM + residual + LayerNorm (8 waves) ----------------
// BM=64, BN=256 (= full row), BK=64, 8 waves (2 row x 4 col), 2-phase dbuf.
// h = LN(h + A@BT^T + bias) * g + beta, written in place to h.
__global__ __launch_bounds__(512) void gemm_ln(const short* __restrict__ A,
                                               const short* __restrict__ BT,
                                               const float* __restrict__ bias,
                                               short* __restrict__ h,
                                               const float* __restrict__ g,
                                               const float* __restrict__ beta,
                                               int K) {
    __shared__ __align__(16) short Alds[2][64 * 64];
    __shared__ __align__(16) short Blds[2][256 * 64];
    __shared__ float lred[64][4][2];   // [row][wc][{sum, sumsq}]
    const int tid = threadIdx.x, lane = tid & 63, wid = tid >> 6;
    const int wr = wid >> 2, wc = wid & 3;     // 2 x 4 wave grid
    const int bm = blockIdx.x * 64;
    const int frow = lane & 15, fs = lane >> 4;
    f4v acc[2][4] = {};

    const short* aB = A + (size_t)bm * K;

    // stage A: 1 round of 512 x 16B; B: 4 rounds
    #define STAGE_AB(buf, k0)                                                            \
        {                                                                                \
            {                                                                            \
                int u = tid;                                                             \
                int row = u >> 3;                                                        \
                GLOAD16(aB + (size_t)row * K + (k0) + (((u & 7) ^ (row & 7)) * 8),       \
                        Alds[buf] + u * 8);                                              \
            }                                                                            \
            _Pragma("unroll")                                                            \
            for (int i = 0; i < 4; ++i) {                                                \
                int u = i * 512 + tid;                                                   \
                int row = u >> 3;                                                        \
                GLOAD16(BT + (size_t)row * K + (k0) + (((u & 7) ^ (row & 7)) * 8),       \
                        Blds[buf] + u * 8);                                              \
            }                                                                            \
        }

    STAGE_AB(0, 0);
    __syncthreads();
    int cur = 0;
    for (int k0 = 0; k0 < K; k0 += 64) {
        if (k0 + 64 < K) STAGE_AB(cur ^ 1, k0 + 64);
        #pragma unroll
        for (int kk = 0; kk < 2; ++kk) {
            s8v af[2], bf[4];
            #pragma unroll
            for (int m = 0; m < 2; ++m) {
                int row = wr * 32 + m * 16 + frow;
                af[m] = *(const s8v*)(Alds[cur] + row * 64 + (((kk * 4 + fs) ^ (row & 7)) * 8));
            }
            #pragma unroll
            for (int n = 0; n < 4; ++n) {
                int row = wc * 64 + n * 16 + frow;
                bf[n] = *(const s8v*)(Blds[cur] + row * 64 + (((kk * 4 + fs) ^ (row & 7)) * 8));
            }
            __builtin_amdgcn_s_setprio(1);
            #pragma unroll
            for (int m = 0; m < 2; ++m)
                #pragma unroll
                for (int n = 0; n < 4; ++n)
                    acc[m][n] = __builtin_amdgcn_mfma_f32_16x16x32_bf16(af[m], bf[n], acc[m][n], 0, 0, 0);
            __builtin_amdgcn_s_setprio(0);
        }
        __syncthreads();
        cur ^= 1;
    }
    #undef STAGE_AB

    // epilogue: v = acc + bias + h; row stats; LN write
    float s1[2][4], s2[2][4];
    #pragma unroll
    for (int m = 0; m < 2; ++m) {
        #pragma unroll
        for (int r = 0; r < 4; ++r) { s1[m][r] = 0.f; s2[m][r] = 0.f; }
    }
    #pragma unroll
    for (int m = 0; m < 2; ++m) {
        #pragma unroll
        for (int n = 0; n < 4; ++n) {
            int gc = wc * 64 + n * 16 + frow;
            float bv = bias[gc];
            #pragma unroll
            for (int r = 0; r < 4; ++r) {
                int gr = bm + wr * 32 + m * 16 + fs * 4 + r;
                float v = acc[m][n][r] + bv + b2f(h[(size_t)gr * HH + gc]);
                acc[m][n][r] = v;
                s1[m][r] += v;
                s2[m][r] += v * v;
            }
        }
    }
    #pragma unroll
    for (int m = 0; m < 2; ++m) {
        #pragma unroll
        for (int r = 0; r < 4; ++r) {
            float a = s1[m][r], bq = s2[m][r];
            #pragma unroll
            for (int off = 1; off < 16; off <<= 1) {   // reduce over frow (within 16-lane group)
                a += __shfl_xor(a, off);
                bq += __shfl_xor(bq, off);
            }
            if (frow == 0) {
                int lr = wr * 32 + m * 16 + fs * 4 + r;
                lred[lr][wc][0] = a;
                lred[lr][wc][1] = bq;
            }
        }
    }
    __syncthreads();
    #pragma unroll
    for (int m = 0; m < 2; ++m) {
        #pragma unroll
        for (int r = 0; r < 4; ++r) {
            int lr = wr * 32 + m * 16 + fs * 4 + r;
            float t1 = lred[lr][0][0] + lred[lr][1][0] + lred[lr][2][0] + lred[lr][3][0];
            float t2 = lred[lr][0][1] + lred[lr][1][1] + lred[lr][2][1] + lred[lr][3][1];
            float mean = t1 * (1.f / HH);
            float var = t2 * (1.f / HH) - mean * mean;
            float rs = rsqrtf(var + 1e-5f);
            int gr = bm + lr;
            #pragma unroll
            for (int n = 0; n < 4; ++n) {
                int gc = wc * 64 + n * 16 + frow;
                h[(size_t)gr * HH + gc] = f2b((acc[m][n][r] - mean) * rs * g[gc] + beta[gc]);
            }
        }
    }
}

// ---------------- MFMA flash attention (swapped QK^T, no-max softmax) ----------------
// 512 thr = 8 waves; wave w: 32 q rows; q-tile 256; KV tile 128 tokens, double-buffered.
// Softmax denominator computed on the MATRIX pipe: l_acc = mfma(P, ones) accumulates
// sum_k P per q-row in the same fragment-row layout as the O accumulator -> lane-local
// normalize, zero cross-lane reduction, and no VALU add-chain in the hot loop.
__global__ __launch_bounds__(512) void attn_mfma(const short* __restrict__ qkv,
                                                 short* __restrict__ o) {
    __shared__ __align__(16) short Klds[2][4][128][8];   // [buf][hd-chunk][token][8hd]
    __shared__ __align__(16) short Vlds[2][32][136];     // [buf][d][token padded, 16B-aligned]
    const int tid = threadIdx.x, lane = tid & 63, wid = tid >> 6;
    const int hi = lane >> 5, lq = lane & 31;
    const int wg = blockIdx.x;
    const int lid = (wg & 7) * 64 + (wg >> 3);   // chunked XCD swizzle
    const int qt = lid & 3;
    const int h  = (lid >> 2) & 7;
    const int b  = lid >> 5;
    const int q0 = qt * 256 + wid * 32;
    const short* qkvb = qkv + (size_t)b * NN * 768;

    s8v qf0, qf1;
    {
        const short* qrow = qkvb + (size_t)(q0 + lq) * 768 + h * 32 + hi * 8;
        qf0 = *(const s8v*)qrow;
        qf1 = *(const s8v*)(qrow + 16);
    }

    const int token = tid & 127, cK = tid >> 7, dc = cK * 8;
    const f16x fz = {};
    const s8v vone = { 0x3F80, 0x3F80, 0x3F80, 0x3F80, 0x3F80, 0x3F80, 0x3F80, 0x3F80 };

    f16x acc = {};
    f16x lacc = {};

    {   // prologue: stage tile 0
        const short* kvrow = qkvb + (size_t)token * 768 + 256 + h * 32;
        GLOAD16(kvrow + cK * 8, &Klds[0][cK][token][0]);
        s8v vv = *(const s8v*)(kvrow + 256 + dc);
        #pragma unroll
        for (int j = 0; j < 8; ++j) Vlds[0][dc + j][token] = vv[j];
    }
    __syncthreads();

    for (int t = 0; t < 8; ++t) {
        const int bb = t & 1;
        s8v vvn;
        if (t < 7) {
            const short* kvrow = qkvb + (size_t)((t + 1) * 128 + token) * 768 + 256 + h * 32;
            GLOAD16(kvrow + cK * 8, &Klds[bb ^ 1][cK][token][0]);
            vvn = *(const s8v*)(kvrow + 256 + dc);
        }
        #pragma unroll
        for (int kt = 0; kt < 4; ++kt) {
            const s8v kf0 = *(const s8v*)&Klds[bb][hi][kt * 32 + lq][0];
            const s8v kf1 = *(const s8v*)&Klds[bb][2 + hi][kt * 32 + lq][0];
            __builtin_amdgcn_s_setprio(1);
            f16x p = __builtin_amdgcn_mfma_f32_32x32x16_bf16(kf0, qf0, fz, 0, 0, 0);
            p = __builtin_amdgcn_mfma_f32_32x32x16_bf16(kf1, qf1, p, 0, 0, 0);
            __builtin_amdgcn_s_setprio(0);
            #pragma unroll
            for (int r = 0; r < 16; ++r) p[r] = __builtin_amdgcn_exp2f(p[r]);
            unsigned w[8];
            #pragma unroll
            for (int i = 0; i < 8; ++i) w[i] = cvtpk_bf16(p[2 * i], p[2 * i + 1]);
            asm volatile("v_permlane32_swap_b32 %0, %1" : "+v"(w[0]), "+v"(w[2]));
            asm volatile("v_permlane32_swap_b32 %0, %1" : "+v"(w[1]), "+v"(w[3]));
            asm volatile("v_permlane32_swap_b32 %0, %1" : "+v"(w[4]), "+v"(w[6]));
            asm volatile("v_permlane32_swap_b32 %0, %1" : "+v"(w[5]), "+v"(w[7]));
            union { unsigned u[4]; s8v v; } pa0, pa1;
            pa0.u[0] = w[0]; pa0.u[1] = w[1]; pa0.u[2] = w[2]; pa0.u[3] = w[3];
            pa1.u[0] = w[4]; pa1.u[1] = w[5]; pa1.u[2] = w[6]; pa1.u[3] = w[7];
            const s8v vf0 = *(const s8v*)&Vlds[bb][lq][kt * 32 + hi * 8];
            const s8v vf1 = *(const s8v*)&Vlds[bb][lq][kt * 32 + 16 + hi * 8];
            __builtin_amdgcn_s_setprio(1);
            acc  = __builtin_amdgcn_mfma_f32_32x32x16_bf16(pa0.v, vf0, acc, 0, 0, 0);
            acc  = __builtin_amdgcn_mfma_f32_32x32x16_bf16(pa1.v, vf1, acc, 0, 0, 0);
            lacc = __builtin_amdgcn_mfma_f32_32x32x16_bf16(pa0.v, vone, lacc, 0, 0, 0);
            lacc = __builtin_amdgcn_mfma_f32_32x32x16_bf16(pa1.v, vone, lacc, 0, 0, 0);
            __builtin_amdgcn_s_setprio(0);
        }
        if (t < 7) {
            #pragma unroll
            for (int j = 0; j < 8; ++j) Vlds[bb ^ 1][dc + j][token] = vvn[j];
        }
        __syncthreads();
    }

    // lacc[r] = sum_k P for the same fragment row as acc[r]: lane-local normalize
    short* ob = o + ((size_t)(b * NN + q0)) * HH + h * 32 + lq;
    #pragma unroll
    for (int r = 0; r < 16; ++r) {
        int qr = (r & 3) + 8 * (r >> 2) + 4 * hi;
        ob[(size_t)qr * HH] = f2b(acc[r] * __builtin_amdgcn_rcpf(lacc[r]));
    }
}

// ---------------- fused allocation: all stages, latency-tuned (block per batch) ----------------
__global__ __launch_bounds__(1024) void alloc_all(const short* __restrict__ enc,
                                                  const int* __restrict__ idx,
                                                  const float* __restrict__ Wc,
                                                  const float* __restrict__ bc,
                                                  float* __restrict__ out) {
    __shared__ float part[16][HH];     // 16 KB; reused: gather partials, then ctx partials
    __shared__ float mean_s[HH];
    __shared__ float ctx_s[HH];
    __shared__ float sc_s[KSEL];
    __shared__ float alloc_s[KSEL];
    __shared__ int   idx_s[KSEL];
    __shared__ float red[16];
    __shared__ float cnt_s, smax_s, ssum_s, diff_s;
    const int b = blockIdx.x, t = threadIdx.x;
    const int w = t >> 6, lane = t & 63;

    if (t < KSEL) idx_s[t] = idx[b * KSEL + t];
    __syncthreads();

    // count valid
    {
        float c = (t < KSEL && idx_s[t] < NN) ? 1.f : 0.f;
        #pragma unroll
        for (int o = 32; o; o >>= 1) c += __shfl_xor(c, o);
        if (lane == 0) red[w] = c;
    }
    // gather partial sums: wave w handles k in [w*32, w*32+32), lane covers 4 cols
    {
        const int c0 = lane * 4;
        float s0 = 0.f, s1 = 0.f, s2 = 0.f, s3 = 0.f;
        #pragma unroll
        for (int i = 0; i < 32; ++i) {
            int id = idx_s[w * 32 + i];
            if (id < NN) {
                s4v v = *(const s4v*)(enc + (size_t)(b * NN + id) * HH + c0);
                s0 += b2f(v[0]); s1 += b2f(v[1]); s2 += b2f(v[2]); s3 += b2f(v[3]);
            }
        }
        part[w][c0] = s0; part[w][c0 + 1] = s1; part[w][c0 + 2] = s2; part[w][c0 + 3] = s3;
    }
    __syncthreads();
    if (t == 0) {
        float s = 0.f;
        #pragma unroll
        for (int i = 0; i < 16; ++i) s += red[i];
        cnt_s = fmaxf(s, 1.f);
    }
    __syncthreads();
    if (t < HH) {
        float s = 0.f;
        #pragma unroll
        for (int p = 0; p < 16; ++p) s += part[p][t];
        mean_s[t] = s / cnt_s;
    }
    __syncthreads();

    // ctx GEMV, wave-parallel: wave w covers j in [w*16, w*16+16); lane covers 4 cols.
    {
        const int c0 = lane * 4;
        f4v pc = {};
        #pragma unroll
        for (int jj = 0; jj < 16; ++jj) {
            int j = w * 16 + jj;
            float mj = mean_s[j];
            const f4v wr = *(const f4v*)(Wc + (size_t)j * HH + c0);
            pc[0] = fmaf(mj, wr[0], pc[0]);
            pc[1] = fmaf(mj, wr[1], pc[1]);
            pc[2] = fmaf(mj, wr[2], pc[2]);
            pc[3] = fmaf(mj, wr[3], pc[3]);
        }
        part[w][c0] = pc[0]; part[w][c0 + 1] = pc[1];
        part[w][c0 + 2] = pc[2]; part[w][c0 + 3] = pc[3];
    }
    __syncthreads();
    if (t < HH) {
        float s = bc[t];
        #pragma unroll
        for (int p = 0; p < 16; ++p) s += part[p][t];
        ctx_s[t] = s;
    }
    __syncthreads();

    // scores: wave w handles indices k in [w*32, w*32+32), 64-lane dot each; unroll 4
    {
        const f4v cv = *(const f4v*)(ctx_s + lane * 4);
        #pragma unroll 4
        for (int i = 0; i < 32; ++i) {
            int k = w * 32 + i;
            int id = idx_s[k];
            float sc = -1e9f;
            if (id < NN) {
                s4v v = *(const s4v*)(enc + (size_t)(b * NN + id) * HH + lane * 4);
                float p = cv[0] * b2f(v[0]) + cv[1] * b2f(v[1]) + cv[2] * b2f(v[2]) + cv[3] * b2f(v[3]);
                #pragma unroll
                for (int o = 32; o; o >>= 1) p += __shfl_xor(p, o);
                sc = p;
            }
            if (lane == 0) sc_s[k] = sc;
        }
    }
    __syncthreads();

    // softmax over 512 + round + fix + scatter
    float myv = (t < KSEL) ? sc_s[t] : -1e9f;
    {
        float m = myv;
        #pragma unroll
        for (int o = 32; o; o >>= 1) m = fmaxf(m, __shfl_xor(m, o));
        if (lane == 0) red[w] = m;
        __syncthreads();
        if (t == 0) {
            float mm = red[0];
            #pragma unroll
            for (int i = 1; i < 16; ++i) mm = fmaxf(mm, red[i]);
            smax_s = mm;
        }
        __syncthreads();
    }
    float e = (t < KSEL && idx_s[t] < NN) ? __expf(myv - smax_s) : 0.f;
    {
        float s = e;
        #pragma unroll
        for (int o = 32; o; o >>= 1) s += __shfl_xor(s, o);
        if (lane == 0) red[w] = s;
        __syncthreads();
        if (t == 0) {
            float ss = 0.f;
            #pragma unroll
            for (int i = 0; i < 16; ++i) ss += red[i];
            ssum_s = ss;
        }
        __syncthreads();
    }
    float a = rintf(e * (100.f / ssum_s));
    if (t < KSEL) alloc_s[t] = a;
    {
        float s = (t < KSEL) ? a : 0.f;
        #pragma unroll
        for (int o = 32; o; o >>= 1) s += __shfl_xor(s, o);
        if (lane == 0) red[w] = s;
        __syncthreads();
        if (t == 0) {
            float ss = 0.f;
            #pragma unroll
            for (int i = 0; i < 16; ++i) ss += red[i];
            diff_s = 100.f - ss;
        }
        __syncthreads();
        if (t == 0 && idx_s[0] < NN) alloc_s[0] += diff_s;
    }

    float* bw = out + BB * KSEL + (size_t)b * NN;
    bw[t] = 0.f;                        // 1024 threads cover NN exactly
    __syncthreads();
    if (t < KSEL) {
        int id = idx_s[t];
        out[b * KSEL + t] = (float)id;
        if (id < NN) bw[id] = alloc_s[t];
    }
}

// ---------------- launch ----------------
extern "C" void kernel_launch(void* const* d_in, const int* in_sizes, int n_in,
                              void* d_out, int out_size, void* d_ws, size_t ws_size,
                              hipStream_t stream) {
    const float* x     = (const float*)d_in[0];
    const int*   sel   = (const int*)  d_in[1];
    const float* W_in  = (const float*)d_in[2];
    const float* b_in  = (const float*)d_in[3];
    const float* Wqkv  = (const float*)d_in[4];
    const float* bqkv  = (const float*)d_in[5];
    const float* Wo    = (const float*)d_in[6];
    const float* bo    = (const float*)d_in[7];
    const float* ln1_g = (const float*)d_in[8];
    const float* ln1_b = (const float*)d_in[9];
    const float* W1    = (const float*)d_in[10];
    const float* b1    = (const float*)d_in[11];
    const float* W2    = (const float*)d_in[12];
    const float* b2    = (const float*)d_in[13];
    const float* ln2_g = (const float*)d_in[14];
    const float* ln2_b = (const float*)d_in[15];
    const float* Wc    = (const float*)d_in[16];
    const float* bc    = (const float*)d_in[17];
    float* out = (float*)d_out;

    char* base = (char*)d_ws;
    short* h    = (short*)(base);                       // 8 MB
    short* qkv  = (short*)(base + (8u << 20));          // 24 MB
    short* obuf = (short*)(base + (32u << 20));         // 8 MB
    short* ff   = (short*)(base + (40u << 20));         // 32 MB
    short* xb   = (short*)(base + (76u << 20));         // 2 MB
    short* wt   = (short*)(base + (78u << 20));         // ~3.1 MB
    short* W_inT  = wt;
    short* WqkvT  = W_inT + 256 * 64;
    short* WoT    = WqkvT + LL * 768 * 256;
    short* W1T    = WoT   + LL * 256 * 256;
    short* W2T    = W1T   + LL * 1024 * 256;

    // fused weight transpose + x conversion: 9 segments (1552 tiles) + 1024 cvt blocks
    {
        WtDesc d;
        const float* srcs[9] = { W_in, Wqkv, Wqkv + (size_t)HH * 768, Wo, Wo + (size_t)HH * HH,
                                 W1, W1 + (size_t)HH * FFD, W2, W2 + (size_t)FFD * HH };
        short* dsts[9] = { W_inT, WqkvT, WqkvT + 768 * 256, WoT, WoT + 256 * 256,
                           W1T, W1T + 1024 * 256, W2T, W2T + 256 * 1024 };
        int Ks[9] = { 64, 256, 256, 256, 256, 256, 256, 1024, 1024 };
        int Ns[9] = { 256, 768, 768, 256, 256, 1024, 1024, 256, 256 };
        int tb = 0;
        for (int i = 0; i < 9; ++i) {
            d.src[i] = srcs[i]; d.dst[i] = dsts[i];
            d.K[i] = Ks[i]; d.N[i] = Ns[i]; d.tb[i] = tb;
            tb += (Ks[i] >> 5) * (Ns[i] >> 5);
        }
        d.x = x; d.xb = xb; d.cvt_tb = tb;
        wtrans_all<<<tb + MTOT * DIN / 1024, 256, 0, stream>>>(d);
    }

    // h = x @ W_in + b_in     BN=64: grid 4*128=512
    gemm_mfma<64,0,0><<<512, 256, 0, stream>>>(xb, W_inT, b_in, h, MTOT, DIN, HH, 4, 64);

    for (int l = 0; l < LL; ++l) {
        // qkv projection; Q columns pre-scaled by log2(e)/sqrt(HD).  grid 6*128=768
        gemm_mfma<128,0,1><<<768, 256, 0, stream>>>(
            h, WqkvT + (size_t)l * 768 * HH, bqkv + l * 768, qkv, MTOT, HH, 768, 6, 96);
        attn_mfma<<<BB * NHEAD * 4, 512, 0, stream>>>(qkv, obuf);
        // o-proj + residual + LN1 fused (block per 64 rows, full row width, 8 waves)
        gemm_ln<<<MTOT / 64, 512, 0, stream>>>(
            obuf, WoT + (size_t)l * HH * HH, bo + l * HH, h, ln1_g + l * HH, ln1_b + l * HH, HH);
        gemm_mfma<128,1,0><<<1024, 256, 0, stream>>>(
            h, W1T + (size_t)l * FFD * HH, b1 + l * FFD, ff, MTOT, HH, FFD, 8, 128);
        // ffn2 + residual + LN2 fused
        gemm_ln<<<MTOT / 64, 512, 0, stream>>>(
            ff, W2T + (size_t)l * HH * FFD, b2 + l * HH, h, ln2_g + l * HH, ln2_b + l * HH, FFD);
    }

    alloc_all<<<BB, 1024, 0, stream>>>(h, sel, Wc, bc, out);
}

// Round 12
// 313.424 us; speedup vs baseline: 8.3242x; 1.0316x over previous
//
#include <hip/hip_runtime.h>
#include <math.h>

#define BB 16
#define NN 1024
#define KSEL 512
#define DIN 64
#define HH 256
#define NHEAD 8
#define HD 32
#define LL 2
#define FFD 1024
#define MTOT (BB*NN)   // 16384

typedef __attribute__((ext_vector_type(8))) short s8v;   // 8 bf16
typedef __attribute__((ext_vector_type(4))) short s4v;
typedef __attribute__((ext_vector_type(4))) float f4v;
typedef __attribute__((ext_vector_type(16))) float f16x;

// 1/sqrt(32) * log2(e): QK^T scores land in log2 domain -> native exp2
#define QK_SCALE 0.25503485f

__device__ __forceinline__ float b2f(short u) {
    union { unsigned int i; float f; } v;
    v.i = ((unsigned int)(unsigned short)u) << 16;
    return v.f;
}
__device__ __forceinline__ short f2b(float f) {
    union { float f; unsigned int i; } v;
    v.f = f;
    unsigned int r = v.i + 0x7fffu + ((v.i >> 16) & 1u);
    return (short)(r >> 16);
}
__device__ __forceinline__ unsigned cvtpk_bf16(float a, float b) {
    unsigned r;
    asm("v_cvt_pk_bf16_f32 %0, %1, %2" : "=v"(r) : "v"(a), "v"(b));
    return r;
}

#define GLOAD16(g, l) __builtin_amdgcn_global_load_lds( \
    (const __attribute__((address_space(1))) unsigned int*)(const void*)(g), \
    (__attribute__((address_space(3))) unsigned int*)(l), 16, 0, 0)

// ---------------- fused weight transpose+convert + x-cvt (one launch) ----------------
struct WtDesc {
    const float* src[9];
    short* dst[9];
    int K[9], N[9], tb[9];
    const float* x;       // cvt source
    short* xb;            // cvt dest
    int cvt_tb;           // first cvt block
};
__global__ __launch_bounds__(256) void wtrans_all(WtDesc d) {
    __shared__ float s[32][33];
    const int bid = blockIdx.x;
    if (bid >= d.cvt_tb) {
        int i = (bid - d.cvt_tb) * 256 + threadIdx.x;   // 4-elem chunk index
        f4v v = *(const f4v*)(d.x + (size_t)i * 4);
        s4v o;
        o[0] = f2b(v[0]); o[1] = f2b(v[1]); o[2] = f2b(v[2]); o[3] = f2b(v[3]);
        *(s4v*)(d.xb + (size_t)i * 4) = o;
        return;
    }
    int si = 0;
    #pragma unroll
    for (int i = 1; i < 9; ++i) si = (bid >= d.tb[i]) ? i : si;
    const float* in = d.src[si];
    short* out = d.dst[si];
    const int K = d.K[si], N = d.N[si];
    const int lt = bid - d.tb[si];
    const int tn = N >> 5;
    const int bk = (lt / tn) * 32, bn = (lt % tn) * 32;
    const int c = threadIdx.x & 31, r8 = threadIdx.x >> 5;
    #pragma unroll
    for (int i = 0; i < 4; ++i) {
        int r = r8 + i * 8;
        s[r][c] = in[(size_t)(bk + r) * N + bn + c];
    }
    __syncthreads();
    #pragma unroll
    for (int i = 0; i < 4; ++i) {
        int r = r8 + i * 8;
        out[(size_t)(bn + r) * K + bk + c] = f2b(s[c][r]);
    }
}

// ---------------- bf16 MFMA GEMM: C[M,N] = A[M,K] @ BT[N,K]^T + bias ----------------
// 128xBN tile (BN = 64 or 128), BK=64, 4 waves (2x2), 16x16x32 mfma,
// global_load_lds staging, 8-slot XOR swizzle, chunked XCD swizzle (grid % 8 == 0).
template<int BN, int RELU, int QSCALE>
__global__ __launch_bounds__(256) void gemm_mfma(const short* __restrict__ A,
                                                 const short* __restrict__ BT,
                                                 const float* __restrict__ bias,
                                                 short* __restrict__ C,
                                                 int M, int K, int N,
                                                 int nbx, int cpx) {
    __shared__ __align__(16) short Alds[128 * 64];
    __shared__ __align__(16) short Blds[BN * 64];
    const int tid = threadIdx.x, lane = tid & 63, wid = tid >> 6;
    const int wg = blockIdx.x;
    const int lid = (wg & 7) * cpx + (wg >> 3);
    const int bx = lid % nbx, by = lid / nbx;
    const int bm = by * 128, bn = bx * BN;
    const int wr = wid >> 1, wc = wid & 1;
    const int NF = BN / 32;
    f4v acc[4][NF] = {};

    const short* aB = A + (size_t)bm * K;
    const short* bB = BT + (size_t)bn * K;
    const int frow = lane & 15, fs = lane >> 4;

    for (int k0 = 0; k0 < K; k0 += 64) {
        #pragma unroll
        for (int i = 0; i < 4; ++i) {
            int cb = wid * 64 + i * 256;
            int c = cb + lane;
            int row = c >> 3;
            GLOAD16(aB + (size_t)row * K + k0 + (((c & 7) ^ (row & 7)) * 8), Alds + cb * 8);
        }
        #pragma unroll
        for (int i = 0; i < NF; ++i) {
            int cb = wid * 64 + i * 256;
            int c = cb + lane;
            int row = c >> 3;
            GLOAD16(bB + (size_t)row * K + k0 + (((c & 7) ^ (row & 7)) * 8), Blds + cb * 8);
        }
        __syncthreads();
        #pragma unroll
        for (int kk = 0; kk < 2; ++kk) {
            s8v af[4], bf[NF];
            #pragma unroll
            for (int m = 0; m < 4; ++m) {
                int row = wr * 64 + m * 16 + frow;
                af[m] = *(const s8v*)(Alds + row * 64 + (((kk * 4 + fs) ^ (row & 7)) * 8));
            }
            #pragma unroll
            for (int n = 0; n < NF; ++n) {
                int row = wc * (BN / 2) + n * 16 + frow;
                bf[n] = *(const s8v*)(Blds + row * 64 + (((kk * 4 + fs) ^ (row & 7)) * 8));
            }
            __builtin_amdgcn_s_setprio(1);
            #pragma unroll
            for (int m = 0; m < 4; ++m)
                #pragma unroll
                for (int n = 0; n < NF; ++n)
                    acc[m][n] = __builtin_amdgcn_mfma_f32_16x16x32_bf16(af[m], bf[n], acc[m][n], 0, 0, 0);
            __builtin_amdgcn_s_setprio(0);
        }
        __syncthreads();
    }
    #pragma unroll
    for (int m = 0; m < 4; ++m) {
        int rbase = bm + wr * 64 + m * 16 + (lane >> 4) * 4;
        #pragma unroll
        for (int n = 0; n < NF; ++n) {
            int col = bn + wc * (BN / 2) + n * 16 + (lane & 15);
            float bv = bias[col];
            #pragma unroll
            for (int r = 0; r < 4; ++r) {
                float v = acc[m][n][r] + bv;
                if (QSCALE) { if (col < 256) v *= QK_SCALE; }
                if (RELU) v = fmaxf(v, 0.f);
                C[(size_t)(rbase + r) * N + col] = f2b(v);
            }
        }
    }
}

// ---------------- fused GEMM + residual + LayerNorm (8 waves) ----------------
// BM=64, BN=256 (= full row), BK=64, 8 waves (2 row x 4 col), 2-phase dbuf.
// h = LN(h + A@BT^T + bias) * g + beta, written in place to h.
__global__ __launch_bounds__(512) void gemm_ln(const short* __restrict__ A,
                                               const short* __restrict__ BT,
                                               const float* __restrict__ bias,
                                               short* __restrict__ h,
                                               const float* __restrict__ g,
                                               const float* __restrict__ beta,
                                               int K) {
    __shared__ __align__(16) short Alds[2][64 * 64];
    __shared__ __align__(16) short Blds[2][256 * 64];
    __shared__ float lred[64][4][2];   // [row][wc][{sum, sumsq}]
    const int tid = threadIdx.x, lane = tid & 63, wid = tid >> 6;
    const int wr = wid >> 2, wc = wid & 3;     // 2 x 4 wave grid
    const int bm = blockIdx.x * 64;
    const int frow = lane & 15, fs = lane >> 4;
    f4v acc[2][4] = {};

    const short* aB = A + (size_t)bm * K;

    // stage A: 1 round of 512 x 16B; B: 4 rounds
    #define STAGE_AB(buf, k0)                                                            \
        {                                                                                \
            {                                                                            \
                int u = tid;                                                             \
                int row = u >> 3;                                                        \
                GLOAD16(aB + (size_t)row * K + (k0) + (((u & 7) ^ (row & 7)) * 8),       \
                        Alds[buf] + u * 8);                                              \
            }                                                                            \
            _Pragma("unroll")                                                            \
            for (int i = 0; i < 4; ++i) {                                                \
                int u = i * 512 + tid;                                                   \
                int row = u >> 3;                                                        \
                GLOAD16(BT + (size_t)row * K + (k0) + (((u & 7) ^ (row & 7)) * 8),       \
                        Blds[buf] + u * 8);                                              \
            }                                                                            \
        }

    STAGE_AB(0, 0);
    __syncthreads();
    int cur = 0;
    for (int k0 = 0; k0 < K; k0 += 64) {
        if (k0 + 64 < K) STAGE_AB(cur ^ 1, k0 + 64);
        #pragma unroll
        for (int kk = 0; kk < 2; ++kk) {
            s8v af[2], bf[4];
            #pragma unroll
            for (int m = 0; m < 2; ++m) {
                int row = wr * 32 + m * 16 + frow;
                af[m] = *(const s8v*)(Alds[cur] + row * 64 + (((kk * 4 + fs) ^ (row & 7)) * 8));
            }
            #pragma unroll
            for (int n = 0; n < 4; ++n) {
                int row = wc * 64 + n * 16 + frow;
                bf[n] = *(const s8v*)(Blds[cur] + row * 64 + (((kk * 4 + fs) ^ (row & 7)) * 8));
            }
            __builtin_amdgcn_s_setprio(1);
            #pragma unroll
            for (int m = 0; m < 2; ++m)
                #pragma unroll
                for (int n = 0; n < 4; ++n)
                    acc[m][n] = __builtin_amdgcn_mfma_f32_16x16x32_bf16(af[m], bf[n], acc[m][n], 0, 0, 0);
            __builtin_amdgcn_s_setprio(0);
        }
        __syncthreads();
        cur ^= 1;
    }
    #undef STAGE_AB

    // epilogue: v = acc + bias + h; row stats; LN write
    float s1[2][4], s2[2][4];
    #pragma unroll
    for (int m = 0; m < 2; ++m) {
        #pragma unroll
        for (int r = 0; r < 4; ++r) { s1[m][r] = 0.f; s2[m][r] = 0.f; }
    }
    #pragma unroll
    for (int m = 0; m < 2; ++m) {
        #pragma unroll
        for (int n = 0; n < 4; ++n) {
            int gc = wc * 64 + n * 16 + frow;
            float bv = bias[gc];
            #pragma unroll
            for (int r = 0; r < 4; ++r) {
                int gr = bm + wr * 32 + m * 16 + fs * 4 + r;
                float v = acc[m][n][r] + bv + b2f(h[(size_t)gr * HH + gc]);
                acc[m][n][r] = v;
                s1[m][r] += v;
                s2[m][r] += v * v;
            }
        }
    }
    #pragma unroll
    for (int m = 0; m < 2; ++m) {
        #pragma unroll
        for (int r = 0; r < 4; ++r) {
            float a = s1[m][r], bq = s2[m][r];
            #pragma unroll
            for (int off = 1; off < 16; off <<= 1) {   // reduce over frow (within 16-lane group)
                a += __shfl_xor(a, off);
                bq += __shfl_xor(bq, off);
            }
            if (frow == 0) {
                int lr = wr * 32 + m * 16 + fs * 4 + r;
                lred[lr][wc][0] = a;
                lred[lr][wc][1] = bq;
            }
        }
    }
    __syncthreads();
    #pragma unroll
    for (int m = 0; m < 2; ++m) {
        #pragma unroll
        for (int r = 0; r < 4; ++r) {
            int lr = wr * 32 + m * 16 + fs * 4 + r;
            float t1 = lred[lr][0][0] + lred[lr][1][0] + lred[lr][2][0] + lred[lr][3][0];
            float t2 = lred[lr][0][1] + lred[lr][1][1] + lred[lr][2][1] + lred[lr][3][1];
            float mean = t1 * (1.f / HH);
            float var = t2 * (1.f / HH) - mean * mean;
            float rs = rsqrtf(var + 1e-5f);
            int gr = bm + lr;
            #pragma unroll
            for (int n = 0; n < 4; ++n) {
                int gc = wc * 64 + n * 16 + frow;
                h[(size_t)gr * HH + gc] = f2b((acc[m][n][r] - mean) * rs * g[gc] + beta[gc]);
            }
        }
    }
}

// ---------------- MFMA flash attention (swapped QK^T, no-max softmax) ----------------
// 512 thr = 8 waves; wave w: 32 q rows; q-tile 256; KV tile 256 tokens, double-buffered
// (4 tiles -> 8 barriers instead of 16: halves barrier/staging serialization).
// Softmax denominator on the MATRIX pipe: lacc = mfma(P, ones) -> lane-local normalize.
__global__ __launch_bounds__(512) void attn_mfma(const short* __restrict__ qkv,
                                                 short* __restrict__ o) {
    __shared__ __align__(16) short Klds[2][4][256][8];   // [buf][hd-chunk][token][8hd]
    __shared__ __align__(16) short Vlds[2][32][264];     // [buf][d][token padded]
    const int tid = threadIdx.x, lane = tid & 63, wid = tid >> 6;
    const int hi = lane >> 5, lq = lane & 31;
    const int wg = blockIdx.x;
    const int lid = (wg & 7) * 64 + (wg >> 3);   // chunked XCD swizzle
    const int qt = lid & 3;
    const int h  = (lid >> 2) & 7;
    const int b  = lid >> 5;
    const int q0 = qt * 256 + wid * 32;
    const short* qkvb = qkv + (size_t)b * NN * 768;

    s8v qf0, qf1;
    {
        const short* qrow = qkvb + (size_t)(q0 + lq) * 768 + h * 32 + hi * 8;
        qf0 = *(const s8v*)qrow;
        qf1 = *(const s8v*)(qrow + 16);
    }

    const int token = tid & 127, cK = tid >> 7, dc = cK * 8;
    const f16x fz = {};
    const s8v vone = { 0x3F80, 0x3F80, 0x3F80, 0x3F80, 0x3F80, 0x3F80, 0x3F80, 0x3F80 };

    f16x acc = {};
    f16x lacc = {};

    {   // prologue: stage tile 0 (256 tokens; each thread covers token and token+128)
        const short* kvrow0 = qkvb + (size_t)token * 768 + 256 + h * 32;
        const short* kvrow1 = qkvb + (size_t)(token + 128) * 768 + 256 + h * 32;
        GLOAD16(kvrow0 + cK * 8, &Klds[0][cK][token][0]);
        GLOAD16(kvrow1 + cK * 8, &Klds[0][cK][token + 128][0]);
        s8v vv0 = *(const s8v*)(kvrow0 + 256 + dc);
        s8v vv1 = *(const s8v*)(kvrow1 + 256 + dc);
        #pragma unroll
        for (int j = 0; j < 8; ++j) {
            Vlds[0][dc + j][token]       = vv0[j];
            Vlds[0][dc + j][token + 128] = vv1[j];
        }
    }
    __syncthreads();

    for (int t = 0; t < 4; ++t) {
        const int bb = t & 1;
        s8v vvn0, vvn1;
        if (t < 3) {
            const short* kvrow0 = qkvb + (size_t)((t + 1) * 256 + token) * 768 + 256 + h * 32;
            const short* kvrow1 = kvrow0 + 128 * 768;
            GLOAD16(kvrow0 + cK * 8, &Klds[bb ^ 1][cK][token][0]);
            GLOAD16(kvrow1 + cK * 8, &Klds[bb ^ 1][cK][token + 128][0]);
            vvn0 = *(const s8v*)(kvrow0 + 256 + dc);
            vvn1 = *(const s8v*)(kvrow1 + 256 + dc);
        }
        #pragma unroll
        for (int kt = 0; kt < 8; ++kt) {
            const s8v kf0 = *(const s8v*)&Klds[bb][hi][kt * 32 + lq][0];
            const s8v kf1 = *(const s8v*)&Klds[bb][2 + hi][kt * 32 + lq][0];
            __builtin_amdgcn_s_setprio(1);
            f16x p = __builtin_amdgcn_mfma_f32_32x32x16_bf16(kf0, qf0, fz, 0, 0, 0);
            p = __builtin_amdgcn_mfma_f32_32x32x16_bf16(kf1, qf1, p, 0, 0, 0);
            __builtin_amdgcn_s_setprio(0);
            #pragma unroll
            for (int r = 0; r < 16; ++r) p[r] = __builtin_amdgcn_exp2f(p[r]);
            unsigned w[8];
            #pragma unroll
            for (int i = 0; i < 8; ++i) w[i] = cvtpk_bf16(p[2 * i], p[2 * i + 1]);
            asm volatile("v_permlane32_swap_b32 %0, %1" : "+v"(w[0]), "+v"(w[2]));
            asm volatile("v_permlane32_swap_b32 %0, %1" : "+v"(w[1]), "+v"(w[3]));
            asm volatile("v_permlane32_swap_b32 %0, %1" : "+v"(w[4]), "+v"(w[6]));
            asm volatile("v_permlane32_swap_b32 %0, %1" : "+v"(w[5]), "+v"(w[7]));
            union { unsigned u[4]; s8v v; } pa0, pa1;
            pa0.u[0] = w[0]; pa0.u[1] = w[1]; pa0.u[2] = w[2]; pa0.u[3] = w[3];
            pa1.u[0] = w[4]; pa1.u[1] = w[5]; pa1.u[2] = w[6]; pa1.u[3] = w[7];
            const s8v vf0 = *(const s8v*)&Vlds[bb][lq][kt * 32 + hi * 8];
            const s8v vf1 = *(const s8v*)&Vlds[bb][lq][kt * 32 + 16 + hi * 8];
            __builtin_amdgcn_s_setprio(1);
            acc  = __builtin_amdgcn_mfma_f32_32x32x16_bf16(pa0.v, vf0, acc, 0, 0, 0);
            acc  = __builtin_amdgcn_mfma_f32_32x32x16_bf16(pa1.v, vf1, acc, 0, 0, 0);
            lacc = __builtin_amdgcn_mfma_f32_32x32x16_bf16(pa0.v, vone, lacc, 0, 0, 0);
            lacc = __builtin_amdgcn_mfma_f32_32x32x16_bf16(pa1.v, vone, lacc, 0, 0, 0);
            __builtin_amdgcn_s_setprio(0);
        }
        if (t < 3) {
            #pragma unroll
            for (int j = 0; j < 8; ++j) {
                Vlds[bb ^ 1][dc + j][token]       = vvn0[j];
                Vlds[bb ^ 1][dc + j][token + 128] = vvn1[j];
            }
        }
        __syncthreads();
    }

    // lacc[r] = sum_k P for the same fragment row as acc[r]: lane-local normalize
    short* ob = o + ((size_t)(b * NN + q0)) * HH + h * 32 + lq;
    #pragma unroll
    for (int r = 0; r < 16; ++r) {
        int qr = (r & 3) + 8 * (r >> 2) + 4 * hi;
        ob[(size_t)qr * HH] = f2b(acc[r] * __builtin_amdgcn_rcpf(lacc[r]));
    }
}

// ---------------- fused allocation: all stages, latency-tuned (block per batch) ----------------
__global__ __launch_bounds__(1024) void alloc_all(const short* __restrict__ enc,
                                                  const int* __restrict__ idx,
                                                  const float* __restrict__ Wc,
                                                  const float* __restrict__ bc,
                                                  float* __restrict__ out) {
    __shared__ float part[16][HH];     // 16 KB; reused: gather partials, then ctx partials
    __shared__ float mean_s[HH];
    __shared__ float ctx_s[HH];
    __shared__ float sc_s[KSEL];
    __shared__ float alloc_s[KSEL];
    __shared__ int   idx_s[KSEL];
    __shared__ float red[16];
    __shared__ float cnt_s, smax_s, ssum_s, diff_s;
    const int b = blockIdx.x, t = threadIdx.x;
    const int w = t >> 6, lane = t & 63;

    if (t < KSEL) idx_s[t] = idx[b * KSEL + t];
    __syncthreads();

    // count valid
    {
        float c = (t < KSEL && idx_s[t] < NN) ? 1.f : 0.f;
        #pragma unroll
        for (int o = 32; o; o >>= 1) c += __shfl_xor(c, o);
        if (lane == 0) red[w] = c;
    }
    // gather partial sums: wave w handles k in [w*32, w*32+32), lane covers 4 cols
    {
        const int c0 = lane * 4;
        float s0 = 0.f, s1 = 0.f, s2 = 0.f, s3 = 0.f;
        #pragma unroll
        for (int i = 0; i < 32; ++i) {
            int id = idx_s[w * 32 + i];
            if (id < NN) {
                s4v v = *(const s4v*)(enc + (size_t)(b * NN + id) * HH + c0);
                s0 += b2f(v[0]); s1 += b2f(v[1]); s2 += b2f(v[2]); s3 += b2f(v[3]);
            }
        }
        part[w][c0] = s0; part[w][c0 + 1] = s1; part[w][c0 + 2] = s2; part[w][c0 + 3] = s3;
    }
    __syncthreads();
    if (t == 0) {
        float s = 0.f;
        #pragma unroll
        for (int i = 0; i < 16; ++i) s += red[i];
        cnt_s = fmaxf(s, 1.f);
    }
    __syncthreads();
    if (t < HH) {
        float s = 0.f;
        #pragma unroll
        for (int p = 0; p < 16; ++p) s += part[p][t];
        mean_s[t] = s / cnt_s;
    }
    __syncthreads();

    // ctx GEMV, wave-parallel: wave w covers j in [w*16, w*16+16); lane covers 4 cols.
    {
        const int c0 = lane * 4;
        f4v pc = {};
        #pragma unroll
        for (int jj = 0; jj < 16; ++jj) {
            int j = w * 16 + jj;
            float mj = mean_s[j];
            const f4v wr = *(const f4v*)(Wc + (size_t)j * HH + c0);
            pc[0] = fmaf(mj, wr[0], pc[0]);
            pc[1] = fmaf(mj, wr[1], pc[1]);
            pc[2] = fmaf(mj, wr[2], pc[2]);
            pc[3] = fmaf(mj, wr[3], pc[3]);
        }
        part[w][c0] = pc[0]; part[w][c0 + 1] = pc[1];
        part[w][c0 + 2] = pc[2]; part[w][c0 + 3] = pc[3];
    }
    __syncthreads();
    if (t < HH) {
        float s = bc[t];
        #pragma unroll
        for (int p = 0; p < 16; ++p) s += part[p][t];
        ctx_s[t] = s;
    }
    __syncthreads();

    // scores: wave w handles indices k in [w*32, w*32+32), 64-lane dot each; unroll 4
    {
        const f4v cv = *(const f4v*)(ctx_s + lane * 4);
        #pragma unroll 4
        for (int i = 0; i < 32; ++i) {
            int k = w * 32 + i;
            int id = idx_s[k];
            float sc = -1e9f;
            if (id < NN) {
                s4v v = *(const s4v*)(enc + (size_t)(b * NN + id) * HH + lane * 4);
                float p = cv[0] * b2f(v[0]) + cv[1] * b2f(v[1]) + cv[2] * b2f(v[2]) + cv[3] * b2f(v[3]);
                #pragma unroll
                for (int o = 32; o; o >>= 1) p += __shfl_xor(p, o);
                sc = p;
            }
            if (lane == 0) sc_s[k] = sc;
        }
    }
    __syncthreads();

    // softmax over 512 + round + fix + scatter
    float myv = (t < KSEL) ? sc_s[t] : -1e9f;
    {
        float m = myv;
        #pragma unroll
        for (int o = 32; o; o >>= 1) m = fmaxf(m, __shfl_xor(m, o));
        if (lane == 0) red[w] = m;
        __syncthreads();
        if (t == 0) {
            float mm = red[0];
            #pragma unroll
            for (int i = 1; i < 16; ++i) mm = fmaxf(mm, red[i]);
            smax_s = mm;
        }
        __syncthreads();
    }
    float e = (t < KSEL && idx_s[t] < NN) ? __expf(myv - smax_s) : 0.f;
    {
        float s = e;
        #pragma unroll
        for (int o = 32; o; o >>= 1) s += __shfl_xor(s, o);
        if (lane == 0) red[w] = s;
        __syncthreads();
        if (t == 0) {
            float ss = 0.f;
            #pragma unroll
            for (int i = 0; i < 16; ++i) ss += red[i];
            ssum_s = ss;
        }
        __syncthreads();
    }
    float a = rintf(e * (100.f / ssum_s));
    if (t < KSEL) alloc_s[t] = a;
    {
        float s = (t < KSEL) ? a : 0.f;
        #pragma unroll
        for (int o = 32; o; o >>= 1) s += __shfl_xor(s, o);
        if (lane == 0) red[w] = s;
        __syncthreads();
        if (t == 0) {
            float ss = 0.f;
            #pragma unroll
            for (int i = 0; i < 16; ++i) ss += red[i];
            diff_s = 100.f - ss;
        }
        __syncthreads();
        if (t == 0 && idx_s[0] < NN) alloc_s[0] += diff_s;
    }

    float* bw = out + BB * KSEL + (size_t)b * NN;
    bw[t] = 0.f;                        // 1024 threads cover NN exactly
    __syncthreads();
    if (t < KSEL) {
        int id = idx_s[t];
        out[b * KSEL + t] = (float)id;
        if (id < NN) bw[id] = alloc_s[t];
    }
}

// ---------------- launch ----------------
extern "C" void kernel_launch(void* const* d_in, const int* in_sizes, int n_in,
                              void* d_out, int out_size, void* d_ws, size_t ws_size,
                              hipStream_t stream) {
    const float* x     = (const float*)d_in[0];
    const int*   sel   = (const int*)  d_in[1];
    const float* W_in  = (const float*)d_in[2];
    const float* b_in  = (const float*)d_in[3];
    const float* Wqkv  = (const float*)d_in[4];
    const float* bqkv  = (const float*)d_in[5];
    const float* Wo    = (const float*)d_in[6];
    const float* bo    = (const float*)d_in[7];
    const float* ln1_g = (const float*)d_in[8];
    const float* ln1_b = (const float*)d_in[9];
    const float* W1    = (const float*)d_in[10];
    const float* b1    = (const float*)d_in[11];
    const float* W2    = (const float*)d_in[12];
    const float* b2    = (const float*)d_in[13];
    const float* ln2_g = (const float*)d_in[14];
    const float* ln2_b = (const float*)d_in[15];
    const float* Wc    = (const float*)d_in[16];
    const float* bc    = (const float*)d_in[17];
    float* out = (float*)d_out;

    char* base = (char*)d_ws;
    short* h    = (short*)(base);                       // 8 MB
    short* qkv  = (short*)(base + (8u << 20));          // 24 MB
    short* obuf = (short*)(base + (32u << 20));         // 8 MB
    short* ff   = (short*)(base + (40u << 20));         // 32 MB
    short* xb   = (short*)(base + (76u << 20));         // 2 MB
    short* wt   = (short*)(base + (78u << 20));         // ~3.1 MB
    short* W_inT  = wt;
    short* WqkvT  = W_inT + 256 * 64;
    short* WoT    = WqkvT + LL * 768 * 256;
    short* W1T    = WoT   + LL * 256 * 256;
    short* W2T    = W1T   + LL * 1024 * 256;

    // fused weight transpose + x conversion: 9 segments (1552 tiles) + 1024 cvt blocks
    {
        WtDesc d;
        const float* srcs[9] = { W_in, Wqkv, Wqkv + (size_t)HH * 768, Wo, Wo + (size_t)HH * HH,
                                 W1, W1 + (size_t)HH * FFD, W2, W2 + (size_t)FFD * HH };
        short* dsts[9] = { W_inT, WqkvT, WqkvT + 768 * 256, WoT, WoT + 256 * 256,
                           W1T, W1T + 1024 * 256, W2T, W2T + 256 * 1024 };
        int Ks[9] = { 64, 256, 256, 256, 256, 256, 256, 1024, 1024 };
        int Ns[9] = { 256, 768, 768, 256, 256, 1024, 1024, 256, 256 };
        int tb = 0;
        for (int i = 0; i < 9; ++i) {
            d.src[i] = srcs[i]; d.dst[i] = dsts[i];
            d.K[i] = Ks[i]; d.N[i] = Ns[i]; d.tb[i] = tb;
            tb += (Ks[i] >> 5) * (Ns[i] >> 5);
        }
        d.x = x; d.xb = xb; d.cvt_tb = tb;
        wtrans_all<<<tb + MTOT * DIN / 1024, 256, 0, stream>>>(d);
    }

    // h = x @ W_in + b_in     BN=64: grid 4*128=512
    gemm_mfma<64,0,0><<<512, 256, 0, stream>>>(xb, W_inT, b_in, h, MTOT, DIN, HH, 4, 64);

    for (int l = 0; l < LL; ++l) {
        // qkv projection; Q columns pre-scaled by log2(e)/sqrt(HD).  grid 6*128=768
        gemm_mfma<128,0,1><<<768, 256, 0, stream>>>(
            h, WqkvT + (size_t)l * 768 * HH, bqkv + l * 768, qkv, MTOT, HH, 768, 6, 96);
        attn_mfma<<<BB * NHEAD * 4, 512, 0, stream>>>(qkv, obuf);
        // o-proj + residual + LN1 fused (block per 64 rows, full row width, 8 waves)
        gemm_ln<<<MTOT / 64, 512, 0, stream>>>(
            obuf, WoT + (size_t)l * HH * HH, bo + l * HH, h, ln1_g + l * HH, ln1_b + l * HH, HH);
        gemm_mfma<128,1,0><<<1024, 256, 0, stream>>>(
            h, W1T + (size_t)l * FFD * HH, b1 + l * FFD, ff, MTOT, HH, FFD, 8, 128);
        // ffn2 + residual + LN2 fused
        gemm_ln<<<MTOT / 64, 512, 0, stream>>>(
            ff, W2T + (size_t)l * HH * FFD, b2 + l * HH, h, ln2_g + l * HH, ln2_b + l * HH, FFD);
    }

    alloc_all<<<BB, 1024, 0, stream>>>(h, sel, Wc, bc, out);
}